// Round 4
// baseline (672.801 us; speedup 1.0000x reference)
//
#include <hip/hip_runtime.h>
#include <math.h>

#define Dv 1024
#define Ev 8
#define Hv 2816
#define Nv 4096
#define NKv 8192
#define CAPv 1280
#define TH2v 5632

typedef unsigned short u16;
typedef __attribute__((ext_vector_type(8))) short s16x8;
typedef __attribute__((ext_vector_type(4))) float f32x4;
typedef __attribute__((ext_vector_type(16))) float f32x16;
typedef __attribute__((ext_vector_type(8))) u16 u16x8;
typedef __attribute__((ext_vector_type(4))) u16 u16x4;

typedef const __attribute__((address_space(1))) void* as1_cvp;
typedef __attribute__((address_space(3))) void* as3_vp;

__device__ __forceinline__ u16 f2bf(float f) {
  unsigned u = __float_as_uint(f);
  u += 0x7fffu + ((u >> 16) & 1u);
  return (u16)(u >> 16);
}
__device__ __forceinline__ float bf2f(u16 h) {
  return __uint_as_float(((unsigned)h) << 16);
}
__device__ __forceinline__ void gload16(const void* g, void* l) {
  __builtin_amdgcn_global_load_lds((as1_cvp)g, (as3_vp)l, 16, 0, 0);
}

// ---------------- router ----------------
__global__ __launch_bounds__(256) void router_kernel(
    const float* __restrict__ x, const float* __restrict__ gw,
    int* __restrict__ tkidx, float* __restrict__ tkprob,
    float* __restrict__ red, float* __restrict__ outIdx)
{
  __shared__ float lred[17];
  int tid = threadIdx.x;
  if (tid < 17) lred[tid] = 0.f;
  __syncthreads();
  int wv = tid >> 6, ln = tid & 63;
  int n = blockIdx.x * 4 + wv;
  float a[8] = {0.f,0.f,0.f,0.f,0.f,0.f,0.f,0.f};
  const float* xr = x + (size_t)n * Dv;
  #pragma unroll
  for (int it = 0; it < 16; ++it) {
    int d = ln + it * 64;
    float xs = xr[d];
    float4 g0 = *(const float4*)(gw + (size_t)d * 8);
    float4 g1 = *(const float4*)(gw + (size_t)d * 8 + 4);
    a[0] += xs * g0.x; a[1] += xs * g0.y; a[2] += xs * g0.z; a[3] += xs * g0.w;
    a[4] += xs * g1.x; a[5] += xs * g1.y; a[6] += xs * g1.z; a[7] += xs * g1.w;
  }
  #pragma unroll
  for (int off = 32; off >= 1; off >>= 1) {
    #pragma unroll
    for (int e = 0; e < 8; ++e) a[e] += __shfl_xor(a[e], off, 64);
  }
  int i1 = 0; float v1 = a[0];
  #pragma unroll
  for (int e = 1; e < 8; ++e) if (a[e] > v1) { v1 = a[e]; i1 = e; }
  int i2 = -1; float v2 = -1e30f;
  #pragma unroll
  for (int e = 0; e < 8; ++e) if (e != i1 && a[e] > v2) { v2 = a[e]; i2 = e; }
  float Z = 0.f;
  #pragma unroll
  for (int e = 0; e < 8; ++e) Z += expf(a[e] - v1);
  float zlse = v1 + logf(Z);
  float t = expf(v2 - v1);
  float p1 = 1.f / (1.f + t);
  float p2 = t * p1;
  if (ln == 0) {
    tkidx[2*n] = i1; tkidx[2*n+1] = i2;
    tkprob[2*n] = p1; tkprob[2*n+1] = p2;
    outIdx[2*n] = (float)i1; outIdx[2*n+1] = (float)i2;
    #pragma unroll
    for (int e = 0; e < 8; ++e) atomicAdd(&lred[e], expf(a[e] - v1) / Z);
    atomicAdd(&lred[8 + i1], 1.f);
    atomicAdd(&lred[16], zlse * zlse);
  }
  __syncthreads();
  if (tid < 17) atomicAdd(&red[tid], lred[tid]);
}

__global__ void aux_kernel(const float* __restrict__ red, float* __restrict__ outAux) {
  float bl = 0.f;
  for (int e = 0; e < 8; ++e) bl += (red[e] / (float)Nv) * (red[8 + e] / (float)Nv);
  bl *= (float)Ev;
  float zl = red[16] / (float)Nv;
  outAux[0] = 0.01f * bl + 0.001f * zl;
}

// ---------------- exact stable rank ----------------
__global__ __launch_bounds__(256) void rank_kernel(const int* __restrict__ tgt,
    int* __restrict__ keep, int* __restrict__ dstNK)
{
  __shared__ int hist[256][8];
  int t = threadIdx.x;
  int h[8] = {0,0,0,0,0,0,0,0};
  int base = t * 32;
  for (int j = 0; j < 32; ++j) h[tgt[base + j]]++;
  for (int e = 0; e < 8; ++e) hist[t][e] = h[e];
  __syncthreads();
  if (t < 8) {
    int run = 0;
    for (int tt = 0; tt < 256; ++tt) { int v = hist[tt][t]; hist[tt][t] = run; run += v; }
  }
  __syncthreads();
  for (int e = 0; e < 8; ++e) h[e] = hist[t][e];
  for (int j = 0; j < 32; ++j) {
    int i = base + j; int e = tgt[i]; int r = h[e]++;
    int kp = (r < CAPv) ? 1 : 0;
    keep[i] = kp;
    if (kp) dstNK[e * CAPv + r] = i;
  }
}

// ---------------- pack ----------------
__global__ __launch_bounds__(256) void pack_kernel(const float* __restrict__ x,
    const int* __restrict__ dstNK, u16* __restrict__ buf)
{
  int s = blockIdx.x * 4 + (threadIdx.x >> 6);
  int ln = threadIdx.x & 63;
  int i = dstNK[s];
  u16* dst = buf + (size_t)s * Dv;
  if (i >= 0) {
    const float* src = x + (size_t)(i >> 1) * Dv;
    #pragma unroll
    for (int j = 0; j < 2; ++j) {
      int d0 = ln * 16 + j * 8;
      float4 v0 = *(const float4*)(src + d0);
      float4 v1 = *(const float4*)(src + d0 + 4);
      u16x8 o;
      o[0]=f2bf(v0.x); o[1]=f2bf(v0.y); o[2]=f2bf(v0.z); o[3]=f2bf(v0.w);
      o[4]=f2bf(v1.x); o[5]=f2bf(v1.y); o[6]=f2bf(v1.z); o[7]=f2bf(v1.w);
      *(u16x8*)(dst + d0) = o;
    }
  } else {
    u16x8 z = {0,0,0,0,0,0,0,0};
    *(u16x8*)(dst + ln * 16) = z;
    *(u16x8*)(dst + ln * 16 + 8) = z;
  }
}

// ---------------- transpose + f32->bf16 ----------------
__global__ __launch_bounds__(256) void tconv_kernel(const float* __restrict__ in,
    u16* __restrict__ out, int R, int C)
{
  __shared__ u16 tile[64][68];
  size_t zoff = (size_t)blockIdx.z * (size_t)R * (size_t)C;
  in += zoff; out += zoff;
  int r0 = blockIdx.y * 64, c0 = blockIdx.x * 64;
  int t = threadIdx.x;
  int cc4 = (t & 15) * 4;
  #pragma unroll
  for (int p = 0; p < 4; ++p) {
    int r = (t >> 4) + p * 16;
    float4 v = *(const float4*)(in + (size_t)(r0 + r) * C + c0 + cc4);
    u16x4 b; b[0]=f2bf(v.x); b[1]=f2bf(v.y); b[2]=f2bf(v.z); b[3]=f2bf(v.w);
    *(u16x4*)(&tile[r][cc4]) = b;
  }
  __syncthreads();
  int rr4 = (t & 15) * 4;
  #pragma unroll
  for (int p = 0; p < 4; ++p) {
    int c = (t >> 4) + p * 16;
    u16x4 o; o[0]=tile[rr4][c]; o[1]=tile[rr4+1][c]; o[2]=tile[rr4+2][c]; o[3]=tile[rr4+3][c];
    *(u16x4*)(out + (size_t)(c0 + c) * R + r0 + rr4) = o;
  }
}

// ======== 256x256 8-wave GEMM, 32x32x16 MFMA, 2-phase counted-vmcnt pipeline ========
// MODE 0: store bf16  1: SwiGLU  2: scatter via dst  3: gelu + split-K A
template<int MODE>
__global__ __launch_bounds__(512, 2) void gemm256(
    const u16* __restrict__ A, const u16* __restrict__ A2, int splitK,
    const u16* __restrict__ B, void* __restrict__ C,
    const int* __restrict__ dst,
    int Ksz, int lda, int ldb, int ldc, int ntm,
    size_t sA, size_t sB, size_t sC)
{
  __shared__ char smem[131072];  // A dbuf [0,64K), B dbuf [64K,128K)
  int e = blockIdx.y;
  int nwgx = gridDim.x;
  int bid0 = blockIdx.x;
  int q = nwgx >> 3, r = nwgx & 7;
  int xcd = bid0 & 7, lo = bid0 >> 3;
  int bid = (xcd < r ? xcd * (q + 1) : r * (q + 1) + (xcd - r) * q) + lo;
  int tm = bid % ntm, tn = bid / ntm;
  const u16* Ae  = A  + (size_t)e * sA;
  const u16* A2e = A2 + (size_t)e * sA;
  const u16* Be  = B  + (size_t)e * sB;
  long long bdelta = (const char*)A2e - (const char*)Ae;
  int tid = threadIdx.x, wv = tid >> 6, ln = tid & 63;
  int wr = wv >> 2, wc = wv & 3;
  int ln31 = ln & 31, lnhi = ln >> 5;

  // staging source pointers (pre-swizzled global; linear gload_lds dest)
  const char* aP[4]; const char* bP[4];
  int colsw = ((tid & 7) << 4) ^ (((tid >> 3) & 7) << 4);
  #pragma unroll
  for (int i = 0; i < 4; ++i) {
    int row = i * 64 + (tid >> 3);
    aP[i] = (const char*)(Ae + (size_t)(tm * 256 + row) * lda) + colsw;
    int brow;
    if (MODE == 1) {
      int s = row & 63, wcl = row >> 6;
      brow = (s < 32) ? (tn * 128 + wcl * 32 + s) : (Hv + tn * 128 + wcl * 32 + (s - 32));
    } else {
      brow = tn * 256 + row;
    }
    bP[i] = (const char*)(Be + (size_t)brow * ldb) + colsw;
  }

  // fragment LDS addressing: rows ≡ ln&7 (mod 8) -> uniform swizzle XOR per lane
  int kb[4];
  #pragma unroll
  for (int ks = 0; ks < 4; ++ks)
    kb[ks] = (ks * 32 + (lnhi << 4)) ^ ((ln & 7) << 4);
  int arb = (wr * 128 + ln31) * 128;   // + mb*32*128
  int brb = (wc * 64 + ln31) * 128;    // + n*32*128

  auto issueA = [&](int t1, int bsel, int band) {
    int k0 = t1 << 6;
    long long kbA;
    if (MODE == 3 && k0 >= splitK) kbA = bdelta + (long long)(k0 - splitK) * 2;
    else kbA = (long long)k0 * 2;
    gload16(aP[band] + kbA, smem + bsel * 32768 + band * 8192 + (wv << 10));
  };
  auto issueB = [&](int t1, int bsel, int band) {
    long long kbB = (long long)(t1 << 6) * 2;
    gload16(bP[band] + kbB, smem + 65536 + bsel * 32768 + band * 8192 + (wv << 10));
  };

  f32x16 acc[4][2];
  #pragma unroll
  for (int m = 0; m < 4; ++m)
    #pragma unroll
    for (int n = 0; n < 2; ++n)
      #pragma unroll
      for (int v = 0; v < 16; ++v) acc[m][n][v] = 0.f;

  int nt = Ksz >> 6;
  // prologue: tile 0, order [B0 B1 B2 B3 A0 A2 A1 A3]
  issueB(0, 0, 0); issueB(0, 0, 1); issueB(0, 0, 2); issueB(0, 0, 3);
  issueA(0, 0, 0); issueA(0, 0, 2); issueA(0, 0, 1); issueA(0, 0, 3);
  asm volatile("s_waitcnt vmcnt(2)" ::: "memory");  // B all + A bands 0,2 landed
  __builtin_amdgcn_s_barrier();

  for (int t = 0; t < nt; ++t) {
    int cur = t & 1;
    int nb = cur ^ 1;
    const char* sa = smem + cur * 32768;
    const char* sb = smem + 65536 + cur * 32768;
    bool pf = (t + 1 < nt);

    // B fragments for the whole tile (8 ds_read_b128)
    s16x8 bf[2][4];
    #pragma unroll
    for (int n = 0; n < 2; ++n)
      #pragma unroll
      for (int ks = 0; ks < 4; ++ks)
        bf[n][ks] = *(const s16x8*)(sb + brb + n * 4096 + kb[ks]);

    #pragma unroll
    for (int half = 0; half < 2; ++half) {
      // A fragments for this half (8 ds_read_b128); bands wr*2+half
      s16x8 af[2][4];
      #pragma unroll
      for (int mi = 0; mi < 2; ++mi)
        #pragma unroll
        for (int ks = 0; ks < 4; ++ks)
          af[mi][ks] = *(const s16x8*)(sa + arb + (half * 2 + mi) * 4096 + kb[ks]);
      if (pf) {
        if (half == 0) {
          issueB(t + 1, nb, 0); issueB(t + 1, nb, 1);
          issueB(t + 1, nb, 2); issueB(t + 1, nb, 3);
          issueA(t + 1, nb, 0); issueA(t + 1, nb, 2);
        } else {
          issueA(t + 1, nb, 1); issueA(t + 1, nb, 3);
        }
      }
      __builtin_amdgcn_s_barrier();
      asm volatile("s_waitcnt lgkmcnt(0)" ::: "memory");
      __builtin_amdgcn_s_setprio(1);
      #pragma unroll
      for (int ks = 0; ks < 4; ++ks) {
        #pragma unroll
        for (int mi = 0; mi < 2; ++mi) {
          acc[half*2+mi][0] = __builtin_amdgcn_mfma_f32_32x32x16_bf16(af[mi][ks], bf[0][ks], acc[half*2+mi][0], 0, 0, 0);
          acc[half*2+mi][1] = __builtin_amdgcn_mfma_f32_32x32x16_bf16(af[mi][ks], bf[1][ks], acc[half*2+mi][1], 0, 0, 0);
        }
      }
      __builtin_amdgcn_s_setprio(0);
      if (half == 0) {
        // A bands 1,3 of cur must be in LDS before half 1 reads them
        if (pf) asm volatile("s_waitcnt vmcnt(6)" ::: "memory");
        else    asm volatile("s_waitcnt vmcnt(0)" ::: "memory");
      } else {
        // boundary: next tile's B all + A bands 0,2 must be in LDS
        if (pf) asm volatile("s_waitcnt vmcnt(2)" ::: "memory");
      }
      __builtin_amdgcn_s_barrier();
    }
  }

  // epilogue; C row for reg r: (r&3) + 8*(r>>2) + 4*lnhi within the 32-row block
  int rb = tm * 256 + wr * 128;
  if (MODE == 0) {
    u16* Cp = (u16*)C;
    int colb = tn * 256 + wc * 64 + ln31;
    #pragma unroll
    for (int m = 0; m < 4; ++m)
      #pragma unroll
      for (int n = 0; n < 2; ++n)
        #pragma unroll
        for (int r = 0; r < 16; ++r) {
          int row = rb + m * 32 + (r & 3) + 8 * (r >> 2) + 4 * lnhi;
          Cp[(size_t)row * ldc + colb + n * 32] = f2bf(acc[m][n][r]);
        }
  } else if (MODE == 1) {
    u16* Cp = (u16*)C + (size_t)e * sC;
    int colb = tn * 128 + wc * 32 + ln31;
    #pragma unroll
    for (int m = 0; m < 4; ++m)
      #pragma unroll
      for (int r = 0; r < 16; ++r) {
        int row = rb + m * 32 + (r & 3) + 8 * (r >> 2) + 4 * lnhi;
        float g = acc[m][0][r];
        float u = acc[m][1][r];
        float sg = g / (1.f + __expf(-g));
        Cp[(size_t)row * ldc + colb] = f2bf(sg * u);
      }
  } else if (MODE == 2) {
    u16* Cp = (u16*)C;
    int colb = tn * 256 + wc * 64 + ln31;
    #pragma unroll
    for (int m = 0; m < 4; ++m)
      #pragma unroll
      for (int r = 0; r < 16; ++r) {
        int gr = rb + m * 32 + (r & 3) + 8 * (r >> 2) + 4 * lnhi;
        int i = dst[e * CAPv + gr];
        if (i >= 0) {
          Cp[(size_t)i * Dv + colb]      = f2bf(acc[m][0][r]);
          Cp[(size_t)i * Dv + colb + 32] = f2bf(acc[m][1][r]);
        }
      }
  } else {
    u16* Cp = (u16*)C;
    int colb = tn * 256 + wc * 64 + ln31;
    #pragma unroll
    for (int m = 0; m < 4; ++m)
      #pragma unroll
      for (int n = 0; n < 2; ++n)
        #pragma unroll
        for (int r = 0; r < 16; ++r) {
          int row = rb + m * 32 + (r & 3) + 8 * (r >> 2) + 4 * lnhi;
          float xg = acc[m][n][r];
          float gl = 0.5f * xg * (1.f + erff(xg * 0.70710678118654752f));
          Cp[(size_t)row * ldc + colb + n * 32] = f2bf(gl);
        }
  }
}

// ---------------- 128x128 GEMM (small final projection, f32 out) ----------------
template<int MODE>
__global__ __launch_bounds__(256) void gemm128(
    const u16* __restrict__ A, const u16* __restrict__ A2, int splitK,
    const u16* __restrict__ B, void* __restrict__ C,
    const int* __restrict__ dst,
    int Ksz, int lda, int ldb, int ldc, int ntm,
    size_t sA, size_t sB, size_t sC)
{
  __shared__ char smem[32768];
  int e = blockIdx.y;
  int bid = blockIdx.x;
  int tm = bid % ntm, tn = bid / ntm;
  const u16* Ae  = A  + (size_t)e * sA;
  const u16* Be  = B  + (size_t)e * sB;
  int tid = threadIdx.x, wv = tid >> 6, ln = tid & 63;

  const char* aP[4]; const char* bP[4];
  unsigned aL[4], bL[4];
  #pragma unroll
  for (int r = 0; r < 4; ++r) {
    int lb = r * 4096 + tid * 16;
    int row = lb >> 7;
    int colb = (lb & 127) ^ ((row & 7) << 4);
    aP[r] = (const char*)(Ae + (size_t)(tm * 128 + row) * lda) + colb;
    bP[r] = (const char*)(Be + (size_t)(tn * 128 + row) * ldb) + colb;
    aL[r] = r * 4096 + wv * 1024;
    bL[r] = 16384 + r * 4096 + wv * 1024;
  }

  f32x4 acc[2][8];
  #pragma unroll
  for (int m = 0; m < 2; ++m)
    #pragma unroll
    for (int n = 0; n < 8; ++n) acc[m][n] = (f32x4){0.f, 0.f, 0.f, 0.f};

  for (int k0 = 0; k0 < Ksz; k0 += 64) {
    size_t kbb = (size_t)k0 * 2;
    #pragma unroll
    for (int r = 0; r < 4; ++r) gload16(aP[r] + kbb, smem + aL[r]);
    #pragma unroll
    for (int r = 0; r < 4; ++r) gload16(bP[r] + kbb, smem + bL[r]);
    __syncthreads();
    #pragma unroll
    for (int ks = 0; ks < 2; ++ks) {
      int kbyte = ks * 64 + ((ln >> 4) << 4);
      s16x8 av[2];
      #pragma unroll
      for (int m = 0; m < 2; ++m) {
        int row = wv * 32 + m * 16 + (ln & 15);
        av[m] = *(const s16x8*)(smem + (row << 7) + (kbyte ^ ((row & 7) << 4)));
      }
      #pragma unroll
      for (int n = 0; n < 8; ++n) {
        int row = n * 16 + (ln & 15);
        s16x8 bv = *(const s16x8*)(smem + 16384 + (row << 7) + (kbyte ^ ((row & 7) << 4)));
        acc[0][n] = __builtin_amdgcn_mfma_f32_16x16x32_bf16(av[0], bv, acc[0][n], 0, 0, 0);
        acc[1][n] = __builtin_amdgcn_mfma_f32_16x16x32_bf16(av[1], bv, acc[1][n], 0, 0, 0);
      }
    }
    __syncthreads();
  }

  int rbase = tm * 128 + wv * 32 + ((ln >> 4) << 2);
  int cb = (ln & 15);
  float* Cp = (float*)C;
  #pragma unroll
  for (int m = 0; m < 2; ++m)
    #pragma unroll
    for (int n = 0; n < 8; ++n)
      #pragma unroll
      for (int v = 0; v < 4; ++v)
        Cp[(size_t)(rbase + m * 16 + v) * ldc + tn * 128 + n * 16 + cb] = acc[m][n][v];
  (void)A2; (void)splitK; (void)dst; (void)sC;
}

// ---------------- per-token scores + masked softmax + Cmsg ----------------
__global__ __launch_bounds__(256) void scores_kernel(
    const u16* __restrict__ MQ, const u16* __restrict__ KK,
    const int* __restrict__ keep, u16* __restrict__ Cmsg)
{
  int wv = threadIdx.x >> 6, ln = threadIdx.x & 63;
  int n = blockIdx.x * 4 + wv;
  const u16* m0 = MQ + (size_t)(2 * n) * 2048;
  const u16* m1 = MQ + (size_t)(2 * n + 1) * 2048;
  const u16* q0 = m0 + 1024;
  const u16* q1 = m1 + 1024;
  const u16* k0p = KK + (size_t)(2 * n) * 1024;
  const u16* k1p = KK + (size_t)(2 * n + 1) * 1024;
  float s00 = 0, s01 = 0, s10 = 0, s11 = 0;
  #pragma unroll
  for (int j = 0; j < 2; ++j) {
    int d0 = ln * 16 + j * 8;
    u16x8 a0 = *(const u16x8*)(q0 + d0);
    u16x8 a1 = *(const u16x8*)(q1 + d0);
    u16x8 b0 = *(const u16x8*)(k0p + d0);
    u16x8 b1 = *(const u16x8*)(k1p + d0);
    #pragma unroll
    for (int t = 0; t < 8; ++t) {
      float fa0 = bf2f(a0[t]), fa1 = bf2f(a1[t]);
      float fb0 = bf2f(b0[t]), fb1 = bf2f(b1[t]);
      s00 += fa0 * fb0; s01 += fa0 * fb1; s10 += fa1 * fb0; s11 += fa1 * fb1;
    }
  }
  #pragma unroll
  for (int off = 32; off >= 1; off >>= 1) {
    s00 += __shfl_xor(s00, off, 64);
    s01 += __shfl_xor(s01, off, 64);
    s10 += __shfl_xor(s10, off, 64);
    s11 += __shfl_xor(s11, off, 64);
  }
  const float inv = 0.03125f;
  int kp0 = keep[2 * n], kp1 = keep[2 * n + 1];
  float A00, A01, A10, A11;
  {
    float v0 = kp0 ? s00 * inv : -1e9f;
    float v1 = (kp0 && kp1) ? s01 * inv : -1e9f;
    float mx = fmaxf(v0, v1);
    float e0 = expf(v0 - mx), e1 = expf(v1 - mx);
    float den = e0 + e1;
    float a0 = kp0 ? e0 / den : 0.f;
    float a1 = (kp0 && kp1) ? e1 / den : 0.f;
    float s = fmaxf(a0 + a1, 1e-12f);
    A00 = a0 / s; A01 = a1 / s;
  }
  {
    float v0 = (kp1 && kp0) ? s10 * inv : -1e9f;
    float v1 = kp1 ? s11 * inv : -1e9f;
    float mx = fmaxf(v0, v1);
    float e0 = expf(v0 - mx), e1 = expf(v1 - mx);
    float den = e0 + e1;
    float a0 = (kp1 && kp0) ? e0 / den : 0.f;
    float a1 = kp1 ? e1 / den : 0.f;
    float s = fmaxf(a0 + a1, 1e-12f);
    A10 = a0 / s; A11 = a1 / s;
  }
  u16* c0 = Cmsg + (size_t)(2 * n) * 1024;
  u16* c1 = Cmsg + (size_t)(2 * n + 1) * 1024;
  #pragma unroll
  for (int j = 0; j < 2; ++j) {
    int d0 = ln * 16 + j * 8;
    u16x8 x0 = *(const u16x8*)(m0 + d0);
    u16x8 x1 = *(const u16x8*)(m1 + d0);
    u16x8 o0, o1;
    #pragma unroll
    for (int t = 0; t < 8; ++t) {
      float f0 = bf2f(x0[t]), f1 = bf2f(x1[t]);
      o0[t] = f2bf(A00 * f0 + A01 * f1);
      o1[t] = f2bf(A10 * f0 + A11 * f1);
    }
    *(u16x8*)(c0 + d0) = o0;
    *(u16x8*)(c1 + d0) = o1;
  }
}

// ---------------- combine ----------------
__global__ __launch_bounds__(256) void combine_kernel(
    const u16* __restrict__ sel, const u16* __restrict__ upd,
    const int* __restrict__ keep, const float* __restrict__ tkprob,
    u16* __restrict__ fusedp)
{
  int n = blockIdx.x;
  int t = threadIdx.x;
  float kp0 = keep[2 * n] ? 1.f : 0.f, kp1 = keep[2 * n + 1] ? 1.f : 0.f;
  float p0 = tkprob[2 * n] * kp0, p1 = tkprob[2 * n + 1] * kp1;
  float s = fmaxf(p0 + p1, 1e-12f);
  float w0 = p0 / s, w1 = p1 / s;
  int d0 = t * 4;
  u16x4 s0 = *(const u16x4*)(sel + (size_t)(2 * n) * Dv + d0);
  u16x4 s1 = *(const u16x4*)(sel + (size_t)(2 * n + 1) * Dv + d0);
  u16x4 u0 = *(const u16x4*)(upd + (size_t)(2 * n) * Dv + d0);
  u16x4 u1 = *(const u16x4*)(upd + (size_t)(2 * n + 1) * Dv + d0);
  u16x4 o;
  #pragma unroll
  for (int j = 0; j < 4; ++j) {
    float r0 = (bf2f(s0[j]) + bf2f(u0[j])) * kp0;
    float r1 = (bf2f(s1[j]) + bf2f(u1[j])) * kp1;
    o[j] = f2bf(w0 * r0 + w1 * r1);
  }
  *(u16x4*)(fusedp + (size_t)n * Dv + d0) = o;
}

extern "C" void kernel_launch(void* const* d_in, const int* in_sizes, int n_in,
                              void* d_out, int out_size, void* d_ws, size_t ws_size,
                              hipStream_t stream) {
  const float* x      = (const float*)d_in[0];
  const float* gate_w = (const float*)d_in[1];
  const float* w13    = (const float*)d_in[2];
  const float* w2     = (const float*)d_in[3];
  const float* msg_w  = (const float*)d_in[4];
  const float* q_w    = (const float*)d_in[5];
  const float* k_w    = (const float*)d_in[6];
  const float* upd_w1 = (const float*)d_in[7];
  const float* upd_w2 = (const float*)d_in[8];
  const float* o_w    = (const float*)d_in[9];
  float* out = (float*)d_out;
  float* outAux = out + (size_t)Nv * Dv;
  float* outIdx = outAux + 1;

  char* ws = (char*)d_ws;
  const size_t MBc = 1ull << 20;
  int*   tkidx  = (int*)(ws + 0);
  float* tkprob = (float*)(ws + 32768);
  int*   keepA  = (int*)(ws + 65536);
  int*   dstNK  = (int*)(ws + 98304);
  float* red    = (float*)(ws + 143360);
  // phase A:
  u16* BUF   = (u16*)(ws + 1 * MBc);
  u16* ACT   = (u16*)(ws + 21 * MBc);
  u16* W13B  = (u16*)(ws + 76 * MBc);
  u16* W2B   = (u16*)(ws + 76 * MBc);
  u16* SEL   = (u16*)(ws + 120 * MBc);
  u16* MSGQB = (u16*)(ws + 136 * MBc);
  u16* KB    = (u16*)(ws + 140 * MBc);
  u16* OB    = (u16*)(ws + 142 * MBc);
  u16* UPD1B = (u16*)(ws + 144 * MBc);
  u16* UPD2B = (u16*)(ws + 152 * MBc);
  // phase B:
  u16* MQ    = (u16*)(ws + 1 * MBc);
  u16* KKb   = (u16*)(ws + 33 * MBc);
  u16* CMSG  = (u16*)(ws + 49 * MBc);
  u16* G1B   = (u16*)(ws + 65 * MBc);
  u16* UPD   = (u16*)(ws + 97 * MBc);
  u16* FUSEDP= (u16*)(ws + 1 * MBc);

  hipMemsetAsync(red, 0, 68, stream);
  hipMemsetAsync(dstNK, 0xFF, Ev * CAPv * 4, stream);

  router_kernel<<<Nv / 4, 256, 0, stream>>>(x, gate_w, tkidx, tkprob, red, outIdx);
  aux_kernel<<<1, 1, 0, stream>>>(red, outAux);
  rank_kernel<<<1, 256, 0, stream>>>(tkidx, keepA, dstNK);
  pack_kernel<<<(Ev * CAPv) / 4, 256, 0, stream>>>(x, dstNK, BUF);

  // G1: convert all w13, one batched SwiGLU GEMM
  tconv_kernel<<<dim3(TH2v / 64, Dv / 64, Ev), 256, 0, stream>>>(w13, W13B, Dv, TH2v);
  gemm256<1><<<dim3((CAPv / 256) * (Hv / 128), Ev), 512, 0, stream>>>(
      BUF, BUF, 1 << 30, W13B, (void*)ACT, nullptr,
      Dv, Dv, Dv, Hv, CAPv / 256, (size_t)CAPv * Dv, (size_t)TH2v * Dv, (size_t)CAPv * Hv);

  hipMemsetAsync(SEL, 0, (size_t)NKv * Dv * 2, stream);
  tconv_kernel<<<dim3(Dv / 64, Hv / 64, Ev), 256, 0, stream>>>(w2, W2B, Hv, Dv);
  tconv_kernel<<<dim3(16, 16, 1), 256, 0, stream>>>(msg_w, MSGQB, Dv, Dv);
  tconv_kernel<<<dim3(16, 16, 1), 256, 0, stream>>>(q_w, MSGQB + (size_t)Dv * Dv, Dv, Dv);
  tconv_kernel<<<dim3(16, 16, 1), 256, 0, stream>>>(k_w, KB, Dv, Dv);
  tconv_kernel<<<dim3(16, 16, 1), 256, 0, stream>>>(o_w, OB, Dv, Dv);
  tconv_kernel<<<dim3(32, 32, 1), 256, 0, stream>>>(upd_w1, UPD1B, 2048, 2048);
  tconv_kernel<<<dim3(16, 32, 1), 256, 0, stream>>>(upd_w2, UPD2B, 2048, Dv);

  // G2: GEMM + scatter into SEL
  gemm256<2><<<dim3((CAPv / 256) * (Dv / 256), Ev), 512, 0, stream>>>(
      ACT, ACT, 1 << 30, W2B, (void*)SEL, dstNK,
      Hv, Hv, Hv, Dv, CAPv / 256, (size_t)CAPv * Hv, (size_t)Dv * Hv, 0);

  // collaboration: fused [M|Q] GEMM, then Kk GEMM, then scores
  gemm256<0><<<dim3(32 * 8, 1), 512, 0, stream>>>(SEL, SEL, 1 << 30, MSGQB, (void*)MQ, nullptr,
      Dv, Dv, Dv, 2048, 32, 0, 0, 0);
  gemm256<0><<<dim3(32 * 4, 1), 512, 0, stream>>>(MQ, MQ, 1 << 30, KB, (void*)KKb, nullptr,
      Dv, 2048, Dv, Dv, 32, 0, 0, 0);
  scores_kernel<<<Nv / 4, 256, 0, stream>>>(MQ, KKb, keepA, CMSG);

  // update MLP: cat = [SEL | CMSG] via split-K A, gelu fused
  gemm256<3><<<dim3(32 * 8, 1), 512, 0, stream>>>(SEL, CMSG, Dv, UPD1B, (void*)G1B, nullptr,
      2048, Dv, 2048, 2048, 32, 0, 0, 0);
  gemm256<0><<<dim3(32 * 4, 1), 512, 0, stream>>>(G1B, G1B, 1 << 30, UPD2B, (void*)UPD, nullptr,
      2048, 2048, 2048, Dv, 32, 0, 0, 0);

  combine_kernel<<<Nv, 256, 0, stream>>>(SEL, UPD, keepA, tkprob, FUSEDP);

  gemm128<4><<<dim3(32 * 8, 1), 256, 0, stream>>>(FUSEDP, FUSEDP, Dv, OB, (void*)out, nullptr,
      Dv, Dv, Dv, Dv, 32, 0, 0, 0);

  (void)in_sizes; (void)n_in; (void)out_size; (void)ws_size;
}

// Round 5
// 647.339 us; speedup vs baseline: 1.0393x; 1.0393x over previous
//
#include <hip/hip_runtime.h>
#include <math.h>

#define Dv 1024
#define Ev 8
#define Hv 2816
#define Nv 4096
#define NKv 8192
#define CAPv 1280
#define TH2v 5632

typedef unsigned short u16;
typedef __attribute__((ext_vector_type(8))) short s16x8;
typedef __attribute__((ext_vector_type(4))) float f32x4;
typedef __attribute__((ext_vector_type(8))) u16 u16x8;
typedef __attribute__((ext_vector_type(4))) u16 u16x4;

typedef const __attribute__((address_space(1))) void* as1_cvp;
typedef __attribute__((address_space(3))) void* as3_vp;

__device__ __forceinline__ u16 f2bf(float f) {
  unsigned u = __float_as_uint(f);
  u += 0x7fffu + ((u >> 16) & 1u);
  return (u16)(u >> 16);
}
__device__ __forceinline__ float bf2f(u16 h) {
  return __uint_as_float(((unsigned)h) << 16);
}
__device__ __forceinline__ void gload16(const void* g, void* l) {
  __builtin_amdgcn_global_load_lds((as1_cvp)g, (as3_vp)l, 16, 0, 0);
}

// ---------------- router ----------------
__global__ __launch_bounds__(256) void router_kernel(
    const float* __restrict__ x, const float* __restrict__ gw,
    int* __restrict__ tkidx, float* __restrict__ tkprob,
    float* __restrict__ red, float* __restrict__ outIdx)
{
  __shared__ float lred[17];
  int tid = threadIdx.x;
  if (tid < 17) lred[tid] = 0.f;
  __syncthreads();
  int wv = tid >> 6, ln = tid & 63;
  int n = blockIdx.x * 4 + wv;
  float a[8] = {0.f,0.f,0.f,0.f,0.f,0.f,0.f,0.f};
  const float* xr = x + (size_t)n * Dv;
  #pragma unroll
  for (int it = 0; it < 16; ++it) {
    int d = ln + it * 64;
    float xs = xr[d];
    float4 g0 = *(const float4*)(gw + (size_t)d * 8);
    float4 g1 = *(const float4*)(gw + (size_t)d * 8 + 4);
    a[0] += xs * g0.x; a[1] += xs * g0.y; a[2] += xs * g0.z; a[3] += xs * g0.w;
    a[4] += xs * g1.x; a[5] += xs * g1.y; a[6] += xs * g1.z; a[7] += xs * g1.w;
  }
  #pragma unroll
  for (int off = 32; off >= 1; off >>= 1) {
    #pragma unroll
    for (int e = 0; e < 8; ++e) a[e] += __shfl_xor(a[e], off, 64);
  }
  int i1 = 0; float v1 = a[0];
  #pragma unroll
  for (int e = 1; e < 8; ++e) if (a[e] > v1) { v1 = a[e]; i1 = e; }
  int i2 = -1; float v2 = -1e30f;
  #pragma unroll
  for (int e = 0; e < 8; ++e) if (e != i1 && a[e] > v2) { v2 = a[e]; i2 = e; }
  float Z = 0.f;
  #pragma unroll
  for (int e = 0; e < 8; ++e) Z += expf(a[e] - v1);
  float zlse = v1 + logf(Z);
  float t = expf(v2 - v1);
  float p1 = 1.f / (1.f + t);
  float p2 = t * p1;
  if (ln == 0) {
    tkidx[2*n] = i1; tkidx[2*n+1] = i2;
    tkprob[2*n] = p1; tkprob[2*n+1] = p2;
    outIdx[2*n] = (float)i1; outIdx[2*n+1] = (float)i2;
    #pragma unroll
    for (int e = 0; e < 8; ++e) atomicAdd(&lred[e], expf(a[e] - v1) / Z);
    atomicAdd(&lred[8 + i1], 1.f);
    atomicAdd(&lred[16], zlse * zlse);
  }
  __syncthreads();
  if (tid < 17) atomicAdd(&red[tid], lred[tid]);
}

__global__ void aux_kernel(const float* __restrict__ red, float* __restrict__ outAux) {
  float bl = 0.f;
  for (int e = 0; e < 8; ++e) bl += (red[e] / (float)Nv) * (red[8 + e] / (float)Nv);
  bl *= (float)Ev;
  float zl = red[16] / (float)Nv;
  outAux[0] = 0.01f * bl + 0.001f * zl;
}

// ---------------- exact stable rank ----------------
__global__ __launch_bounds__(256) void rank_kernel(const int* __restrict__ tgt,
    int* __restrict__ keep, int* __restrict__ dstNK)
{
  __shared__ int hist[256][8];
  int t = threadIdx.x;
  int h[8] = {0,0,0,0,0,0,0,0};
  int base = t * 32;
  for (int j = 0; j < 32; ++j) h[tgt[base + j]]++;
  for (int e = 0; e < 8; ++e) hist[t][e] = h[e];
  __syncthreads();
  if (t < 8) {
    int run = 0;
    for (int tt = 0; tt < 256; ++tt) { int v = hist[tt][t]; hist[tt][t] = run; run += v; }
  }
  __syncthreads();
  for (int e = 0; e < 8; ++e) h[e] = hist[t][e];
  for (int j = 0; j < 32; ++j) {
    int i = base + j; int e = tgt[i]; int r = h[e]++;
    int kp = (r < CAPv) ? 1 : 0;
    keep[i] = kp;
    if (kp) dstNK[e * CAPv + r] = i;
  }
}

// ---------------- pack ----------------
__global__ __launch_bounds__(256) void pack_kernel(const float* __restrict__ x,
    const int* __restrict__ dstNK, u16* __restrict__ buf)
{
  int s = blockIdx.x * 4 + (threadIdx.x >> 6);
  int ln = threadIdx.x & 63;
  int i = dstNK[s];
  u16* dst = buf + (size_t)s * Dv;
  if (i >= 0) {
    const float* src = x + (size_t)(i >> 1) * Dv;
    #pragma unroll
    for (int j = 0; j < 2; ++j) {
      int d0 = ln * 16 + j * 8;
      float4 v0 = *(const float4*)(src + d0);
      float4 v1 = *(const float4*)(src + d0 + 4);
      u16x8 o;
      o[0]=f2bf(v0.x); o[1]=f2bf(v0.y); o[2]=f2bf(v0.z); o[3]=f2bf(v0.w);
      o[4]=f2bf(v1.x); o[5]=f2bf(v1.y); o[6]=f2bf(v1.z); o[7]=f2bf(v1.w);
      *(u16x8*)(dst + d0) = o;
    }
  } else {
    u16x8 z = {0,0,0,0,0,0,0,0};
    *(u16x8*)(dst + ln * 16) = z;
    *(u16x8*)(dst + ln * 16 + 8) = z;
  }
}

// ---------------- transpose + f32->bf16 ----------------
__global__ __launch_bounds__(256) void tconv_kernel(const float* __restrict__ in,
    u16* __restrict__ out, int R, int C)
{
  __shared__ u16 tile[64][68];
  size_t zoff = (size_t)blockIdx.z * (size_t)R * (size_t)C;
  in += zoff; out += zoff;
  int r0 = blockIdx.y * 64, c0 = blockIdx.x * 64;
  int t = threadIdx.x;
  int cc4 = (t & 15) * 4;
  #pragma unroll
  for (int p = 0; p < 4; ++p) {
    int r = (t >> 4) + p * 16;
    float4 v = *(const float4*)(in + (size_t)(r0 + r) * C + c0 + cc4);
    u16x4 b; b[0]=f2bf(v.x); b[1]=f2bf(v.y); b[2]=f2bf(v.z); b[3]=f2bf(v.w);
    *(u16x4*)(&tile[r][cc4]) = b;
  }
  __syncthreads();
  int rr4 = (t & 15) * 4;
  #pragma unroll
  for (int p = 0; p < 4; ++p) {
    int c = (t >> 4) + p * 16;
    u16x4 o; o[0]=tile[rr4][c]; o[1]=tile[rr4+1][c]; o[2]=tile[rr4+2][c]; o[3]=tile[rr4+3][c];
    *(u16x4*)(out + (size_t)(c0 + c) * R + r0 + rr4) = o;
  }
}

// ===== 256x256 8-wave GEMM, 16x16x32 MFMA, A-dbuf + B-tribuf (2-tile B depth) =====
// LDS: A dbuf [0,64K) ; B tribuf [64K,160K). vmcnt(6) counted waits.
// MODE 0: store bf16  1: SwiGLU  2: scatter via dst  3: gelu + split-K A
template<int MODE>
__global__ __launch_bounds__(512, 2) void gemm256(
    const u16* __restrict__ A, const u16* __restrict__ A2, int splitK,
    const u16* __restrict__ B, void* __restrict__ C,
    const int* __restrict__ dst,
    int Ksz, int lda, int ldb, int ldc, int ntm,
    size_t sA, size_t sB, size_t sC)
{
  __shared__ char smem[163840];
  int e = blockIdx.y;
  int nwgx = gridDim.x;
  int bid0 = blockIdx.x;
  int q = nwgx >> 3, r = nwgx & 7;
  int xcd = bid0 & 7, lo = bid0 >> 3;
  int bid = (xcd < r ? xcd * (q + 1) : r * (q + 1) + (xcd - r) * q) + lo;
  int tm = bid % ntm, tn = bid / ntm;
  const u16* Ae  = A  + (size_t)e * sA;
  const u16* A2e = A2 + (size_t)e * sA;
  const u16* Be  = B  + (size_t)e * sB;
  long long bdelta = (const char*)A2e - (const char*)Ae;
  int tid = threadIdx.x, wv = tid >> 6, ln = tid & 63;
  int wr = wv >> 2, wc = wv & 3;
  int lnl = ln & 15, lnh = ln >> 4;

  // staging source pointers (pre-swizzled global; linear gload_lds dest)
  const char* aP[4]; const char* bP[4];
  int colsw = ((tid & 7) << 4) ^ (((tid >> 3) & 7) << 4);
  #pragma unroll
  for (int i = 0; i < 4; ++i) {
    int row = i * 64 + (tid >> 3);
    aP[i] = (const char*)(Ae + (size_t)(tm * 256 + row) * lda) + colsw;
    int brow;
    if (MODE == 1) {
      int s = row & 63, wcl = row >> 6;
      brow = (s < 32) ? (tn * 128 + wcl * 32 + s) : (Hv + tn * 128 + wcl * 32 + (s - 32));
    } else {
      brow = tn * 256 + row;
    }
    bP[i] = (const char*)(Be + (size_t)brow * ldb) + colsw;
  }

  // fragment LDS byte offsets (round-3 proven conflict-free pattern)
  int arow0 = wr * 128 + lnl;
  int brow0 = wc * 64 + lnl;
  int ksw0 = ((lnh << 4)) ^ ((ln & 7) << 4);
  int ksw1 = (64 + (lnh << 4)) ^ ((ln & 7) << 4);

  auto issueA = [&](int t1, int bsel, int band) {
    int k0 = t1 << 6;
    long long kbA;
    if (MODE == 3 && k0 >= splitK) kbA = bdelta + (long long)(k0 - splitK) * 2;
    else kbA = (long long)k0 * 2;
    gload16(aP[band] + kbA, smem + bsel * 32768 + band * 8192 + (wv << 10));
  };
  auto issueB = [&](int t1, int bsel, int band) {
    long long kbB = (long long)(t1 << 6) * 2;
    gload16(bP[band] + kbB, smem + 65536 + bsel * 32768 + band * 8192 + (wv << 10));
  };

  f32x4 acc[8][4];
  #pragma unroll
  for (int m = 0; m < 8; ++m)
    #pragma unroll
    for (int n = 0; n < 4; ++n) acc[m][n] = (f32x4){0.f, 0.f, 0.f, 0.f};

  int nt = Ksz >> 6;
  // prologue: [B0 x4][A0 b0,b2][A0 b1,b3][B1 x4] -> wait through A0 b0,b2
  issueB(0, 0, 0); issueB(0, 0, 1); issueB(0, 0, 2); issueB(0, 0, 3);
  issueA(0, 0, 0); issueA(0, 0, 2);
  issueA(0, 0, 1); issueA(0, 0, 3);
  issueB(1, 1, 0); issueB(1, 1, 1); issueB(1, 1, 2); issueB(1, 1, 3);
  asm volatile("s_waitcnt vmcnt(6)" ::: "memory");
  __builtin_amdgcn_s_barrier();

  int bcur = 0;
  for (int t = 0; t < nt; ++t) {
    int cur = t & 1;
    const char* sa = smem + cur * 32768;
    const char* sb = smem + 65536 + bcur * 32768;
    int bnx = bcur - 1; if (bnx < 0) bnx = 2;   // (t+2)%3
    bool pfA = (t + 1 < nt), pfB = (t + 2 < nt);

    // tile top: all B fragments (8 ds_read_b128)
    s16x8 bfr[4][2];
    #pragma unroll
    for (int n = 0; n < 4; ++n) {
      bfr[n][0] = *(const s16x8*)(sb + (brow0 + n * 16) * 128 + ksw0);
      bfr[n][1] = *(const s16x8*)(sb + (brow0 + n * 16) * 128 + ksw1);
    }

    #pragma unroll
    for (int p = 0; p < 4; ++p) {
      if (p == 0 && pfA) { issueA(t + 1, cur ^ 1, 0); issueA(t + 1, cur ^ 1, 2); }
      if (p == 2) {
        if (pfA) { issueA(t + 1, cur ^ 1, 1); issueA(t + 1, cur ^ 1, 3); }
        if (pfB) { issueB(t + 2, bnx, 0); issueB(t + 2, bnx, 1);
                   issueB(t + 2, bnx, 2); issueB(t + 2, bnx, 3); }
      }
      s16x8 af0_0 = *(const s16x8*)(sa + (arow0 + (p * 2 + 0) * 16) * 128 + ksw0);
      s16x8 af0_1 = *(const s16x8*)(sa + (arow0 + (p * 2 + 0) * 16) * 128 + ksw1);
      s16x8 af1_0 = *(const s16x8*)(sa + (arow0 + (p * 2 + 1) * 16) * 128 + ksw0);
      s16x8 af1_1 = *(const s16x8*)(sa + (arow0 + (p * 2 + 1) * 16) * 128 + ksw1);
      __builtin_amdgcn_s_barrier();
      asm volatile("s_waitcnt lgkmcnt(0)" ::: "memory");
      __builtin_amdgcn_s_setprio(1);
      #pragma unroll
      for (int n = 0; n < 4; ++n) {
        acc[p*2+0][n] = __builtin_amdgcn_mfma_f32_16x16x32_bf16(af0_0, bfr[n][0], acc[p*2+0][n], 0, 0, 0);
        acc[p*2+0][n] = __builtin_amdgcn_mfma_f32_16x16x32_bf16(af0_1, bfr[n][1], acc[p*2+0][n], 0, 0, 0);
        acc[p*2+1][n] = __builtin_amdgcn_mfma_f32_16x16x32_bf16(af1_0, bfr[n][0], acc[p*2+1][n], 0, 0, 0);
        acc[p*2+1][n] = __builtin_amdgcn_mfma_f32_16x16x32_bf16(af1_1, bfr[n][1], acc[p*2+1][n], 0, 0, 0);
      }
      __builtin_amdgcn_s_setprio(0);
      if (p == 1) {
        // need A(t) bands 1,3 before phases 2-3 read them
        if (pfA) asm volatile("s_waitcnt vmcnt(6)" ::: "memory");
        else     asm volatile("s_waitcnt vmcnt(0)" ::: "memory");
      } else if (p == 3) {
        // boundary: need B(t+1) + A(t+1) bands 0,2
        if (pfB)      asm volatile("s_waitcnt vmcnt(6)" ::: "memory");
        else if (pfA) asm volatile("s_waitcnt vmcnt(2)" ::: "memory");
      }
      __builtin_amdgcn_s_barrier();
    }
    bcur = (bcur == 2) ? 0 : bcur + 1;
  }

  int rb = tm * 256 + wr * 128 + (lnh << 2);
  if (MODE == 0) {
    u16* Cp = (u16*)C;
    #pragma unroll
    for (int m = 0; m < 8; ++m)
      #pragma unroll
      for (int n = 0; n < 4; ++n) {
        int col = tn * 256 + wc * 64 + n * 16 + lnl;
        #pragma unroll
        for (int v = 0; v < 4; ++v)
          Cp[(size_t)(rb + m * 16 + v) * ldc + col] = f2bf(acc[m][n][v]);
      }
  } else if (MODE == 1) {
    u16* Cp = (u16*)C + (size_t)e * sC;
    #pragma unroll
    for (int m = 0; m < 8; ++m)
      #pragma unroll
      for (int n = 0; n < 2; ++n) {
        int col = tn * 128 + wc * 32 + n * 16 + lnl;
        #pragma unroll
        for (int v = 0; v < 4; ++v) {
          float g = acc[m][n][v];
          float u = acc[m][n + 2][v];
          float sg = g / (1.f + __expf(-g));
          Cp[(size_t)(rb + m * 16 + v) * ldc + col] = f2bf(sg * u);
        }
      }
  } else if (MODE == 2) {
    u16* Cp = (u16*)C;
    #pragma unroll
    for (int m = 0; m < 8; ++m)
      #pragma unroll
      for (int v = 0; v < 4; ++v) {
        int gr = rb + m * 16 + v;
        int i = dst[e * CAPv + gr];
        if (i >= 0) {
          #pragma unroll
          for (int n = 0; n < 4; ++n)
            Cp[(size_t)i * Dv + tn * 256 + wc * 64 + n * 16 + lnl] = f2bf(acc[m][n][v]);
        }
      }
  } else {
    u16* Cp = (u16*)C;
    #pragma unroll
    for (int m = 0; m < 8; ++m)
      #pragma unroll
      for (int n = 0; n < 4; ++n) {
        int col = tn * 256 + wc * 64 + n * 16 + lnl;
        #pragma unroll
        for (int v = 0; v < 4; ++v) {
          float xg = acc[m][n][v];
          float gl = 0.5f * xg * (1.f + erff(xg * 0.70710678118654752f));
          Cp[(size_t)(rb + m * 16 + v) * ldc + col] = f2bf(gl);
        }
      }
  }
}

// ---------------- 128x128 GEMM (small final projection, f32 out) ----------------
template<int MODE>
__global__ __launch_bounds__(256) void gemm128(
    const u16* __restrict__ A, const u16* __restrict__ A2, int splitK,
    const u16* __restrict__ B, void* __restrict__ C,
    const int* __restrict__ dst,
    int Ksz, int lda, int ldb, int ldc, int ntm,
    size_t sA, size_t sB, size_t sC)
{
  __shared__ char smem[32768];
  int e = blockIdx.y;
  int bid = blockIdx.x;
  int tm = bid % ntm, tn = bid / ntm;
  const u16* Ae  = A  + (size_t)e * sA;
  const u16* Be  = B  + (size_t)e * sB;
  int tid = threadIdx.x, wv = tid >> 6, ln = tid & 63;

  const char* aP[4]; const char* bP[4];
  unsigned aL[4], bL[4];
  #pragma unroll
  for (int r = 0; r < 4; ++r) {
    int lb = r * 4096 + tid * 16;
    int row = lb >> 7;
    int colb = (lb & 127) ^ ((row & 7) << 4);
    aP[r] = (const char*)(Ae + (size_t)(tm * 128 + row) * lda) + colb;
    bP[r] = (const char*)(Be + (size_t)(tn * 128 + row) * ldb) + colb;
    aL[r] = r * 4096 + wv * 1024;
    bL[r] = 16384 + r * 4096 + wv * 1024;
  }

  f32x4 acc[2][8];
  #pragma unroll
  for (int m = 0; m < 2; ++m)
    #pragma unroll
    for (int n = 0; n < 8; ++n) acc[m][n] = (f32x4){0.f, 0.f, 0.f, 0.f};

  for (int k0 = 0; k0 < Ksz; k0 += 64) {
    size_t kbb = (size_t)k0 * 2;
    #pragma unroll
    for (int r = 0; r < 4; ++r) gload16(aP[r] + kbb, smem + aL[r]);
    #pragma unroll
    for (int r = 0; r < 4; ++r) gload16(bP[r] + kbb, smem + bL[r]);
    __syncthreads();
    #pragma unroll
    for (int ks = 0; ks < 2; ++ks) {
      int kbyte = ks * 64 + ((ln >> 4) << 4);
      s16x8 av[2];
      #pragma unroll
      for (int m = 0; m < 2; ++m) {
        int row = wv * 32 + m * 16 + (ln & 15);
        av[m] = *(const s16x8*)(smem + (row << 7) + (kbyte ^ ((row & 7) << 4)));
      }
      #pragma unroll
      for (int n = 0; n < 8; ++n) {
        int row = n * 16 + (ln & 15);
        s16x8 bv = *(const s16x8*)(smem + 16384 + (row << 7) + (kbyte ^ ((row & 7) << 4)));
        acc[0][n] = __builtin_amdgcn_mfma_f32_16x16x32_bf16(av[0], bv, acc[0][n], 0, 0, 0);
        acc[1][n] = __builtin_amdgcn_mfma_f32_16x16x32_bf16(av[1], bv, acc[1][n], 0, 0, 0);
      }
    }
    __syncthreads();
  }

  int rbase = tm * 128 + wv * 32 + ((ln >> 4) << 2);
  int cb = (ln & 15);
  float* Cp = (float*)C;
  #pragma unroll
  for (int m = 0; m < 2; ++m)
    #pragma unroll
    for (int n = 0; n < 8; ++n)
      #pragma unroll
      for (int v = 0; v < 4; ++v)
        Cp[(size_t)(rbase + m * 16 + v) * ldc + tn * 128 + n * 16 + cb] = acc[m][n][v];
  (void)A2; (void)splitK; (void)dst; (void)sC;
}

// ---------------- per-token scores + masked softmax + Cmsg ----------------
__global__ __launch_bounds__(256) void scores_kernel(
    const u16* __restrict__ MQ, const u16* __restrict__ KK,
    const int* __restrict__ keep, u16* __restrict__ Cmsg)
{
  int wv = threadIdx.x >> 6, ln = threadIdx.x & 63;
  int n = blockIdx.x * 4 + wv;
  const u16* m0 = MQ + (size_t)(2 * n) * 2048;
  const u16* m1 = MQ + (size_t)(2 * n + 1) * 2048;
  const u16* q0 = m0 + 1024;
  const u16* q1 = m1 + 1024;
  const u16* k0p = KK + (size_t)(2 * n) * 1024;
  const u16* k1p = KK + (size_t)(2 * n + 1) * 1024;
  float s00 = 0, s01 = 0, s10 = 0, s11 = 0;
  #pragma unroll
  for (int j = 0; j < 2; ++j) {
    int d0 = ln * 16 + j * 8;
    u16x8 a0 = *(const u16x8*)(q0 + d0);
    u16x8 a1 = *(const u16x8*)(q1 + d0);
    u16x8 b0 = *(const u16x8*)(k0p + d0);
    u16x8 b1 = *(const u16x8*)(k1p + d0);
    #pragma unroll
    for (int t = 0; t < 8; ++t) {
      float fa0 = bf2f(a0[t]), fa1 = bf2f(a1[t]);
      float fb0 = bf2f(b0[t]), fb1 = bf2f(b1[t]);
      s00 += fa0 * fb0; s01 += fa0 * fb1; s10 += fa1 * fb0; s11 += fa1 * fb1;
    }
  }
  #pragma unroll
  for (int off = 32; off >= 1; off >>= 1) {
    s00 += __shfl_xor(s00, off, 64);
    s01 += __shfl_xor(s01, off, 64);
    s10 += __shfl_xor(s10, off, 64);
    s11 += __shfl_xor(s11, off, 64);
  }
  const float inv = 0.03125f;
  int kp0 = keep[2 * n], kp1 = keep[2 * n + 1];
  float A00, A01, A10, A11;
  {
    float v0 = kp0 ? s00 * inv : -1e9f;
    float v1 = (kp0 && kp1) ? s01 * inv : -1e9f;
    float mx = fmaxf(v0, v1);
    float e0 = expf(v0 - mx), e1 = expf(v1 - mx);
    float den = e0 + e1;
    float a0 = kp0 ? e0 / den : 0.f;
    float a1 = (kp0 && kp1) ? e1 / den : 0.f;
    float s = fmaxf(a0 + a1, 1e-12f);
    A00 = a0 / s; A01 = a1 / s;
  }
  {
    float v0 = (kp1 && kp0) ? s10 * inv : -1e9f;
    float v1 = kp1 ? s11 * inv : -1e9f;
    float mx = fmaxf(v0, v1);
    float e0 = expf(v0 - mx), e1 = expf(v1 - mx);
    float den = e0 + e1;
    float a0 = (kp1 && kp0) ? e0 / den : 0.f;
    float a1 = kp1 ? e1 / den : 0.f;
    float s = fmaxf(a0 + a1, 1e-12f);
    A10 = a0 / s; A11 = a1 / s;
  }
  u16* c0 = Cmsg + (size_t)(2 * n) * 1024;
  u16* c1 = Cmsg + (size_t)(2 * n + 1) * 1024;
  #pragma unroll
  for (int j = 0; j < 2; ++j) {
    int d0 = ln * 16 + j * 8;
    u16x8 x0 = *(const u16x8*)(m0 + d0);
    u16x8 x1 = *(const u16x8*)(m1 + d0);
    u16x8 o0, o1;
    #pragma unroll
    for (int t = 0; t < 8; ++t) {
      float f0 = bf2f(x0[t]), f1 = bf2f(x1[t]);
      o0[t] = f2bf(A00 * f0 + A01 * f1);
      o1[t] = f2bf(A10 * f0 + A11 * f1);
    }
    *(u16x8*)(c0 + d0) = o0;
    *(u16x8*)(c1 + d0) = o1;
  }
}

// ---------------- combine ----------------
__global__ __launch_bounds__(256) void combine_kernel(
    const u16* __restrict__ sel, const u16* __restrict__ upd,
    const int* __restrict__ keep, const float* __restrict__ tkprob,
    u16* __restrict__ fusedp)
{
  int n = blockIdx.x;
  int t = threadIdx.x;
  float kp0 = keep[2 * n] ? 1.f : 0.f, kp1 = keep[2 * n + 1] ? 1.f : 0.f;
  float p0 = tkprob[2 * n] * kp0, p1 = tkprob[2 * n + 1] * kp1;
  float s = fmaxf(p0 + p1, 1e-12f);
  float w0 = p0 / s, w1 = p1 / s;
  int d0 = t * 4;
  u16x4 s0 = *(const u16x4*)(sel + (size_t)(2 * n) * Dv + d0);
  u16x4 s1 = *(const u16x4*)(sel + (size_t)(2 * n + 1) * Dv + d0);
  u16x4 u0 = *(const u16x4*)(upd + (size_t)(2 * n) * Dv + d0);
  u16x4 u1 = *(const u16x4*)(upd + (size_t)(2 * n + 1) * Dv + d0);
  u16x4 o;
  #pragma unroll
  for (int j = 0; j < 4; ++j) {
    float r0 = (bf2f(s0[j]) + bf2f(u0[j])) * kp0;
    float r1 = (bf2f(s1[j]) + bf2f(u1[j])) * kp1;
    o[j] = f2bf(w0 * r0 + w1 * r1);
  }
  *(u16x4*)(fusedp + (size_t)n * Dv + d0) = o;
}

extern "C" void kernel_launch(void* const* d_in, const int* in_sizes, int n_in,
                              void* d_out, int out_size, void* d_ws, size_t ws_size,
                              hipStream_t stream) {
  const float* x      = (const float*)d_in[0];
  const float* gate_w = (const float*)d_in[1];
  const float* w13    = (const float*)d_in[2];
  const float* w2     = (const float*)d_in[3];
  const float* msg_w  = (const float*)d_in[4];
  const float* q_w    = (const float*)d_in[5];
  const float* k_w    = (const float*)d_in[6];
  const float* upd_w1 = (const float*)d_in[7];
  const float* upd_w2 = (const float*)d_in[8];
  const float* o_w    = (const float*)d_in[9];
  float* out = (float*)d_out;
  float* outAux = out + (size_t)Nv * Dv;
  float* outIdx = outAux + 1;

  char* ws = (char*)d_ws;
  const size_t MBc = 1ull << 20;
  int*   tkidx  = (int*)(ws + 0);
  float* tkprob = (float*)(ws + 32768);
  int*   keepA  = (int*)(ws + 65536);
  int*   dstNK  = (int*)(ws + 98304);
  float* red    = (float*)(ws + 143360);
  // phase A:
  u16* BUF   = (u16*)(ws + 1 * MBc);
  u16* ACT   = (u16*)(ws + 21 * MBc);
  u16* W13B  = (u16*)(ws + 76 * MBc);
  u16* W2B   = (u16*)(ws + 76 * MBc);
  u16* SEL   = (u16*)(ws + 120 * MBc);
  u16* MSGQB = (u16*)(ws + 136 * MBc);
  u16* KB    = (u16*)(ws + 140 * MBc);
  u16* OB    = (u16*)(ws + 142 * MBc);
  u16* UPD1B = (u16*)(ws + 144 * MBc);
  u16* UPD2B = (u16*)(ws + 152 * MBc);
  // phase B:
  u16* MQ    = (u16*)(ws + 1 * MBc);
  u16* KKb   = (u16*)(ws + 33 * MBc);
  u16* CMSG  = (u16*)(ws + 49 * MBc);
  u16* G1B   = (u16*)(ws + 65 * MBc);
  u16* UPD   = (u16*)(ws + 97 * MBc);
  u16* FUSEDP= (u16*)(ws + 1 * MBc);

  hipMemsetAsync(red, 0, 68, stream);
  hipMemsetAsync(dstNK, 0xFF, Ev * CAPv * 4, stream);

  router_kernel<<<Nv / 4, 256, 0, stream>>>(x, gate_w, tkidx, tkprob, red, outIdx);
  aux_kernel<<<1, 1, 0, stream>>>(red, outAux);
  rank_kernel<<<1, 256, 0, stream>>>(tkidx, keepA, dstNK);
  pack_kernel<<<(Ev * CAPv) / 4, 256, 0, stream>>>(x, dstNK, BUF);

  // G1: convert all w13, one batched SwiGLU GEMM
  tconv_kernel<<<dim3(TH2v / 64, Dv / 64, Ev), 256, 0, stream>>>(w13, W13B, Dv, TH2v);
  gemm256<1><<<dim3((CAPv / 256) * (Hv / 128), Ev), 512, 0, stream>>>(
      BUF, BUF, 1 << 30, W13B, (void*)ACT, nullptr,
      Dv, Dv, Dv, Hv, CAPv / 256, (size_t)CAPv * Dv, (size_t)TH2v * Dv, (size_t)CAPv * Hv);

  hipMemsetAsync(SEL, 0, (size_t)NKv * Dv * 2, stream);
  tconv_kernel<<<dim3(Dv / 64, Hv / 64, Ev), 256, 0, stream>>>(w2, W2B, Hv, Dv);
  tconv_kernel<<<dim3(16, 16, 1), 256, 0, stream>>>(msg_w, MSGQB, Dv, Dv);
  tconv_kernel<<<dim3(16, 16, 1), 256, 0, stream>>>(q_w, MSGQB + (size_t)Dv * Dv, Dv, Dv);
  tconv_kernel<<<dim3(16, 16, 1), 256, 0, stream>>>(k_w, KB, Dv, Dv);
  tconv_kernel<<<dim3(16, 16, 1), 256, 0, stream>>>(o_w, OB, Dv, Dv);
  tconv_kernel<<<dim3(32, 32, 1), 256, 0, stream>>>(upd_w1, UPD1B, 2048, 2048);
  tconv_kernel<<<dim3(16, 32, 1), 256, 0, stream>>>(upd_w2, UPD2B, 2048, Dv);

  // G2: GEMM + scatter into SEL
  gemm256<2><<<dim3((CAPv / 256) * (Dv / 256), Ev), 512, 0, stream>>>(
      ACT, ACT, 1 << 30, W2B, (void*)SEL, dstNK,
      Hv, Hv, Hv, Dv, CAPv / 256, (size_t)CAPv * Hv, (size_t)Dv * Hv, 0);

  // collaboration: fused [M|Q] GEMM, then Kk GEMM, then scores
  gemm256<0><<<dim3(32 * 8, 1), 512, 0, stream>>>(SEL, SEL, 1 << 30, MSGQB, (void*)MQ, nullptr,
      Dv, Dv, Dv, 2048, 32, 0, 0, 0);
  gemm256<0><<<dim3(32 * 4, 1), 512, 0, stream>>>(MQ, MQ, 1 << 30, KB, (void*)KKb, nullptr,
      Dv, 2048, Dv, Dv, 32, 0, 0, 0);
  scores_kernel<<<Nv / 4, 256, 0, stream>>>(MQ, KKb, keepA, CMSG);

  // update MLP: cat = [SEL | CMSG] via split-K A, gelu fused
  gemm256<3><<<dim3(32 * 8, 1), 512, 0, stream>>>(SEL, CMSG, Dv, UPD1B, (void*)G1B, nullptr,
      2048, Dv, 2048, 2048, 32, 0, 0, 0);
  gemm256<0><<<dim3(32 * 4, 1), 512, 0, stream>>>(G1B, G1B, 1 << 30, UPD2B, (void*)UPD, nullptr,
      2048, 2048, 2048, Dv, 32, 0, 0, 0);

  combine_kernel<<<Nv, 256, 0, stream>>>(SEL, UPD, keepA, tkprob, FUSEDP);

  gemm128<4><<<dim3(32 * 8, 1), 256, 0, stream>>>(FUSEDP, FUSEDP, Dv, OB, (void*)out, nullptr,
      Dv, Dv, Dv, Dv, 32, 0, 0, 0);

  (void)in_sizes; (void)n_in; (void)out_size; (void)ws_size;
}

// Round 6
// 569.550 us; speedup vs baseline: 1.1813x; 1.1366x over previous
//
#include <hip/hip_runtime.h>
#include <math.h>

#define Dv 1024
#define Ev 8
#define Hv 2816
#define Nv 4096
#define NKv 8192
#define CAPv 1280
#define TH2v 5632

typedef unsigned short u16;
typedef unsigned char u8;
typedef __attribute__((ext_vector_type(8))) short s16x8;
typedef __attribute__((ext_vector_type(4))) float f32x4;
typedef __attribute__((ext_vector_type(4))) int i32x4;
typedef __attribute__((ext_vector_type(8))) int i32x8;
typedef __attribute__((ext_vector_type(8))) u16 u16x8;
typedef __attribute__((ext_vector_type(4))) u16 u16x4;

typedef const __attribute__((address_space(1))) void* as1_cvp;
typedef __attribute__((address_space(3))) void* as3_vp;

__device__ __forceinline__ u16 f2bf(float f) {
  unsigned u = __float_as_uint(f);
  u += 0x7fffu + ((u >> 16) & 1u);
  return (u16)(u >> 16);
}
__device__ __forceinline__ float bf2f(u16 h) {
  return __uint_as_float(((unsigned)h) << 16);
}
// f32 -> OCP e4m3fn, RNE, saturate to 448
__device__ __forceinline__ unsigned f2e4(float f) {
  unsigned u = __float_as_uint(f);
  unsigned sgn = (u >> 24) & 0x80u;
  unsigned ax = u & 0x7FFFFFFFu;
  if (ax >= 0x43E00000u) return sgn | 0x7Eu;           // |x| >= 448
  if (ax < 0x3C800000u) {                              // |x| < 2^-6: subnormal
    int qv = (int)rintf(__uint_as_float(ax) * 512.f);  // units of 2^-9
    return sgn | (unsigned)qv;                         // 8 == 2^-6 normal, ok
  }
  unsigned lsb = (ax >> 20) & 1u;
  unsigned rr = ax + 0x0007FFFFu + lsb;                // RNE at bit 20
  unsigned ee = rr >> 23;
  unsigned mm = (rr >> 20) & 7u;
  if (ee > 135u) return sgn | 0x7Eu;
  return sgn | ((ee - 120u) << 3) | mm;
}
__device__ __forceinline__ void gload16(const void* g, void* l) {
  __builtin_amdgcn_global_load_lds((as1_cvp)g, (as3_vp)l, 16, 0, 0);
}

// ---------------- router ----------------
__global__ __launch_bounds__(256) void router_kernel(
    const float* __restrict__ x, const float* __restrict__ gw,
    int* __restrict__ tkidx, float* __restrict__ tkprob,
    float* __restrict__ red, float* __restrict__ outIdx)
{
  __shared__ float lred[17];
  int tid = threadIdx.x;
  if (tid < 17) lred[tid] = 0.f;
  __syncthreads();
  int wv = tid >> 6, ln = tid & 63;
  int n = blockIdx.x * 4 + wv;
  float a[8] = {0.f,0.f,0.f,0.f,0.f,0.f,0.f,0.f};
  const float* xr = x + (size_t)n * Dv;
  #pragma unroll
  for (int it = 0; it < 16; ++it) {
    int d = ln + it * 64;
    float xs = xr[d];
    float4 g0 = *(const float4*)(gw + (size_t)d * 8);
    float4 g1 = *(const float4*)(gw + (size_t)d * 8 + 4);
    a[0] += xs * g0.x; a[1] += xs * g0.y; a[2] += xs * g0.z; a[3] += xs * g0.w;
    a[4] += xs * g1.x; a[5] += xs * g1.y; a[6] += xs * g1.z; a[7] += xs * g1.w;
  }
  #pragma unroll
  for (int off = 32; off >= 1; off >>= 1) {
    #pragma unroll
    for (int e = 0; e < 8; ++e) a[e] += __shfl_xor(a[e], off, 64);
  }
  int i1 = 0; float v1 = a[0];
  #pragma unroll
  for (int e = 1; e < 8; ++e) if (a[e] > v1) { v1 = a[e]; i1 = e; }
  int i2 = -1; float v2 = -1e30f;
  #pragma unroll
  for (int e = 0; e < 8; ++e) if (e != i1 && a[e] > v2) { v2 = a[e]; i2 = e; }
  float Z = 0.f;
  #pragma unroll
  for (int e = 0; e < 8; ++e) Z += expf(a[e] - v1);
  float zlse = v1 + logf(Z);
  float t = expf(v2 - v1);
  float p1 = 1.f / (1.f + t);
  float p2 = t * p1;
  if (ln == 0) {
    tkidx[2*n] = i1; tkidx[2*n+1] = i2;
    tkprob[2*n] = p1; tkprob[2*n+1] = p2;
    outIdx[2*n] = (float)i1; outIdx[2*n+1] = (float)i2;
    #pragma unroll
    for (int e = 0; e < 8; ++e) atomicAdd(&lred[e], expf(a[e] - v1) / Z);
    atomicAdd(&lred[8 + i1], 1.f);
    atomicAdd(&lred[16], zlse * zlse);
  }
  __syncthreads();
  if (tid < 17) atomicAdd(&red[tid], lred[tid]);
}

__global__ void aux_kernel(const float* __restrict__ red, float* __restrict__ outAux) {
  float bl = 0.f;
  for (int e = 0; e < 8; ++e) bl += (red[e] / (float)Nv) * (red[8 + e] / (float)Nv);
  bl *= (float)Ev;
  float zl = red[16] / (float)Nv;
  outAux[0] = 0.01f * bl + 0.001f * zl;
}

// ---------------- exact stable rank ----------------
__global__ __launch_bounds__(256) void rank_kernel(const int* __restrict__ tgt,
    int* __restrict__ keep, int* __restrict__ dstNK)
{
  __shared__ int hist[256][8];
  int t = threadIdx.x;
  int h[8] = {0,0,0,0,0,0,0,0};
  int base = t * 32;
  for (int j = 0; j < 32; ++j) h[tgt[base + j]]++;
  for (int e = 0; e < 8; ++e) hist[t][e] = h[e];
  __syncthreads();
  if (t < 8) {
    int run = 0;
    for (int tt = 0; tt < 256; ++tt) { int v = hist[tt][t]; hist[tt][t] = run; run += v; }
  }
  __syncthreads();
  for (int e = 0; e < 8; ++e) h[e] = hist[t][e];
  for (int j = 0; j < 32; ++j) {
    int i = base + j; int e = tgt[i]; int r = h[e]++;
    int kp = (r < CAPv) ? 1 : 0;
    keep[i] = kp;
    if (kp) dstNK[e * CAPv + r] = i;
  }
}

// ---------------- pack tokens -> fp8 ----------------
__global__ __launch_bounds__(256) void pack8_kernel(const float* __restrict__ x,
    const int* __restrict__ dstNK, u8* __restrict__ buf)
{
  int s = blockIdx.x * 4 + (threadIdx.x >> 6);
  int ln = threadIdx.x & 63;
  int i = dstNK[s];
  u8* dst = buf + (size_t)s * Dv;
  if (i >= 0) {
    const float* src = x + (size_t)(i >> 1) * Dv;
    #pragma unroll
    for (int j = 0; j < 4; ++j) {
      int d0 = ln * 16 + j * 4;
      float4 v = *(const float4*)(src + d0);
      unsigned w = f2e4(v.x) | (f2e4(v.y) << 8) | (f2e4(v.z) << 16) | (f2e4(v.w) << 24);
      *(unsigned*)(dst + d0) = w;
    }
  } else {
    #pragma unroll
    for (int j = 0; j < 4; ++j) *(unsigned*)(dst + ln * 16 + j * 4) = 0u;
  }
}

// ---------------- transpose + f32->bf16 ----------------
__global__ __launch_bounds__(256) void tconv_kernel(const float* __restrict__ in,
    u16* __restrict__ out, int R, int C)
{
  __shared__ u16 tile[64][68];
  size_t zoff = (size_t)blockIdx.z * (size_t)R * (size_t)C;
  in += zoff; out += zoff;
  int r0 = blockIdx.y * 64, c0 = blockIdx.x * 64;
  int t = threadIdx.x;
  int cc4 = (t & 15) * 4;
  #pragma unroll
  for (int p = 0; p < 4; ++p) {
    int r = (t >> 4) + p * 16;
    float4 v = *(const float4*)(in + (size_t)(r0 + r) * C + c0 + cc4);
    u16x4 b; b[0]=f2bf(v.x); b[1]=f2bf(v.y); b[2]=f2bf(v.z); b[3]=f2bf(v.w);
    *(u16x4*)(&tile[r][cc4]) = b;
  }
  __syncthreads();
  int rr4 = (t & 15) * 4;
  #pragma unroll
  for (int p = 0; p < 4; ++p) {
    int c = (t >> 4) + p * 16;
    u16x4 o; o[0]=tile[rr4][c]; o[1]=tile[rr4+1][c]; o[2]=tile[rr4+2][c]; o[3]=tile[rr4+3][c];
    *(u16x4*)(out + (size_t)(c0 + c) * R + r0 + rr4) = o;
  }
}

// ---------------- transpose + f32->e4m3 (xsmul) ----------------
__global__ __launch_bounds__(256) void tconv8_kernel(const float* __restrict__ in,
    u8* __restrict__ out, int R, int C, float smul)
{
  __shared__ u8 tile[64][68];
  size_t zoff = (size_t)blockIdx.z * (size_t)R * (size_t)C;
  in += zoff; out += zoff;
  int r0 = blockIdx.y * 64, c0 = blockIdx.x * 64;
  int t = threadIdx.x;
  int cc4 = (t & 15) * 4;
  #pragma unroll
  for (int p = 0; p < 4; ++p) {
    int r = (t >> 4) + p * 16;
    float4 v = *(const float4*)(in + (size_t)(r0 + r) * C + c0 + cc4);
    unsigned w = f2e4(v.x * smul) | (f2e4(v.y * smul) << 8)
               | (f2e4(v.z * smul) << 16) | (f2e4(v.w * smul) << 24);
    *(unsigned*)(&tile[r][cc4]) = w;
  }
  __syncthreads();
  int rr4 = (t & 15) * 4;
  #pragma unroll
  for (int p = 0; p < 4; ++p) {
    int c = (t >> 4) + p * 16;
    unsigned w = (unsigned)tile[rr4][c] | ((unsigned)tile[rr4+1][c] << 8)
               | ((unsigned)tile[rr4+2][c] << 16) | ((unsigned)tile[rr4+3][c] << 24);
    *(unsigned*)(out + (size_t)(c0 + c) * R + r0 + rr4) = w;
  }
}

// ===== 256x256 8-wave MX-fp8 GEMM, 16x16x128 scaled MFMA, BK=128, dbuf =====
// Strides in BYTES (== fp8 elems). MODE 1: SwiGLU -> fp8 out. MODE 2: scatter -> bf16.
template<int MODE>
__global__ __launch_bounds__(512, 2) void gemm256f8(
    const u8* __restrict__ A, const u8* __restrict__ B, void* __restrict__ C,
    const int* __restrict__ dst, int Ksz, int lda, int ldb, int ldc, int ntm,
    size_t sA, size_t sB, size_t sC, unsigned sclB)
{
  __shared__ char smem[131072];  // A dbuf [0,64K), B dbuf [64K,128K)
  int e = blockIdx.y;
  int nwgx = gridDim.x, bid0 = blockIdx.x;
  int q = nwgx >> 3, r = nwgx & 7;
  int xcd = bid0 & 7, lo2 = bid0 >> 3;
  int bid = (xcd < r ? xcd * (q + 1) : r * (q + 1) + (xcd - r) * q) + lo2;
  int tm = bid % ntm, tn = bid / ntm;
  const u8* Ae = A + (size_t)e * sA;
  const u8* Be = B + (size_t)e * sB;
  int tid = threadIdx.x, wv = tid >> 6, ln = tid & 63;
  int wr = wv >> 2, wc = wv & 3;
  int lnl = ln & 15, lnh = ln >> 4;

  const u8* aP[4]; const u8* bP[4];
  int colsw = ((tid & 7) << 4) ^ (((tid >> 3) & 7) << 4);
  #pragma unroll
  for (int i = 0; i < 4; ++i) {
    int row = i * 64 + (tid >> 3);
    aP[i] = Ae + (size_t)(tm * 256 + row) * lda + colsw;
    int brow;
    if (MODE == 1) {
      int s = row & 63, wcl = row >> 6;
      brow = (s < 32) ? (tn * 128 + wcl * 32 + s) : (Hv + tn * 128 + wcl * 32 + (s - 32));
    } else {
      brow = tn * 256 + row;
    }
    bP[i] = Be + (size_t)brow * ldb + colsw;
  }

  int arow0 = wr * 128 + lnl;
  int brow0 = wc * 64 + lnl;

  auto issueA = [&](int t1, int bsel, int band) {
    gload16(aP[band] + (size_t)t1 * 128, smem + bsel * 32768 + band * 8192 + (wv << 10));
  };
  auto issueB = [&](int t1, int bsel, int band) {
    gload16(bP[band] + (size_t)t1 * 128, smem + 65536 + bsel * 32768 + band * 8192 + (wv << 10));
  };

  f32x4 acc[8][4];
  #pragma unroll
  for (int m = 0; m < 8; ++m)
    #pragma unroll
    for (int n = 0; n < 4; ++n) acc[m][n] = (f32x4){0.f, 0.f, 0.f, 0.f};

  int nt = Ksz >> 7;
  issueB(0, 0, 0); issueB(0, 0, 1); issueB(0, 0, 2); issueB(0, 0, 3);
  issueA(0, 0, 0); issueA(0, 0, 2); issueA(0, 0, 1); issueA(0, 0, 3);
  asm volatile("s_waitcnt vmcnt(2)" ::: "memory");  // B all + A bands 0,2
  __builtin_amdgcn_s_barrier();

  for (int t = 0; t < nt; ++t) {
    int cur = t & 1;
    const char* sa = smem + cur * 32768;
    const char* sb = smem + 65536 + cur * 32768;
    bool pf = (t + 1 < nt);

    // all B fragments: 16-row span, lnh slot spread (r3 conflict-free pattern)
    i32x8 bf[4];
    #pragma unroll
    for (int n = 0; n < 4; ++n) {
      int row = brow0 + n * 16;
      int swz = (row & 7) << 4;
      i32x4 lo = *(const i32x4*)(sb + row * 128 + ((lnh << 5) ^ swz));
      i32x4 hi = *(const i32x4*)(sb + row * 128 + (((lnh << 5) + 16) ^ swz));
      bf[n][0]=lo[0]; bf[n][1]=lo[1]; bf[n][2]=lo[2]; bf[n][3]=lo[3];
      bf[n][4]=hi[0]; bf[n][5]=hi[1]; bf[n][6]=hi[2]; bf[n][7]=hi[3];
    }

    #pragma unroll
    for (int h = 0; h < 2; ++h) {
      if (pf) {
        if (h == 0) { issueB(t + 1, cur ^ 1, 0); issueB(t + 1, cur ^ 1, 1);
                      issueB(t + 1, cur ^ 1, 2); issueB(t + 1, cur ^ 1, 3); }
        else        { issueA(t + 1, cur ^ 1, 0); issueA(t + 1, cur ^ 1, 2);
                      issueA(t + 1, cur ^ 1, 1); issueA(t + 1, cur ^ 1, 3); }
      }
      i32x8 af[4];
      #pragma unroll
      for (int mi = 0; mi < 4; ++mi) {
        int row = arow0 + (h * 4 + mi) * 16;
        int swz = (row & 7) << 4;
        i32x4 lo = *(const i32x4*)(sa + row * 128 + ((lnh << 5) ^ swz));
        i32x4 hi = *(const i32x4*)(sa + row * 128 + (((lnh << 5) + 16) ^ swz));
        af[mi][0]=lo[0]; af[mi][1]=lo[1]; af[mi][2]=lo[2]; af[mi][3]=lo[3];
        af[mi][4]=hi[0]; af[mi][5]=hi[1]; af[mi][6]=hi[2]; af[mi][7]=hi[3];
      }
      __builtin_amdgcn_s_barrier();
      asm volatile("s_waitcnt lgkmcnt(0)" ::: "memory");
      __builtin_amdgcn_s_setprio(1);
      #pragma unroll
      for (int mi = 0; mi < 4; ++mi)
        #pragma unroll
        for (int n = 0; n < 4; ++n)
          acc[h*4+mi][n] = __builtin_amdgcn_mfma_scale_f32_16x16x128_f8f6f4(
              af[mi], bf[n], acc[h*4+mi][n], 0, 0, 0, 0x7F7F7F7Fu, 0, sclB);
      __builtin_amdgcn_s_setprio(0);
      if (h == 0) {
        if (pf) asm volatile("s_waitcnt vmcnt(4)" ::: "memory");   // A(t) b1,b3 in
        else    asm volatile("s_waitcnt vmcnt(0)" ::: "memory");
      } else {
        if (pf) asm volatile("s_waitcnt vmcnt(2)" ::: "memory");   // B(t+1)+A(t+1)b0,2 in
      }
      __builtin_amdgcn_s_barrier();
    }
  }

  int rb = tm * 256 + wr * 128 + (lnh << 2);
  if (MODE == 1) {
    u8* Cp = (u8*)C + (size_t)e * sC;
    #pragma unroll
    for (int m = 0; m < 8; ++m)
      #pragma unroll
      for (int n = 0; n < 2; ++n) {
        int col = tn * 128 + wc * 32 + n * 16 + lnl;
        #pragma unroll
        for (int v = 0; v < 4; ++v) {
          float g = acc[m][n][v];
          float u = acc[m][n + 2][v];
          float sg = g / (1.f + __expf(-g));
          Cp[(size_t)(rb + m * 16 + v) * ldc + col] = (u8)f2e4(sg * u);
        }
      }
  } else {
    u16* Cp = (u16*)C;
    #pragma unroll
    for (int m = 0; m < 8; ++m)
      #pragma unroll
      for (int v = 0; v < 4; ++v) {
        int gr = rb + m * 16 + v;
        int i = dst[e * CAPv + gr];
        if (i >= 0) {
          #pragma unroll
          for (int n = 0; n < 4; ++n)
            Cp[(size_t)i * Dv + tn * 256 + wc * 64 + n * 16 + lnl] = f2bf(acc[m][n][v]);
        }
      }
  }
}

// ===== 256x256 8-wave bf16 GEMM (round-3 schedule), BK=64, dbuf =====
// MODE 0: store bf16  3: gelu + split-K A
template<int MODE>
__global__ __launch_bounds__(512, 2) void gemm256(
    const u16* __restrict__ A, const u16* __restrict__ A2, int splitK,
    const u16* __restrict__ B, void* __restrict__ C,
    int Ksz, int lda, int ldb, int ldc, int ntm)
{
  __shared__ char smem[131072];
  int nwgx = gridDim.x, bid0 = blockIdx.x;
  int q = nwgx >> 3, r = nwgx & 7;
  int xcd = bid0 & 7, lo2 = bid0 >> 3;
  int bid = (xcd < r ? xcd * (q + 1) : r * (q + 1) + (xcd - r) * q) + lo2;
  int tm = bid % ntm, tn = bid / ntm;
  long long bdelta = (const char*)A2 - (const char*)A;
  int tid = threadIdx.x, wv = tid >> 6, ln = tid & 63;
  int wr = wv >> 2, wc = wv & 3;
  int lnl = ln & 15, lnh = ln >> 4;

  const char* aP[4]; const char* bP[4];
  int colsw = ((tid & 7) << 4) ^ (((tid >> 3) & 7) << 4);
  #pragma unroll
  for (int i = 0; i < 4; ++i) {
    int row = i * 64 + (tid >> 3);
    aP[i] = (const char*)(A + (size_t)(tm * 256 + row) * lda) + colsw;
    bP[i] = (const char*)(B + (size_t)(tn * 256 + row) * ldb) + colsw;
  }

  int arow0 = wr * 128 + lnl;
  int brow0 = wc * 64 + lnl;
  int ksw0 = ((lnh << 4)) ^ ((ln & 7) << 4);
  int ksw1 = (64 + (lnh << 4)) ^ ((ln & 7) << 4);

  auto issueA = [&](int t1, int bsel, int band) {
    int k0 = t1 << 6;
    long long kbA;
    if (MODE == 3 && k0 >= splitK) kbA = bdelta + (long long)(k0 - splitK) * 2;
    else kbA = (long long)k0 * 2;
    gload16(aP[band] + kbA, smem + bsel * 32768 + band * 8192 + (wv << 10));
  };
  auto issueB = [&](int t1, int bsel, int band) {
    long long kbB = (long long)(t1 << 6) * 2;
    gload16(bP[band] + kbB, smem + 65536 + bsel * 32768 + band * 8192 + (wv << 10));
  };

  f32x4 acc[8][4];
  #pragma unroll
  for (int m = 0; m < 8; ++m)
    #pragma unroll
    for (int n = 0; n < 4; ++n) acc[m][n] = (f32x4){0.f, 0.f, 0.f, 0.f};

  int nt = Ksz >> 6;
  issueB(0, 0, 0); issueB(0, 0, 1); issueB(0, 0, 2); issueB(0, 0, 3);
  issueA(0, 0, 0); issueA(0, 0, 2); issueA(0, 0, 1); issueA(0, 0, 3);
  asm volatile("s_waitcnt vmcnt(2)" ::: "memory");
  __builtin_amdgcn_s_barrier();

  for (int t = 0; t < nt; ++t) {
    int cur = t & 1;
    int nb = cur ^ 1;
    const char* sa = smem + cur * 32768;
    const char* sb = smem + 65536 + cur * 32768;
    bool pf = (t + 1 < nt);

    s16x8 bfr[4][2];
    #pragma unroll
    for (int n = 0; n < 4; ++n) {
      bfr[n][0] = *(const s16x8*)(sb + (brow0 + n * 16) * 128 + ksw0);
      bfr[n][1] = *(const s16x8*)(sb + (brow0 + n * 16) * 128 + ksw1);
    }

    #pragma unroll
    for (int p = 0; p < 4; ++p) {
      if (pf) {
        if (p == 0)      { issueB(t + 1, nb, 0); issueB(t + 1, nb, 1); }
        else if (p == 1) { issueB(t + 1, nb, 2); issueB(t + 1, nb, 3); }
        else if (p == 2) { issueA(t + 1, nb, 0); issueA(t + 1, nb, 2); }
        else             { issueA(t + 1, nb, 1); issueA(t + 1, nb, 3); }
      }
      s16x8 af0_0 = *(const s16x8*)(sa + (arow0 + (p * 2 + 0) * 16) * 128 + ksw0);
      s16x8 af0_1 = *(const s16x8*)(sa + (arow0 + (p * 2 + 0) * 16) * 128 + ksw1);
      s16x8 af1_0 = *(const s16x8*)(sa + (arow0 + (p * 2 + 1) * 16) * 128 + ksw0);
      s16x8 af1_1 = *(const s16x8*)(sa + (arow0 + (p * 2 + 1) * 16) * 128 + ksw1);
      __builtin_amdgcn_s_barrier();
      asm volatile("s_waitcnt lgkmcnt(0)" ::: "memory");
      __builtin_amdgcn_s_setprio(1);
      #pragma unroll
      for (int n = 0; n < 4; ++n) {
        acc[p*2+0][n] = __builtin_amdgcn_mfma_f32_16x16x32_bf16(af0_0, bfr[n][0], acc[p*2+0][n], 0, 0, 0);
        acc[p*2+0][n] = __builtin_amdgcn_mfma_f32_16x16x32_bf16(af0_1, bfr[n][1], acc[p*2+0][n], 0, 0, 0);
        acc[p*2+1][n] = __builtin_amdgcn_mfma_f32_16x16x32_bf16(af1_0, bfr[n][0], acc[p*2+1][n], 0, 0, 0);
        acc[p*2+1][n] = __builtin_amdgcn_mfma_f32_16x16x32_bf16(af1_1, bfr[n][1], acc[p*2+1][n], 0, 0, 0);
      }
      __builtin_amdgcn_s_setprio(0);
      if (p == 1) {
        if (pf) asm volatile("s_waitcnt vmcnt(4)" ::: "memory");
        else    asm volatile("s_waitcnt vmcnt(0)" ::: "memory");
      } else if (p == 3) {
        if (pf) asm volatile("s_waitcnt vmcnt(2)" ::: "memory");
      }
      __builtin_amdgcn_s_barrier();
    }
  }

  int rb = tm * 256 + wr * 128 + (lnh << 2);
  if (MODE == 0) {
    u16* Cp = (u16*)C;
    #pragma unroll
    for (int m = 0; m < 8; ++m)
      #pragma unroll
      for (int n = 0; n < 4; ++n) {
        int col = tn * 256 + wc * 64 + n * 16 + lnl;
        #pragma unroll
        for (int v = 0; v < 4; ++v)
          Cp[(size_t)(rb + m * 16 + v) * ldc + col] = f2bf(acc[m][n][v]);
      }
  } else {
    u16* Cp = (u16*)C;
    #pragma unroll
    for (int m = 0; m < 8; ++m)
      #pragma unroll
      for (int n = 0; n < 4; ++n) {
        int col = tn * 256 + wc * 64 + n * 16 + lnl;
        #pragma unroll
        for (int v = 0; v < 4; ++v) {
          float xg = acc[m][n][v];
          float gl = 0.5f * xg * (1.f + erff(xg * 0.70710678118654752f));
          Cp[(size_t)(rb + m * 16 + v) * ldc + col] = f2bf(gl);
        }
      }
  }
}

// ---------------- 128x128 GEMM (small final projection, f32 out) ----------------
__global__ __launch_bounds__(256) void gemm128(
    const u16* __restrict__ A, const u16* __restrict__ B, float* __restrict__ C,
    int Ksz, int lda, int ldb, int ldc, int ntm)
{
  __shared__ char smem[32768];
  int bid = blockIdx.x;
  int tm = bid % ntm, tn = bid / ntm;
  int tid = threadIdx.x, wv = tid >> 6, ln = tid & 63;

  const char* aP[4]; const char* bP[4];
  unsigned aL[4], bL[4];
  #pragma unroll
  for (int r = 0; r < 4; ++r) {
    int lb = r * 4096 + tid * 16;
    int row = lb >> 7;
    int colb = (lb & 127) ^ ((row & 7) << 4);
    aP[r] = (const char*)(A + (size_t)(tm * 128 + row) * lda) + colb;
    bP[r] = (const char*)(B + (size_t)(tn * 128 + row) * ldb) + colb;
    aL[r] = r * 4096 + wv * 1024;
    bL[r] = 16384 + r * 4096 + wv * 1024;
  }

  f32x4 acc[2][8];
  #pragma unroll
  for (int m = 0; m < 2; ++m)
    #pragma unroll
    for (int n = 0; n < 8; ++n) acc[m][n] = (f32x4){0.f, 0.f, 0.f, 0.f};

  for (int k0 = 0; k0 < Ksz; k0 += 64) {
    size_t kbb = (size_t)k0 * 2;
    #pragma unroll
    for (int r = 0; r < 4; ++r) gload16(aP[r] + kbb, smem + aL[r]);
    #pragma unroll
    for (int r = 0; r < 4; ++r) gload16(bP[r] + kbb, smem + bL[r]);
    __syncthreads();
    #pragma unroll
    for (int ks = 0; ks < 2; ++ks) {
      int kbyte = ks * 64 + ((ln >> 4) << 4);
      s16x8 av[2];
      #pragma unroll
      for (int m = 0; m < 2; ++m) {
        int row = wv * 32 + m * 16 + (ln & 15);
        av[m] = *(const s16x8*)(smem + (row << 7) + (kbyte ^ ((row & 7) << 4)));
      }
      #pragma unroll
      for (int n = 0; n < 8; ++n) {
        int row = n * 16 + (ln & 15);
        s16x8 bv = *(const s16x8*)(smem + 16384 + (row << 7) + (kbyte ^ ((row & 7) << 4)));
        acc[0][n] = __builtin_amdgcn_mfma_f32_16x16x32_bf16(av[0], bv, acc[0][n], 0, 0, 0);
        acc[1][n] = __builtin_amdgcn_mfma_f32_16x16x32_bf16(av[1], bv, acc[1][n], 0, 0, 0);
      }
    }
    __syncthreads();
  }

  int rbase = tm * 128 + wv * 32 + ((ln >> 4) << 2);
  int cb = (ln & 15);
  #pragma unroll
  for (int m = 0; m < 2; ++m)
    #pragma unroll
    for (int n = 0; n < 8; ++n)
      #pragma unroll
      for (int v = 0; v < 4; ++v)
        C[(size_t)(rbase + m * 16 + v) * ldc + tn * 128 + n * 16 + cb] = acc[m][n][v];
}

// ---------------- per-token scores + masked softmax + Cmsg ----------------
__global__ __launch_bounds__(256) void scores_kernel(
    const u16* __restrict__ MQ, const u16* __restrict__ KK,
    const int* __restrict__ keep, u16* __restrict__ Cmsg)
{
  int wv = threadIdx.x >> 6, ln = threadIdx.x & 63;
  int n = blockIdx.x * 4 + wv;
  const u16* m0 = MQ + (size_t)(2 * n) * 2048;
  const u16* m1 = MQ + (size_t)(2 * n + 1) * 2048;
  const u16* q0 = m0 + 1024;
  const u16* q1 = m1 + 1024;
  const u16* k0p = KK + (size_t)(2 * n) * 1024;
  const u16* k1p = KK + (size_t)(2 * n + 1) * 1024;
  float s00 = 0, s01 = 0, s10 = 0, s11 = 0;
  #pragma unroll
  for (int j = 0; j < 2; ++j) {
    int d0 = ln * 16 + j * 8;
    u16x8 a0 = *(const u16x8*)(q0 + d0);
    u16x8 a1 = *(const u16x8*)(q1 + d0);
    u16x8 b0 = *(const u16x8*)(k0p + d0);
    u16x8 b1 = *(const u16x8*)(k1p + d0);
    #pragma unroll
    for (int t = 0; t < 8; ++t) {
      float fa0 = bf2f(a0[t]), fa1 = bf2f(a1[t]);
      float fb0 = bf2f(b0[t]), fb1 = bf2f(b1[t]);
      s00 += fa0 * fb0; s01 += fa0 * fb1; s10 += fa1 * fb0; s11 += fa1 * fb1;
    }
  }
  #pragma unroll
  for (int off = 32; off >= 1; off >>= 1) {
    s00 += __shfl_xor(s00, off, 64);
    s01 += __shfl_xor(s01, off, 64);
    s10 += __shfl_xor(s10, off, 64);
    s11 += __shfl_xor(s11, off, 64);
  }
  const float inv = 0.03125f;
  int kp0 = keep[2 * n], kp1 = keep[2 * n + 1];
  float A00, A01, A10, A11;
  {
    float v0 = kp0 ? s00 * inv : -1e9f;
    float v1 = (kp0 && kp1) ? s01 * inv : -1e9f;
    float mx = fmaxf(v0, v1);
    float e0 = expf(v0 - mx), e1 = expf(v1 - mx);
    float den = e0 + e1;
    float a0 = kp0 ? e0 / den : 0.f;
    float a1 = (kp0 && kp1) ? e1 / den : 0.f;
    float s = fmaxf(a0 + a1, 1e-12f);
    A00 = a0 / s; A01 = a1 / s;
  }
  {
    float v0 = (kp1 && kp0) ? s10 * inv : -1e9f;
    float v1 = kp1 ? s11 * inv : -1e9f;
    float mx = fmaxf(v0, v1);
    float e0 = expf(v0 - mx), e1 = expf(v1 - mx);
    float den = e0 + e1;
    float a0 = (kp1 && kp0) ? e0 / den : 0.f;
    float a1 = kp1 ? e1 / den : 0.f;
    float s = fmaxf(a0 + a1, 1e-12f);
    A10 = a0 / s; A11 = a1 / s;
  }
  u16* c0 = Cmsg + (size_t)(2 * n) * 1024;
  u16* c1 = Cmsg + (size_t)(2 * n + 1) * 1024;
  #pragma unroll
  for (int j = 0; j < 2; ++j) {
    int d0 = ln * 16 + j * 8;
    u16x8 x0 = *(const u16x8*)(m0 + d0);
    u16x8 x1 = *(const u16x8*)(m1 + d0);
    u16x8 o0, o1;
    #pragma unroll
    for (int t = 0; t < 8; ++t) {
      float f0 = bf2f(x0[t]), f1 = bf2f(x1[t]);
      o0[t] = f2bf(A00 * f0 + A01 * f1);
      o1[t] = f2bf(A10 * f0 + A11 * f1);
    }
    *(u16x8*)(c0 + d0) = o0;
    *(u16x8*)(c1 + d0) = o1;
  }
}

// ---------------- combine ----------------
__global__ __launch_bounds__(256) void combine_kernel(
    const u16* __restrict__ sel, const u16* __restrict__ upd,
    const int* __restrict__ keep, const float* __restrict__ tkprob,
    u16* __restrict__ fusedp)
{
  int n = blockIdx.x;
  int t = threadIdx.x;
  float kp0 = keep[2 * n] ? 1.f : 0.f, kp1 = keep[2 * n + 1] ? 1.f : 0.f;
  float p0 = tkprob[2 * n] * kp0, p1 = tkprob[2 * n + 1] * kp1;
  float s = fmaxf(p0 + p1, 1e-12f);
  float w0 = p0 / s, w1 = p1 / s;
  int d0 = t * 4;
  u16x4 s0 = *(const u16x4*)(sel + (size_t)(2 * n) * Dv + d0);
  u16x4 s1 = *(const u16x4*)(sel + (size_t)(2 * n + 1) * Dv + d0);
  u16x4 u0 = *(const u16x4*)(upd + (size_t)(2 * n) * Dv + d0);
  u16x4 u1 = *(const u16x4*)(upd + (size_t)(2 * n + 1) * Dv + d0);
  u16x4 o;
  #pragma unroll
  for (int j = 0; j < 4; ++j) {
    float r0 = (bf2f(s0[j]) + bf2f(u0[j])) * kp0;
    float r1 = (bf2f(s1[j]) + bf2f(u1[j])) * kp1;
    o[j] = f2bf(w0 * r0 + w1 * r1);
  }
  *(u16x4*)(fusedp + (size_t)n * Dv + d0) = o;
}

extern "C" void kernel_launch(void* const* d_in, const int* in_sizes, int n_in,
                              void* d_out, int out_size, void* d_ws, size_t ws_size,
                              hipStream_t stream) {
  const float* x      = (const float*)d_in[0];
  const float* gate_w = (const float*)d_in[1];
  const float* w13    = (const float*)d_in[2];
  const float* w2     = (const float*)d_in[3];
  const float* msg_w  = (const float*)d_in[4];
  const float* q_w    = (const float*)d_in[5];
  const float* k_w    = (const float*)d_in[6];
  const float* upd_w1 = (const float*)d_in[7];
  const float* upd_w2 = (const float*)d_in[8];
  const float* o_w    = (const float*)d_in[9];
  float* out = (float*)d_out;
  float* outAux = out + (size_t)Nv * Dv;
  float* outIdx = outAux + 1;

  char* ws = (char*)d_ws;
  const size_t MBc = 1ull << 20;
  int*   tkidx  = (int*)(ws + 0);
  float* tkprob = (float*)(ws + 32768);
  int*   keepA  = (int*)(ws + 65536);
  int*   dstNK  = (int*)(ws + 98304);
  float* red    = (float*)(ws + 143360);
  // phase A (fp8 experts):
  u8*  BUF8  = (u8*)(ws + 1 * MBc);     // 10 MiB [1,12)
  u8*  ACT8  = (u8*)(ws + 12 * MBc);    // 28.8 MiB [12,41)
  u8*  W13B8 = (u8*)(ws + 41 * MBc);    // 46 MiB [41,88), dead after G1
  u8*  W2B8  = (u8*)(ws + 41 * MBc);    // 23 MiB, converted after G1
  u16* SEL   = (u16*)(ws + 120 * MBc);
  u16* MSGQB = (u16*)(ws + 136 * MBc);
  u16* KB    = (u16*)(ws + 140 * MBc);
  u16* OB    = (u16*)(ws + 142 * MBc);
  u16* UPD1B = (u16*)(ws + 144 * MBc);
  u16* UPD2B = (u16*)(ws + 152 * MBc);
  // phase B overlays (experts' buffers dead):
  u16* MQ    = (u16*)(ws + 1 * MBc);
  u16* KKb   = (u16*)(ws + 33 * MBc);
  u16* CMSG  = (u16*)(ws + 49 * MBc);
  u16* G1B   = (u16*)(ws + 65 * MBc);
  u16* UPD   = (u16*)(ws + 97 * MBc);
  u16* FUSEDP= (u16*)(ws + 1 * MBc);

  hipMemsetAsync(red, 0, 68, stream);
  hipMemsetAsync(dstNK, 0xFF, Ev * CAPv * 4, stream);

  router_kernel<<<Nv / 4, 256, 0, stream>>>(x, gate_w, tkidx, tkprob, red, outIdx);
  aux_kernel<<<1, 1, 0, stream>>>(red, outAux);
  rank_kernel<<<1, 256, 0, stream>>>(tkidx, keepA, dstNK);
  pack8_kernel<<<(Ev * CAPv) / 4, 256, 0, stream>>>(x, dstNK, BUF8);

  // G1: w13 -> fp8 (x16, HW scale 2^-4), MX-fp8 SwiGLU GEMM -> ACT8
  tconv8_kernel<<<dim3(TH2v / 64, Dv / 64, Ev), 256, 0, stream>>>(w13, W13B8, Dv, TH2v, 16.f);
  gemm256f8<1><<<dim3((CAPv / 256) * (Hv / 128), Ev), 512, 0, stream>>>(
      BUF8, W13B8, (void*)ACT8, nullptr,
      Dv, Dv, Dv, Hv, CAPv / 256,
      (size_t)CAPv * Dv, (size_t)TH2v * Dv, (size_t)CAPv * Hv, 0x7B7B7B7Bu);

  hipMemsetAsync(SEL, 0, (size_t)NKv * Dv * 2, stream);
  tconv8_kernel<<<dim3(Dv / 64, Hv / 64, Ev), 256, 0, stream>>>(w2, W2B8, Hv, Dv, 16.f);
  tconv_kernel<<<dim3(16, 16, 1), 256, 0, stream>>>(msg_w, MSGQB, Dv, Dv);
  tconv_kernel<<<dim3(16, 16, 1), 256, 0, stream>>>(q_w, MSGQB + (size_t)Dv * Dv, Dv, Dv);
  tconv_kernel<<<dim3(16, 16, 1), 256, 0, stream>>>(k_w, KB, Dv, Dv);
  tconv_kernel<<<dim3(16, 16, 1), 256, 0, stream>>>(o_w, OB, Dv, Dv);
  tconv_kernel<<<dim3(32, 32, 1), 256, 0, stream>>>(upd_w1, UPD1B, 2048, 2048);
  tconv_kernel<<<dim3(16, 32, 1), 256, 0, stream>>>(upd_w2, UPD2B, 2048, Dv);

  // G2: MX-fp8 GEMM + scatter -> SEL (bf16)
  gemm256f8<2><<<dim3((CAPv / 256) * (Dv / 256), Ev), 512, 0, stream>>>(
      ACT8, W2B8, (void*)SEL, dstNK,
      Hv, Hv, Hv, Dv, CAPv / 256,
      (size_t)CAPv * Hv, (size_t)Dv * Hv, 0, 0x7B7B7B7Bu);

  // collaboration: fused [M|Q] GEMM, then Kk GEMM, then scores (bf16)
  gemm256<0><<<dim3(32 * 8, 1), 512, 0, stream>>>(SEL, SEL, 1 << 30, MSGQB, (void*)MQ,
      Dv, Dv, Dv, 2048, 32);
  gemm256<0><<<dim3(32 * 4, 1), 512, 0, stream>>>(MQ, MQ, 1 << 30, KB, (void*)KKb,
      Dv, 2048, Dv, Dv, 32);
  scores_kernel<<<Nv / 4, 256, 0, stream>>>(MQ, KKb, keepA, CMSG);

  // update MLP: cat = [SEL | CMSG] via split-K A, gelu fused
  gemm256<3><<<dim3(32 * 8, 1), 512, 0, stream>>>(SEL, CMSG, Dv, UPD1B, (void*)G1B,
      2048, Dv, 2048, 2048, 32);
  gemm256<0><<<dim3(32 * 4, 1), 512, 0, stream>>>(G1B, G1B, 1 << 30, UPD2B, (void*)UPD,
      2048, 2048, 2048, Dv, 32);

  combine_kernel<<<Nv, 256, 0, stream>>>(SEL, UPD, keepA, tkprob, FUSEDP);

  gemm128<<<dim3(32 * 8, 1), 256, 0, stream>>>(FUSEDP, OB, out, Dv, Dv, Dv, Dv, 32);

  (void)in_sizes; (void)n_in; (void)out_size; (void)ws_size;
}

// Round 7
// 564.837 us; speedup vs baseline: 1.1911x; 1.0083x over previous
//
#include <hip/hip_runtime.h>
#include <math.h>

#define Dv 1024
#define Ev 8
#define Hv 2816
#define Nv 4096
#define NKv 8192
#define CAPv 1280
#define TH2v 5632

typedef unsigned short u16;
typedef unsigned char u8;
typedef __attribute__((ext_vector_type(8))) short s16x8;
typedef __attribute__((ext_vector_type(4))) float f32x4;
typedef __attribute__((ext_vector_type(4))) int i32x4;
typedef __attribute__((ext_vector_type(8))) int i32x8;
typedef __attribute__((ext_vector_type(8))) u16 u16x8;
typedef __attribute__((ext_vector_type(4))) u16 u16x4;

typedef const __attribute__((address_space(1))) void* as1_cvp;
typedef __attribute__((address_space(3))) void* as3_vp;

__device__ __forceinline__ u16 f2bf(float f) {
  unsigned u = __float_as_uint(f);
  u += 0x7fffu + ((u >> 16) & 1u);
  return (u16)(u >> 16);
}
__device__ __forceinline__ float bf2f(u16 h) {
  return __uint_as_float(((unsigned)h) << 16);
}
// f32 -> OCP e4m3fn, RNE, saturate to 448
__device__ __forceinline__ unsigned f2e4(float f) {
  unsigned u = __float_as_uint(f);
  unsigned sgn = (u >> 24) & 0x80u;
  unsigned ax = u & 0x7FFFFFFFu;
  if (ax >= 0x43E00000u) return sgn | 0x7Eu;
  if (ax < 0x3C800000u) {
    int qv = (int)rintf(__uint_as_float(ax) * 512.f);
    return sgn | (unsigned)qv;
  }
  unsigned lsb = (ax >> 20) & 1u;
  unsigned rr = ax + 0x0007FFFFu + lsb;
  unsigned ee = rr >> 23;
  unsigned mm = (rr >> 20) & 7u;
  if (ee > 135u) return sgn | 0x7Eu;
  return sgn | ((ee - 120u) << 3) | mm;
}
__device__ __forceinline__ void gload16(const void* g, void* l) {
  __builtin_amdgcn_global_load_lds((as1_cvp)g, (as3_vp)l, 16, 0, 0);
}

// ---------------- router ----------------
__global__ __launch_bounds__(256) void router_kernel(
    const float* __restrict__ x, const float* __restrict__ gw,
    int* __restrict__ tkidx, float* __restrict__ tkprob,
    float* __restrict__ red, float* __restrict__ outIdx)
{
  __shared__ float lred[17];
  int tid = threadIdx.x;
  if (tid < 17) lred[tid] = 0.f;
  __syncthreads();
  int wv = tid >> 6, ln = tid & 63;
  int n = blockIdx.x * 4 + wv;
  float a[8] = {0.f,0.f,0.f,0.f,0.f,0.f,0.f,0.f};
  const float* xr = x + (size_t)n * Dv;
  #pragma unroll
  for (int it = 0; it < 16; ++it) {
    int d = ln + it * 64;
    float xs = xr[d];
    float4 g0 = *(const float4*)(gw + (size_t)d * 8);
    float4 g1 = *(const float4*)(gw + (size_t)d * 8 + 4);
    a[0] += xs * g0.x; a[1] += xs * g0.y; a[2] += xs * g0.z; a[3] += xs * g0.w;
    a[4] += xs * g1.x; a[5] += xs * g1.y; a[6] += xs * g1.z; a[7] += xs * g1.w;
  }
  #pragma unroll
  for (int off = 32; off >= 1; off >>= 1) {
    #pragma unroll
    for (int e = 0; e < 8; ++e) a[e] += __shfl_xor(a[e], off, 64);
  }
  int i1 = 0; float v1 = a[0];
  #pragma unroll
  for (int e = 1; e < 8; ++e) if (a[e] > v1) { v1 = a[e]; i1 = e; }
  int i2 = -1; float v2 = -1e30f;
  #pragma unroll
  for (int e = 0; e < 8; ++e) if (e != i1 && a[e] > v2) { v2 = a[e]; i2 = e; }
  float Z = 0.f;
  #pragma unroll
  for (int e = 0; e < 8; ++e) Z += expf(a[e] - v1);
  float zlse = v1 + logf(Z);
  float t = expf(v2 - v1);
  float p1 = 1.f / (1.f + t);
  float p2 = t * p1;
  if (ln == 0) {
    tkidx[2*n] = i1; tkidx[2*n+1] = i2;
    tkprob[2*n] = p1; tkprob[2*n+1] = p2;
    outIdx[2*n] = (float)i1; outIdx[2*n+1] = (float)i2;
    #pragma unroll
    for (int e = 0; e < 8; ++e) atomicAdd(&lred[e], expf(a[e] - v1) / Z);
    atomicAdd(&lred[8 + i1], 1.f);
    atomicAdd(&lred[16], zlse * zlse);
  }
  __syncthreads();
  if (tid < 17) atomicAdd(&red[tid], lred[tid]);
}

__global__ void aux_kernel(const float* __restrict__ red, float* __restrict__ outAux) {
  float bl = 0.f;
  for (int e = 0; e < 8; ++e) bl += (red[e] / (float)Nv) * (red[8 + e] / (float)Nv);
  bl *= (float)Ev;
  float zl = red[16] / (float)Nv;
  outAux[0] = 0.01f * bl + 0.001f * zl;
}

// ---------------- exact stable rank ----------------
__global__ __launch_bounds__(256) void rank_kernel(const int* __restrict__ tgt,
    int* __restrict__ keep, int* __restrict__ dstNK)
{
  __shared__ int hist[256][8];
  int t = threadIdx.x;
  int h[8] = {0,0,0,0,0,0,0,0};
  int base = t * 32;
  for (int j = 0; j < 32; ++j) h[tgt[base + j]]++;
  for (int e = 0; e < 8; ++e) hist[t][e] = h[e];
  __syncthreads();
  if (t < 8) {
    int run = 0;
    for (int tt = 0; tt < 256; ++tt) { int v = hist[tt][t]; hist[tt][t] = run; run += v; }
  }
  __syncthreads();
  for (int e = 0; e < 8; ++e) h[e] = hist[t][e];
  for (int j = 0; j < 32; ++j) {
    int i = base + j; int e = tgt[i]; int r = h[e]++;
    int kp = (r < CAPv) ? 1 : 0;
    keep[i] = kp;
    if (kp) dstNK[e * CAPv + r] = i;
  }
}

// ---------------- pack tokens -> fp8 ----------------
__global__ __launch_bounds__(256) void pack8_kernel(const float* __restrict__ x,
    const int* __restrict__ dstNK, u8* __restrict__ buf)
{
  int s = blockIdx.x * 4 + (threadIdx.x >> 6);
  int ln = threadIdx.x & 63;
  int i = dstNK[s];
  u8* dst = buf + (size_t)s * Dv;
  if (i >= 0) {
    const float* src = x + (size_t)(i >> 1) * Dv;
    #pragma unroll
    for (int j = 0; j < 4; ++j) {
      int d0 = ln * 16 + j * 4;
      float4 v = *(const float4*)(src + d0);
      unsigned w = f2e4(v.x) | (f2e4(v.y) << 8) | (f2e4(v.z) << 16) | (f2e4(v.w) << 24);
      *(unsigned*)(dst + d0) = w;
    }
  } else {
    #pragma unroll
    for (int j = 0; j < 4; ++j) *(unsigned*)(dst + ln * 16 + j * 4) = 0u;
  }
}

// ---------------- transpose + f32->bf16 ----------------
__global__ __launch_bounds__(256) void tconv_kernel(const float* __restrict__ in,
    u16* __restrict__ out, int R, int C)
{
  __shared__ u16 tile[64][68];
  size_t zoff = (size_t)blockIdx.z * (size_t)R * (size_t)C;
  in += zoff; out += zoff;
  int r0 = blockIdx.y * 64, c0 = blockIdx.x * 64;
  int t = threadIdx.x;
  int cc4 = (t & 15) * 4;
  #pragma unroll
  for (int p = 0; p < 4; ++p) {
    int r = (t >> 4) + p * 16;
    float4 v = *(const float4*)(in + (size_t)(r0 + r) * C + c0 + cc4);
    u16x4 b; b[0]=f2bf(v.x); b[1]=f2bf(v.y); b[2]=f2bf(v.z); b[3]=f2bf(v.w);
    *(u16x4*)(&tile[r][cc4]) = b;
  }
  __syncthreads();
  int rr4 = (t & 15) * 4;
  #pragma unroll
  for (int p = 0; p < 4; ++p) {
    int c = (t >> 4) + p * 16;
    u16x4 o; o[0]=tile[rr4][c]; o[1]=tile[rr4+1][c]; o[2]=tile[rr4+2][c]; o[3]=tile[rr4+3][c];
    *(u16x4*)(out + (size_t)(c0 + c) * R + r0 + rr4) = o;
  }
}

// ---------------- transpose + f32->e4m3 (xsmul) ----------------
__global__ __launch_bounds__(256) void tconv8_kernel(const float* __restrict__ in,
    u8* __restrict__ out, int R, int C, float smul)
{
  __shared__ u8 tile[64][68];
  size_t zoff = (size_t)blockIdx.z * (size_t)R * (size_t)C;
  in += zoff; out += zoff;
  int r0 = blockIdx.y * 64, c0 = blockIdx.x * 64;
  int t = threadIdx.x;
  int cc4 = (t & 15) * 4;
  #pragma unroll
  for (int p = 0; p < 4; ++p) {
    int r = (t >> 4) + p * 16;
    float4 v = *(const float4*)(in + (size_t)(r0 + r) * C + c0 + cc4);
    unsigned w = f2e4(v.x * smul) | (f2e4(v.y * smul) << 8)
               | (f2e4(v.z * smul) << 16) | (f2e4(v.w * smul) << 24);
    *(unsigned*)(&tile[r][cc4]) = w;
  }
  __syncthreads();
  int rr4 = (t & 15) * 4;
  #pragma unroll
  for (int p = 0; p < 4; ++p) {
    int c = (t >> 4) + p * 16;
    unsigned w = (unsigned)tile[rr4][c] | ((unsigned)tile[rr4+1][c] << 8)
               | ((unsigned)tile[rr4+2][c] << 16) | ((unsigned)tile[rr4+3][c] << 24);
    *(unsigned*)(out + (size_t)(c0 + c) * R + r0 + rr4) = w;
  }
}

// ===== 256x256 8-wave MX-fp8 GEMM, 16x16x128 scaled MFMA, BK=128, dbuf =====
// LDS k-chunk permutation P: global chunk 2m -> slot m, 2m+1 -> slot m+4, so
// fragment reads are byte-identical to the bf16 zero-conflict pattern.
// MODE 1: SwiGLU -> fp8 out. MODE 2: scatter -> bf16.
template<int MODE>
__global__ __launch_bounds__(512, 2) void gemm256f8(
    const u8* __restrict__ A, const u8* __restrict__ B, void* __restrict__ C,
    const int* __restrict__ dst, int Ksz, int lda, int ldb, int ldc, int ntm,
    size_t sA, size_t sB, size_t sC, unsigned sclB)
{
  __shared__ char smem[131072];  // A dbuf [0,64K), B dbuf [64K,128K)
  int e = blockIdx.y;
  int nwgx = gridDim.x, bid0 = blockIdx.x;
  int q = nwgx >> 3, r = nwgx & 7;
  int xcd = bid0 & 7, lo2 = bid0 >> 3;
  int bid = (xcd < r ? xcd * (q + 1) : r * (q + 1) + (xcd - r) * q) + lo2;
  int tm = bid % ntm, tn = bid / ntm;
  const u8* Ae = A + (size_t)e * sA;
  const u8* Be = B + (size_t)e * sB;
  int tid = threadIdx.x, wv = tid >> 6, ln = tid & 63;
  int wr = wv >> 2, wc = wv & 3;
  int lnl = ln & 15, lnh = ln >> 4;

  const u8* aP[4]; const u8* bP[4];
  // staging: slot sl=ln&7, row parity r7=(ln>>3)&7; fetch global chunk P(sl^r7)
  int sx = (tid & 7) ^ ((tid >> 3) & 7);
  int colsw = ((((sx & 3) << 1) | (sx >> 2)) << 4);
  #pragma unroll
  for (int i = 0; i < 4; ++i) {
    int row = i * 64 + (tid >> 3);
    aP[i] = Ae + (size_t)(tm * 256 + row) * lda + colsw;
    int brow;
    if (MODE == 1) {
      int s = row & 63, wcl = row >> 6;
      brow = (s < 32) ? (tn * 128 + wcl * 32 + s) : (Hv + tn * 128 + wcl * 32 + (s - 32));
    } else {
      brow = tn * 256 + row;
    }
    bP[i] = Be + (size_t)brow * ldb + colsw;
  }

  int arow0 = wr * 128 + lnl;
  int brow0 = wc * 64 + lnl;
  // read offsets: exactly the bf16-proven slots
  int ksw0 = (lnh << 4);        // ^ ((row&7)<<4) at use  -> k [32*lnh, +16)
  int ksw1 = 64 + (lnh << 4);   // ^ ((row&7)<<4) at use  -> k [32*lnh+16, +16)

  auto issueA = [&](int t1, int bsel, int band) {
    gload16(aP[band] + (size_t)t1 * 128, smem + bsel * 32768 + band * 8192 + (wv << 10));
  };
  auto issueB = [&](int t1, int bsel, int band) {
    gload16(bP[band] + (size_t)t1 * 128, smem + 65536 + bsel * 32768 + band * 8192 + (wv << 10));
  };

  f32x4 acc[8][4];
  #pragma unroll
  for (int m = 0; m < 8; ++m)
    #pragma unroll
    for (int n = 0; n < 4; ++n) acc[m][n] = (f32x4){0.f, 0.f, 0.f, 0.f};

  int nt = Ksz >> 7;
  issueB(0, 0, 0); issueB(0, 0, 1); issueB(0, 0, 2); issueB(0, 0, 3);
  issueA(0, 0, 0); issueA(0, 0, 2); issueA(0, 0, 1); issueA(0, 0, 3);
  asm volatile("s_waitcnt vmcnt(2)" ::: "memory");  // B all + A bands 0,2
  __builtin_amdgcn_s_barrier();

  for (int t = 0; t < nt; ++t) {
    int cur = t & 1;
    const char* sa = smem + cur * 32768;
    const char* sb = smem + 65536 + cur * 32768;
    bool pf = (t + 1 < nt);

    i32x8 bf[4];
    #pragma unroll
    for (int n = 0; n < 4; ++n) {
      int row = brow0 + n * 16;
      int swz = (row & 7) << 4;
      i32x4 lo = *(const i32x4*)(sb + row * 128 + (ksw0 ^ swz));
      i32x4 hi = *(const i32x4*)(sb + row * 128 + (ksw1 ^ swz));
      bf[n][0]=lo[0]; bf[n][1]=lo[1]; bf[n][2]=lo[2]; bf[n][3]=lo[3];
      bf[n][4]=hi[0]; bf[n][5]=hi[1]; bf[n][6]=hi[2]; bf[n][7]=hi[3];
    }

    #pragma unroll
    for (int h = 0; h < 2; ++h) {
      if (pf) {
        if (h == 0) { issueB(t + 1, cur ^ 1, 0); issueB(t + 1, cur ^ 1, 1);
                      issueB(t + 1, cur ^ 1, 2); issueB(t + 1, cur ^ 1, 3); }
        else        { issueA(t + 1, cur ^ 1, 0); issueA(t + 1, cur ^ 1, 2);
                      issueA(t + 1, cur ^ 1, 1); issueA(t + 1, cur ^ 1, 3); }
      }
      i32x8 af[4];
      #pragma unroll
      for (int mi = 0; mi < 4; ++mi) {
        int row = arow0 + (h * 4 + mi) * 16;
        int swz = (row & 7) << 4;
        i32x4 lo = *(const i32x4*)(sa + row * 128 + (ksw0 ^ swz));
        i32x4 hi = *(const i32x4*)(sa + row * 128 + (ksw1 ^ swz));
        af[mi][0]=lo[0]; af[mi][1]=lo[1]; af[mi][2]=lo[2]; af[mi][3]=lo[3];
        af[mi][4]=hi[0]; af[mi][5]=hi[1]; af[mi][6]=hi[2]; af[mi][7]=hi[3];
      }
      __builtin_amdgcn_s_barrier();
      asm volatile("s_waitcnt lgkmcnt(0)" ::: "memory");
      __builtin_amdgcn_s_setprio(1);
      #pragma unroll
      for (int mi = 0; mi < 4; ++mi)
        #pragma unroll
        for (int n = 0; n < 4; ++n)
          acc[h*4+mi][n] = __builtin_amdgcn_mfma_scale_f32_16x16x128_f8f6f4(
              af[mi], bf[n], acc[h*4+mi][n], 0, 0, 0, 0x7F7F7F7Fu, 0, sclB);
      __builtin_amdgcn_s_setprio(0);
      if (h == 0) {
        if (pf) asm volatile("s_waitcnt vmcnt(4)" ::: "memory");
        else    asm volatile("s_waitcnt vmcnt(0)" ::: "memory");
      } else {
        if (pf) asm volatile("s_waitcnt vmcnt(2)" ::: "memory");
      }
      __builtin_amdgcn_s_barrier();
    }
  }

  int rb = tm * 256 + wr * 128 + (lnh << 2);
  if (MODE == 1) {
    u8* Cp = (u8*)C + (size_t)e * sC;
    #pragma unroll
    for (int m = 0; m < 8; ++m)
      #pragma unroll
      for (int n = 0; n < 2; ++n) {
        int col = tn * 128 + wc * 32 + n * 16 + lnl;
        #pragma unroll
        for (int v = 0; v < 4; ++v) {
          float g = acc[m][n][v];
          float u = acc[m][n + 2][v];
          float sg = g / (1.f + __expf(-g));
          Cp[(size_t)(rb + m * 16 + v) * ldc + col] = (u8)f2e4(sg * u);
        }
      }
  } else {
    u16* Cp = (u16*)C;
    #pragma unroll
    for (int m = 0; m < 8; ++m)
      #pragma unroll
      for (int v = 0; v < 4; ++v) {
        int gr = rb + m * 16 + v;
        int i = dst[e * CAPv + gr];
        if (i >= 0) {
          #pragma unroll
          for (int n = 0; n < 4; ++n)
            Cp[(size_t)i * Dv + tn * 256 + wc * 64 + n * 16 + lnl] = f2bf(acc[m][n][v]);
        }
      }
  }
}

// ===== 256x256 8-wave bf16 GEMM (round-3 schedule), BK=64, dbuf =====
// MODE 0: store bf16  3: gelu + split-K A
template<int MODE>
__global__ __launch_bounds__(512, 2) void gemm256(
    const u16* __restrict__ A, const u16* __restrict__ A2, int splitK,
    const u16* __restrict__ B, void* __restrict__ C,
    int Ksz, int lda, int ldb, int ldc, int ntm)
{
  __shared__ char smem[131072];
  int nwgx = gridDim.x, bid0 = blockIdx.x;
  int q = nwgx >> 3, r = nwgx & 7;
  int xcd = bid0 & 7, lo2 = bid0 >> 3;
  int bid = (xcd < r ? xcd * (q + 1) : r * (q + 1) + (xcd - r) * q) + lo2;
  int tm = bid % ntm, tn = bid / ntm;
  long long bdelta = (const char*)A2 - (const char*)A;
  int tid = threadIdx.x, wv = tid >> 6, ln = tid & 63;
  int wr = wv >> 2, wc = wv & 3;
  int lnl = ln & 15, lnh = ln >> 4;

  const char* aP[4]; const char* bP[4];
  int colsw = ((tid & 7) << 4) ^ (((tid >> 3) & 7) << 4);
  #pragma unroll
  for (int i = 0; i < 4; ++i) {
    int row = i * 64 + (tid >> 3);
    aP[i] = (const char*)(A + (size_t)(tm * 256 + row) * lda) + colsw;
    bP[i] = (const char*)(B + (size_t)(tn * 256 + row) * ldb) + colsw;
  }

  int arow0 = wr * 128 + lnl;
  int brow0 = wc * 64 + lnl;
  int ksw0 = ((lnh << 4)) ^ ((ln & 7) << 4);
  int ksw1 = (64 + (lnh << 4)) ^ ((ln & 7) << 4);

  auto issueA = [&](int t1, int bsel, int band) {
    int k0 = t1 << 6;
    long long kbA;
    if (MODE == 3 && k0 >= splitK) kbA = bdelta + (long long)(k0 - splitK) * 2;
    else kbA = (long long)k0 * 2;
    gload16(aP[band] + kbA, smem + bsel * 32768 + band * 8192 + (wv << 10));
  };
  auto issueB = [&](int t1, int bsel, int band) {
    long long kbB = (long long)(t1 << 6) * 2;
    gload16(bP[band] + kbB, smem + 65536 + bsel * 32768 + band * 8192 + (wv << 10));
  };

  f32x4 acc[8][4];
  #pragma unroll
  for (int m = 0; m < 8; ++m)
    #pragma unroll
    for (int n = 0; n < 4; ++n) acc[m][n] = (f32x4){0.f, 0.f, 0.f, 0.f};

  int nt = Ksz >> 6;
  issueB(0, 0, 0); issueB(0, 0, 1); issueB(0, 0, 2); issueB(0, 0, 3);
  issueA(0, 0, 0); issueA(0, 0, 2); issueA(0, 0, 1); issueA(0, 0, 3);
  asm volatile("s_waitcnt vmcnt(2)" ::: "memory");
  __builtin_amdgcn_s_barrier();

  for (int t = 0; t < nt; ++t) {
    int cur = t & 1;
    int nb = cur ^ 1;
    const char* sa = smem + cur * 32768;
    const char* sb = smem + 65536 + cur * 32768;
    bool pf = (t + 1 < nt);

    s16x8 bfr[4][2];
    #pragma unroll
    for (int n = 0; n < 4; ++n) {
      bfr[n][0] = *(const s16x8*)(sb + (brow0 + n * 16) * 128 + ksw0);
      bfr[n][1] = *(const s16x8*)(sb + (brow0 + n * 16) * 128 + ksw1);
    }

    #pragma unroll
    for (int p = 0; p < 4; ++p) {
      if (pf) {
        if (p == 0)      { issueB(t + 1, nb, 0); issueB(t + 1, nb, 1); }
        else if (p == 1) { issueB(t + 1, nb, 2); issueB(t + 1, nb, 3); }
        else if (p == 2) { issueA(t + 1, nb, 0); issueA(t + 1, nb, 2); }
        else             { issueA(t + 1, nb, 1); issueA(t + 1, nb, 3); }
      }
      s16x8 af0_0 = *(const s16x8*)(sa + (arow0 + (p * 2 + 0) * 16) * 128 + ksw0);
      s16x8 af0_1 = *(const s16x8*)(sa + (arow0 + (p * 2 + 0) * 16) * 128 + ksw1);
      s16x8 af1_0 = *(const s16x8*)(sa + (arow0 + (p * 2 + 1) * 16) * 128 + ksw0);
      s16x8 af1_1 = *(const s16x8*)(sa + (arow0 + (p * 2 + 1) * 16) * 128 + ksw1);
      __builtin_amdgcn_s_barrier();
      asm volatile("s_waitcnt lgkmcnt(0)" ::: "memory");
      __builtin_amdgcn_s_setprio(1);
      #pragma unroll
      for (int n = 0; n < 4; ++n) {
        acc[p*2+0][n] = __builtin_amdgcn_mfma_f32_16x16x32_bf16(af0_0, bfr[n][0], acc[p*2+0][n], 0, 0, 0);
        acc[p*2+0][n] = __builtin_amdgcn_mfma_f32_16x16x32_bf16(af0_1, bfr[n][1], acc[p*2+0][n], 0, 0, 0);
        acc[p*2+1][n] = __builtin_amdgcn_mfma_f32_16x16x32_bf16(af1_0, bfr[n][0], acc[p*2+1][n], 0, 0, 0);
        acc[p*2+1][n] = __builtin_amdgcn_mfma_f32_16x16x32_bf16(af1_1, bfr[n][1], acc[p*2+1][n], 0, 0, 0);
      }
      __builtin_amdgcn_s_setprio(0);
      if (p == 1) {
        if (pf) asm volatile("s_waitcnt vmcnt(4)" ::: "memory");
        else    asm volatile("s_waitcnt vmcnt(0)" ::: "memory");
      } else if (p == 3) {
        if (pf) asm volatile("s_waitcnt vmcnt(2)" ::: "memory");
      }
      __builtin_amdgcn_s_barrier();
    }
  }

  int rb = tm * 256 + wr * 128 + (lnh << 2);
  if (MODE == 0) {
    u16* Cp = (u16*)C;
    #pragma unroll
    for (int m = 0; m < 8; ++m)
      #pragma unroll
      for (int n = 0; n < 4; ++n) {
        int col = tn * 256 + wc * 64 + n * 16 + lnl;
        #pragma unroll
        for (int v = 0; v < 4; ++v)
          Cp[(size_t)(rb + m * 16 + v) * ldc + col] = f2bf(acc[m][n][v]);
      }
  } else {
    u16* Cp = (u16*)C;
    #pragma unroll
    for (int m = 0; m < 8; ++m)
      #pragma unroll
      for (int n = 0; n < 4; ++n) {
        int col = tn * 256 + wc * 64 + n * 16 + lnl;
        #pragma unroll
        for (int v = 0; v < 4; ++v) {
          float xg = acc[m][n][v];
          float gl = 0.5f * xg * (1.f + erff(xg * 0.70710678118654752f));
          Cp[(size_t)(rb + m * 16 + v) * ldc + col] = f2bf(gl);
        }
      }
  }
}

// ---------------- 128x128 GEMM (small final projection, f32 out) ----------------
__global__ __launch_bounds__(256) void gemm128(
    const u16* __restrict__ A, const u16* __restrict__ B, float* __restrict__ C,
    int Ksz, int lda, int ldb, int ldc, int ntm)
{
  __shared__ char smem[32768];
  int bid = blockIdx.x;
  int tm = bid % ntm, tn = bid / ntm;
  int tid = threadIdx.x, wv = tid >> 6, ln = tid & 63;

  const char* aP[4]; const char* bP[4];
  unsigned aL[4], bL[4];
  #pragma unroll
  for (int r = 0; r < 4; ++r) {
    int lb = r * 4096 + tid * 16;
    int row = lb >> 7;
    int colb = (lb & 127) ^ ((row & 7) << 4);
    aP[r] = (const char*)(A + (size_t)(tm * 128 + row) * lda) + colb;
    bP[r] = (const char*)(B + (size_t)(tn * 128 + row) * ldb) + colb;
    aL[r] = r * 4096 + wv * 1024;
    bL[r] = 16384 + r * 4096 + wv * 1024;
  }

  f32x4 acc[2][8];
  #pragma unroll
  for (int m = 0; m < 2; ++m)
    #pragma unroll
    for (int n = 0; n < 8; ++n) acc[m][n] = (f32x4){0.f, 0.f, 0.f, 0.f};

  for (int k0 = 0; k0 < Ksz; k0 += 64) {
    size_t kbb = (size_t)k0 * 2;
    #pragma unroll
    for (int r = 0; r < 4; ++r) gload16(aP[r] + kbb, smem + aL[r]);
    #pragma unroll
    for (int r = 0; r < 4; ++r) gload16(bP[r] + kbb, smem + bL[r]);
    __syncthreads();
    #pragma unroll
    for (int ks = 0; ks < 2; ++ks) {
      int kbyte = ks * 64 + ((ln >> 4) << 4);
      s16x8 av[2];
      #pragma unroll
      for (int m = 0; m < 2; ++m) {
        int row = wv * 32 + m * 16 + (ln & 15);
        av[m] = *(const s16x8*)(smem + (row << 7) + (kbyte ^ ((row & 7) << 4)));
      }
      #pragma unroll
      for (int n = 0; n < 8; ++n) {
        int row = n * 16 + (ln & 15);
        s16x8 bv = *(const s16x8*)(smem + 16384 + (row << 7) + (kbyte ^ ((row & 7) << 4)));
        acc[0][n] = __builtin_amdgcn_mfma_f32_16x16x32_bf16(av[0], bv, acc[0][n], 0, 0, 0);
        acc[1][n] = __builtin_amdgcn_mfma_f32_16x16x32_bf16(av[1], bv, acc[1][n], 0, 0, 0);
      }
    }
    __syncthreads();
  }

  int rbase = tm * 128 + wv * 32 + ((ln >> 4) << 2);
  int cb = (ln & 15);
  #pragma unroll
  for (int m = 0; m < 2; ++m)
    #pragma unroll
    for (int n = 0; n < 8; ++n)
      #pragma unroll
      for (int v = 0; v < 4; ++v)
        C[(size_t)(rbase + m * 16 + v) * ldc + tn * 128 + n * 16 + cb] = acc[m][n][v];
}

// ---------------- per-token scores + masked softmax + Cmsg ----------------
__global__ __launch_bounds__(256) void scores_kernel(
    const u16* __restrict__ MQ, const u16* __restrict__ KK,
    const int* __restrict__ keep, u16* __restrict__ Cmsg)
{
  int wv = threadIdx.x >> 6, ln = threadIdx.x & 63;
  int n = blockIdx.x * 4 + wv;
  const u16* m0 = MQ + (size_t)(2 * n) * 2048;
  const u16* m1 = MQ + (size_t)(2 * n + 1) * 2048;
  const u16* q0 = m0 + 1024;
  const u16* q1 = m1 + 1024;
  const u16* k0p = KK + (size_t)(2 * n) * 1024;
  const u16* k1p = KK + (size_t)(2 * n + 1) * 1024;
  float s00 = 0, s01 = 0, s10 = 0, s11 = 0;
  #pragma unroll
  for (int j = 0; j < 2; ++j) {
    int d0 = ln * 16 + j * 8;
    u16x8 a0 = *(const u16x8*)(q0 + d0);
    u16x8 a1 = *(const u16x8*)(q1 + d0);
    u16x8 b0 = *(const u16x8*)(k0p + d0);
    u16x8 b1 = *(const u16x8*)(k1p + d0);
    #pragma unroll
    for (int t = 0; t < 8; ++t) {
      float fa0 = bf2f(a0[t]), fa1 = bf2f(a1[t]);
      float fb0 = bf2f(b0[t]), fb1 = bf2f(b1[t]);
      s00 += fa0 * fb0; s01 += fa0 * fb1; s10 += fa1 * fb0; s11 += fa1 * fb1;
    }
  }
  #pragma unroll
  for (int off = 32; off >= 1; off >>= 1) {
    s00 += __shfl_xor(s00, off, 64);
    s01 += __shfl_xor(s01, off, 64);
    s10 += __shfl_xor(s10, off, 64);
    s11 += __shfl_xor(s11, off, 64);
  }
  const float inv = 0.03125f;
  int kp0 = keep[2 * n], kp1 = keep[2 * n + 1];
  float A00, A01, A10, A11;
  {
    float v0 = kp0 ? s00 * inv : -1e9f;
    float v1 = (kp0 && kp1) ? s01 * inv : -1e9f;
    float mx = fmaxf(v0, v1);
    float e0 = expf(v0 - mx), e1 = expf(v1 - mx);
    float den = e0 + e1;
    float a0 = kp0 ? e0 / den : 0.f;
    float a1 = (kp0 && kp1) ? e1 / den : 0.f;
    float s = fmaxf(a0 + a1, 1e-12f);
    A00 = a0 / s; A01 = a1 / s;
  }
  {
    float v0 = (kp1 && kp0) ? s10 * inv : -1e9f;
    float v1 = kp1 ? s11 * inv : -1e9f;
    float mx = fmaxf(v0, v1);
    float e0 = expf(v0 - mx), e1 = expf(v1 - mx);
    float den = e0 + e1;
    float a0 = (kp1 && kp0) ? e0 / den : 0.f;
    float a1 = kp1 ? e1 / den : 0.f;
    float s = fmaxf(a0 + a1, 1e-12f);
    A10 = a0 / s; A11 = a1 / s;
  }
  u16* c0 = Cmsg + (size_t)(2 * n) * 1024;
  u16* c1 = Cmsg + (size_t)(2 * n + 1) * 1024;
  #pragma unroll
  for (int j = 0; j < 2; ++j) {
    int d0 = ln * 16 + j * 8;
    u16x8 x0 = *(const u16x8*)(m0 + d0);
    u16x8 x1 = *(const u16x8*)(m1 + d0);
    u16x8 o0, o1;
    #pragma unroll
    for (int t = 0; t < 8; ++t) {
      float f0 = bf2f(x0[t]), f1 = bf2f(x1[t]);
      o0[t] = f2bf(A00 * f0 + A01 * f1);
      o1[t] = f2bf(A10 * f0 + A11 * f1);
    }
    *(u16x8*)(c0 + d0) = o0;
    *(u16x8*)(c1 + d0) = o1;
  }
}

// ---------------- combine ----------------
__global__ __launch_bounds__(256) void combine_kernel(
    const u16* __restrict__ sel, const u16* __restrict__ upd,
    const int* __restrict__ keep, const float* __restrict__ tkprob,
    u16* __restrict__ fusedp)
{
  int n = blockIdx.x;
  int t = threadIdx.x;
  float kp0 = keep[2 * n] ? 1.f : 0.f, kp1 = keep[2 * n + 1] ? 1.f : 0.f;
  float p0 = tkprob[2 * n] * kp0, p1 = tkprob[2 * n + 1] * kp1;
  float s = fmaxf(p0 + p1, 1e-12f);
  float w0 = p0 / s, w1 = p1 / s;
  int d0 = t * 4;
  u16x4 s0 = *(const u16x4*)(sel + (size_t)(2 * n) * Dv + d0);
  u16x4 s1 = *(const u16x4*)(sel + (size_t)(2 * n + 1) * Dv + d0);
  u16x4 u0 = *(const u16x4*)(upd + (size_t)(2 * n) * Dv + d0);
  u16x4 u1 = *(const u16x4*)(upd + (size_t)(2 * n + 1) * Dv + d0);
  u16x4 o;
  #pragma unroll
  for (int j = 0; j < 4; ++j) {
    float r0 = (bf2f(s0[j]) + bf2f(u0[j])) * kp0;
    float r1 = (bf2f(s1[j]) + bf2f(u1[j])) * kp1;
    o[j] = f2bf(w0 * r0 + w1 * r1);
  }
  *(u16x4*)(fusedp + (size_t)n * Dv + d0) = o;
}

extern "C" void kernel_launch(void* const* d_in, const int* in_sizes, int n_in,
                              void* d_out, int out_size, void* d_ws, size_t ws_size,
                              hipStream_t stream) {
  const float* x      = (const float*)d_in[0];
  const float* gate_w = (const float*)d_in[1];
  const float* w13    = (const float*)d_in[2];
  const float* w2     = (const float*)d_in[3];
  const float* msg_w  = (const float*)d_in[4];
  const float* q_w    = (const float*)d_in[5];
  const float* k_w    = (const float*)d_in[6];
  const float* upd_w1 = (const float*)d_in[7];
  const float* upd_w2 = (const float*)d_in[8];
  const float* o_w    = (const float*)d_in[9];
  float* out = (float*)d_out;
  float* outAux = out + (size_t)Nv * Dv;
  float* outIdx = outAux + 1;

  char* ws = (char*)d_ws;
  const size_t MBc = 1ull << 20;
  int*   tkidx  = (int*)(ws + 0);
  float* tkprob = (float*)(ws + 32768);
  int*   keepA  = (int*)(ws + 65536);
  int*   dstNK  = (int*)(ws + 98304);
  float* red    = (float*)(ws + 143360);
  // phase A (fp8 experts):
  u8*  BUF8  = (u8*)(ws + 1 * MBc);
  u8*  ACT8  = (u8*)(ws + 12 * MBc);
  u8*  W13B8 = (u8*)(ws + 41 * MBc);
  u8*  W2B8  = (u8*)(ws + 41 * MBc);
  u16* SEL   = (u16*)(ws + 120 * MBc);
  u16* MSGQB = (u16*)(ws + 136 * MBc);
  u16* KB    = (u16*)(ws + 140 * MBc);
  u16* OB    = (u16*)(ws + 142 * MBc);
  u16* UPD1B = (u16*)(ws + 144 * MBc);
  u16* UPD2B = (u16*)(ws + 152 * MBc);
  // phase B overlays:
  u16* MQ    = (u16*)(ws + 1 * MBc);
  u16* KKb   = (u16*)(ws + 33 * MBc);
  u16* CMSG  = (u16*)(ws + 49 * MBc);
  u16* G1B   = (u16*)(ws + 65 * MBc);
  u16* UPD   = (u16*)(ws + 97 * MBc);
  u16* FUSEDP= (u16*)(ws + 1 * MBc);

  hipMemsetAsync(red, 0, 68, stream);
  hipMemsetAsync(dstNK, 0xFF, Ev * CAPv * 4, stream);

  router_kernel<<<Nv / 4, 256, 0, stream>>>(x, gate_w, tkidx, tkprob, red, outIdx);
  aux_kernel<<<1, 1, 0, stream>>>(red, outAux);
  rank_kernel<<<1, 256, 0, stream>>>(tkidx, keepA, dstNK);
  pack8_kernel<<<(Ev * CAPv) / 4, 256, 0, stream>>>(x, dstNK, BUF8);

  // G1: w13 -> fp8 (x16, HW scale 2^-4), MX-fp8 SwiGLU GEMM -> ACT8
  tconv8_kernel<<<dim3(TH2v / 64, Dv / 64, Ev), 256, 0, stream>>>(w13, W13B8, Dv, TH2v, 16.f);
  gemm256f8<1><<<dim3((CAPv / 256) * (Hv / 128), Ev), 512, 0, stream>>>(
      BUF8, W13B8, (void*)ACT8, nullptr,
      Dv, Dv, Dv, Hv, CAPv / 256,
      (size_t)CAPv * Dv, (size_t)TH2v * Dv, (size_t)CAPv * Hv, 0x7B7B7B7Bu);

  hipMemsetAsync(SEL, 0, (size_t)NKv * Dv * 2, stream);
  tconv8_kernel<<<dim3(Dv / 64, Hv / 64, Ev), 256, 0, stream>>>(w2, W2B8, Hv, Dv, 16.f);
  tconv_kernel<<<dim3(16, 16, 1), 256, 0, stream>>>(msg_w, MSGQB, Dv, Dv);
  tconv_kernel<<<dim3(16, 16, 1), 256, 0, stream>>>(q_w, MSGQB + (size_t)Dv * Dv, Dv, Dv);
  tconv_kernel<<<dim3(16, 16, 1), 256, 0, stream>>>(k_w, KB, Dv, Dv);
  tconv_kernel<<<dim3(16, 16, 1), 256, 0, stream>>>(o_w, OB, Dv, Dv);
  tconv_kernel<<<dim3(32, 32, 1), 256, 0, stream>>>(upd_w1, UPD1B, 2048, 2048);
  tconv_kernel<<<dim3(16, 32, 1), 256, 0, stream>>>(upd_w2, UPD2B, 2048, Dv);

  // G2: MX-fp8 GEMM + scatter -> SEL (bf16)
  gemm256f8<2><<<dim3((CAPv / 256) * (Dv / 256), Ev), 512, 0, stream>>>(
      ACT8, W2B8, (void*)SEL, dstNK,
      Hv, Hv, Hv, Dv, CAPv / 256,
      (size_t)CAPv * Hv, (size_t)Dv * Hv, 0, 0x7B7B7B7Bu);

  // collaboration: fused [M|Q] GEMM, then Kk GEMM, then scores (bf16)
  gemm256<0><<<dim3(32 * 8, 1), 512, 0, stream>>>(SEL, SEL, 1 << 30, MSGQB, (void*)MQ,
      Dv, Dv, Dv, 2048, 32);
  gemm256<0><<<dim3(32 * 4, 1), 512, 0, stream>>>(MQ, MQ, 1 << 30, KB, (void*)KKb,
      Dv, 2048, Dv, Dv, 32);
  scores_kernel<<<Nv / 4, 256, 0, stream>>>(MQ, KKb, keepA, CMSG);

  // update MLP: cat = [SEL | CMSG] via split-K A, gelu fused
  gemm256<3><<<dim3(32 * 8, 1), 512, 0, stream>>>(SEL, CMSG, Dv, UPD1B, (void*)G1B,
      2048, Dv, 2048, 2048, 32);
  gemm256<0><<<dim3(32 * 4, 1), 512, 0, stream>>>(G1B, G1B, 1 << 30, UPD2B, (void*)UPD,
      2048, 2048, 2048, Dv, 32);

  combine_kernel<<<Nv, 256, 0, stream>>>(SEL, UPD, keepA, tkprob, FUSEDP);

  gemm128<<<dim3(32 * 8, 1), 256, 0, stream>>>(FUSEDP, OB, out, Dv, Dv, Dv, Dv, 32);

  (void)in_sizes; (void)n_in; (void)out_size; (void)ws_size;
}

// Round 8
// 536.973 us; speedup vs baseline: 1.2530x; 1.0519x over previous
//
#include <hip/hip_runtime.h>
#include <math.h>

#define Dv 1024
#define Ev 8
#define Hv 2816
#define Nv 4096
#define NKv 8192
#define CAPv 1280
#define TH2v 5632

typedef unsigned short u16;
typedef unsigned char u8;
typedef __attribute__((ext_vector_type(8))) short s16x8;
typedef __attribute__((ext_vector_type(4))) float f32x4;
typedef __attribute__((ext_vector_type(4))) int i32x4;
typedef __attribute__((ext_vector_type(8))) int i32x8;
typedef __attribute__((ext_vector_type(8))) u16 u16x8;
typedef __attribute__((ext_vector_type(4))) u16 u16x4;

typedef const __attribute__((address_space(1))) void* as1_cvp;
typedef __attribute__((address_space(3))) void* as3_vp;

__device__ __forceinline__ u16 f2bf(float f) {
  unsigned u = __float_as_uint(f);
  u += 0x7fffu + ((u >> 16) & 1u);
  return (u16)(u >> 16);
}
__device__ __forceinline__ float bf2f(u16 h) {
  return __uint_as_float(((unsigned)h) << 16);
}
// f32 -> OCP e4m3fn, RNE, saturate to 448
__device__ __forceinline__ unsigned f2e4(float f) {
  unsigned u = __float_as_uint(f);
  unsigned sgn = (u >> 24) & 0x80u;
  unsigned ax = u & 0x7FFFFFFFu;
  if (ax >= 0x43E00000u) return sgn | 0x7Eu;
  if (ax < 0x3C800000u) {
    int qv = (int)rintf(__uint_as_float(ax) * 512.f);
    return sgn | (unsigned)qv;
  }
  unsigned lsb = (ax >> 20) & 1u;
  unsigned rr = ax + 0x0007FFFFu + lsb;
  unsigned ee = rr >> 23;
  unsigned mm = (rr >> 20) & 7u;
  if (ee > 135u) return sgn | 0x7Eu;
  return sgn | ((ee - 120u) << 3) | mm;
}
// e4m3fn -> f32
__device__ __forceinline__ float e42f(unsigned v) {
  unsigned s = (v & 0x80u) << 24, e = (v >> 3) & 15u, m = v & 7u;
  if (e) return __uint_as_float(s | ((e + 120u) << 23) | (m << 20));
  return __uint_as_float(__float_as_uint((float)m * 0.001953125f) | s);
}
__device__ __forceinline__ void dec16(const u8* p, float* o) {
  const unsigned* w = (const unsigned*)p;
  #pragma unroll
  for (int j = 0; j < 4; ++j) {
    unsigned x = w[j];
    o[j*4+0] = e42f(x & 255u);
    o[j*4+1] = e42f((x >> 8) & 255u);
    o[j*4+2] = e42f((x >> 16) & 255u);
    o[j*4+3] = e42f((x >> 24) & 255u);
  }
}
__device__ __forceinline__ void gload16(const void* g, void* l) {
  __builtin_amdgcn_global_load_lds((as1_cvp)g, (as3_vp)l, 16, 0, 0);
}

// ---------------- router ----------------
__global__ __launch_bounds__(256) void router_kernel(
    const float* __restrict__ x, const float* __restrict__ gw,
    int* __restrict__ tkidx, float* __restrict__ tkprob,
    float* __restrict__ red, float* __restrict__ outIdx)
{
  __shared__ float lred[17];
  int tid = threadIdx.x;
  if (tid < 17) lred[tid] = 0.f;
  __syncthreads();
  int wv = tid >> 6, ln = tid & 63;
  int n = blockIdx.x * 4 + wv;
  float a[8] = {0.f,0.f,0.f,0.f,0.f,0.f,0.f,0.f};
  const float* xr = x + (size_t)n * Dv;
  #pragma unroll
  for (int it = 0; it < 16; ++it) {
    int d = ln + it * 64;
    float xs = xr[d];
    float4 g0 = *(const float4*)(gw + (size_t)d * 8);
    float4 g1 = *(const float4*)(gw + (size_t)d * 8 + 4);
    a[0] += xs * g0.x; a[1] += xs * g0.y; a[2] += xs * g0.z; a[3] += xs * g0.w;
    a[4] += xs * g1.x; a[5] += xs * g1.y; a[6] += xs * g1.z; a[7] += xs * g1.w;
  }
  #pragma unroll
  for (int off = 32; off >= 1; off >>= 1) {
    #pragma unroll
    for (int e = 0; e < 8; ++e) a[e] += __shfl_xor(a[e], off, 64);
  }
  int i1 = 0; float v1 = a[0];
  #pragma unroll
  for (int e = 1; e < 8; ++e) if (a[e] > v1) { v1 = a[e]; i1 = e; }
  int i2 = -1; float v2 = -1e30f;
  #pragma unroll
  for (int e = 0; e < 8; ++e) if (e != i1 && a[e] > v2) { v2 = a[e]; i2 = e; }
  float Z = 0.f;
  #pragma unroll
  for (int e = 0; e < 8; ++e) Z += expf(a[e] - v1);
  float zlse = v1 + logf(Z);
  float t = expf(v2 - v1);
  float p1 = 1.f / (1.f + t);
  float p2 = t * p1;
  if (ln == 0) {
    tkidx[2*n] = i1; tkidx[2*n+1] = i2;
    tkprob[2*n] = p1; tkprob[2*n+1] = p2;
    outIdx[2*n] = (float)i1; outIdx[2*n+1] = (float)i2;
    #pragma unroll
    for (int e = 0; e < 8; ++e) atomicAdd(&lred[e], expf(a[e] - v1) / Z);
    atomicAdd(&lred[8 + i1], 1.f);
    atomicAdd(&lred[16], zlse * zlse);
  }
  __syncthreads();
  if (tid < 17) atomicAdd(&red[tid], lred[tid]);
}

__global__ void aux_kernel(const float* __restrict__ red, float* __restrict__ outAux) {
  float bl = 0.f;
  for (int e = 0; e < 8; ++e) bl += (red[e] / (float)Nv) * (red[8 + e] / (float)Nv);
  bl *= (float)Ev;
  float zl = red[16] / (float)Nv;
  outAux[0] = 0.01f * bl + 0.001f * zl;
}

// ---------------- exact stable rank ----------------
__global__ __launch_bounds__(256) void rank_kernel(const int* __restrict__ tgt,
    int* __restrict__ keep, int* __restrict__ dstNK)
{
  __shared__ int hist[256][8];
  int t = threadIdx.x;
  int h[8] = {0,0,0,0,0,0,0,0};
  int base = t * 32;
  for (int j = 0; j < 32; ++j) h[tgt[base + j]]++;
  for (int e = 0; e < 8; ++e) hist[t][e] = h[e];
  __syncthreads();
  if (t < 8) {
    int run = 0;
    for (int tt = 0; tt < 256; ++tt) { int v = hist[tt][t]; hist[tt][t] = run; run += v; }
  }
  __syncthreads();
  for (int e = 0; e < 8; ++e) h[e] = hist[t][e];
  for (int j = 0; j < 32; ++j) {
    int i = base + j; int e = tgt[i]; int r = h[e]++;
    int kp = (r < CAPv) ? 1 : 0;
    keep[i] = kp;
    if (kp) dstNK[e * CAPv + r] = i;
  }
}

// ---------------- pack tokens -> fp8 ----------------
__global__ __launch_bounds__(256) void pack8_kernel(const float* __restrict__ x,
    const int* __restrict__ dstNK, u8* __restrict__ buf)
{
  int s = blockIdx.x * 4 + (threadIdx.x >> 6);
  int ln = threadIdx.x & 63;
  int i = dstNK[s];
  u8* dst = buf + (size_t)s * Dv;
  if (i >= 0) {
    const float* src = x + (size_t)(i >> 1) * Dv;
    #pragma unroll
    for (int j = 0; j < 4; ++j) {
      int d0 = ln * 16 + j * 4;
      float4 v = *(const float4*)(src + d0);
      unsigned w = f2e4(v.x) | (f2e4(v.y) << 8) | (f2e4(v.z) << 16) | (f2e4(v.w) << 24);
      *(unsigned*)(dst + d0) = w;
    }
  } else {
    #pragma unroll
    for (int j = 0; j < 4; ++j) *(unsigned*)(dst + ln * 16 + j * 4) = 0u;
  }
}

// ---------------- transpose + f32->bf16 ----------------
__global__ __launch_bounds__(256) void tconv_kernel(const float* __restrict__ in,
    u16* __restrict__ out, int R, int C)
{
  __shared__ u16 tile[64][68];
  size_t zoff = (size_t)blockIdx.z * (size_t)R * (size_t)C;
  in += zoff; out += zoff;
  int r0 = blockIdx.y * 64, c0 = blockIdx.x * 64;
  int t = threadIdx.x;
  int cc4 = (t & 15) * 4;
  #pragma unroll
  for (int p = 0; p < 4; ++p) {
    int r = (t >> 4) + p * 16;
    float4 v = *(const float4*)(in + (size_t)(r0 + r) * C + c0 + cc4);
    u16x4 b; b[0]=f2bf(v.x); b[1]=f2bf(v.y); b[2]=f2bf(v.z); b[3]=f2bf(v.w);
    *(u16x4*)(&tile[r][cc4]) = b;
  }
  __syncthreads();
  int rr4 = (t & 15) * 4;
  #pragma unroll
  for (int p = 0; p < 4; ++p) {
    int c = (t >> 4) + p * 16;
    u16x4 o; o[0]=tile[rr4][c]; o[1]=tile[rr4+1][c]; o[2]=tile[rr4+2][c]; o[3]=tile[rr4+3][c];
    *(u16x4*)(out + (size_t)(c0 + c) * R + r0 + rr4) = o;
  }
}

// ---------------- transpose + f32->e4m3 (xsmul) ----------------
__global__ __launch_bounds__(256) void tconv8_kernel(const float* __restrict__ in,
    u8* __restrict__ out, int R, int C, float smul)
{
  __shared__ u8 tile[64][68];
  size_t zoff = (size_t)blockIdx.z * (size_t)R * (size_t)C;
  in += zoff; out += zoff;
  int r0 = blockIdx.y * 64, c0 = blockIdx.x * 64;
  int t = threadIdx.x;
  int cc4 = (t & 15) * 4;
  #pragma unroll
  for (int p = 0; p < 4; ++p) {
    int r = (t >> 4) + p * 16;
    float4 v = *(const float4*)(in + (size_t)(r0 + r) * C + c0 + cc4);
    unsigned w = f2e4(v.x * smul) | (f2e4(v.y * smul) << 8)
               | (f2e4(v.z * smul) << 16) | (f2e4(v.w * smul) << 24);
    *(unsigned*)(&tile[r][cc4]) = w;
  }
  __syncthreads();
  int rr4 = (t & 15) * 4;
  #pragma unroll
  for (int p = 0; p < 4; ++p) {
    int c = (t >> 4) + p * 16;
    unsigned w = (unsigned)tile[rr4][c] | ((unsigned)tile[rr4+1][c] << 8)
               | ((unsigned)tile[rr4+2][c] << 16) | ((unsigned)tile[rr4+3][c] << 24);
    *(unsigned*)(out + (size_t)(c0 + c) * R + r0 + rr4) = w;
  }
}

// ===== 256x256 8-wave MX-fp8 GEMM, 16x16x128 scaled MFMA, BK=128, dbuf =====
// MODE 0: bf16 out  1: SwiGLU -> fp8 (e-idx)  2: scatter -> bf16 + fp8 dual
// MODE 4: fp8 out   5: gelu -> fp8 (split-K A)
template<int MODE>
__global__ __launch_bounds__(512, 2) void gemm256f8(
    const u8* __restrict__ A, const u8* __restrict__ A2, int splitK,
    const u8* __restrict__ B, void* __restrict__ C, void* __restrict__ C2,
    const int* __restrict__ dst, int Ksz, int lda, int ldb, int ldc, int ntm,
    size_t sA, size_t sB, size_t sC, unsigned sclB)
{
  __shared__ char smem[131072];
  int e = blockIdx.y;
  int nwgx = gridDim.x, bid0 = blockIdx.x;
  int q = nwgx >> 3, r = nwgx & 7;
  int xcd = bid0 & 7, lo2 = bid0 >> 3;
  int bid = (xcd < r ? xcd * (q + 1) : r * (q + 1) + (xcd - r) * q) + lo2;
  int tm = bid % ntm, tn = bid / ntm;
  const u8* Ae = A + (size_t)e * sA;
  const u8* Be = B + (size_t)e * sB;
  long long bdelta = (const char*)A2 - (const char*)Ae;
  int tid = threadIdx.x, wv = tid >> 6, ln = tid & 63;
  int wr = wv >> 2, wc = wv & 3;
  int lnl = ln & 15, lnh = ln >> 4;

  const u8* aP[4]; const u8* bP[4];
  int sx = (tid & 7) ^ ((tid >> 3) & 7);
  int colsw = ((((sx & 3) << 1) | (sx >> 2)) << 4);
  #pragma unroll
  for (int i = 0; i < 4; ++i) {
    int row = i * 64 + (tid >> 3);
    aP[i] = Ae + (size_t)(tm * 256 + row) * lda + colsw;
    int brow;
    if (MODE == 1) {
      int s = row & 63, wcl = row >> 6;
      brow = (s < 32) ? (tn * 128 + wcl * 32 + s) : (Hv + tn * 128 + wcl * 32 + (s - 32));
    } else {
      brow = tn * 256 + row;
    }
    bP[i] = Be + (size_t)brow * ldb + colsw;
  }

  int arow0 = wr * 128 + lnl;
  int brow0 = wc * 64 + lnl;
  int ksw0 = (lnh << 4);
  int ksw1 = 64 + (lnh << 4);

  auto issueA = [&](int t1, int bsel, int band) {
    int k0 = t1 << 7;
    long long kbA;
    if (MODE == 5 && k0 >= splitK) kbA = bdelta + (long long)(k0 - splitK);
    else kbA = (long long)k0;
    gload16(aP[band] + kbA, smem + bsel * 32768 + band * 8192 + (wv << 10));
  };
  auto issueB = [&](int t1, int bsel, int band) {
    gload16(bP[band] + (size_t)(t1 << 7), smem + 65536 + bsel * 32768 + band * 8192 + (wv << 10));
  };

  f32x4 acc[8][4];
  #pragma unroll
  for (int m = 0; m < 8; ++m)
    #pragma unroll
    for (int n = 0; n < 4; ++n) acc[m][n] = (f32x4){0.f, 0.f, 0.f, 0.f};

  int nt = Ksz >> 7;
  issueB(0, 0, 0); issueB(0, 0, 1); issueB(0, 0, 2); issueB(0, 0, 3);
  issueA(0, 0, 0); issueA(0, 0, 2); issueA(0, 0, 1); issueA(0, 0, 3);
  asm volatile("s_waitcnt vmcnt(2)" ::: "memory");
  __builtin_amdgcn_s_barrier();

  for (int t = 0; t < nt; ++t) {
    int cur = t & 1;
    const char* sa = smem + cur * 32768;
    const char* sb = smem + 65536 + cur * 32768;
    bool pf = (t + 1 < nt);

    i32x8 bf[4];
    #pragma unroll
    for (int n = 0; n < 4; ++n) {
      int row = brow0 + n * 16;
      int swz = (row & 7) << 4;
      *(i32x4*)&bf[n] = *(const i32x4*)(sb + row * 128 + (ksw0 ^ swz));
      *((i32x4*)&bf[n] + 1) = *(const i32x4*)(sb + row * 128 + (ksw1 ^ swz));
    }

    #pragma unroll
    for (int h = 0; h < 2; ++h) {
      if (pf) {
        if (h == 0) { issueB(t + 1, cur ^ 1, 0); issueB(t + 1, cur ^ 1, 1);
                      issueB(t + 1, cur ^ 1, 2); issueB(t + 1, cur ^ 1, 3); }
        else        { issueA(t + 1, cur ^ 1, 0); issueA(t + 1, cur ^ 1, 2);
                      issueA(t + 1, cur ^ 1, 1); issueA(t + 1, cur ^ 1, 3); }
      }
      i32x8 af[4];
      #pragma unroll
      for (int mi = 0; mi < 4; ++mi) {
        int row = arow0 + (h * 4 + mi) * 16;
        int swz = (row & 7) << 4;
        *(i32x4*)&af[mi] = *(const i32x4*)(sa + row * 128 + (ksw0 ^ swz));
        *((i32x4*)&af[mi] + 1) = *(const i32x4*)(sa + row * 128 + (ksw1 ^ swz));
      }
      __builtin_amdgcn_s_barrier();
      asm volatile("s_waitcnt lgkmcnt(0)" ::: "memory");
      __builtin_amdgcn_s_setprio(1);
      #pragma unroll
      for (int mi = 0; mi < 4; ++mi)
        #pragma unroll
        for (int n = 0; n < 4; ++n)
          acc[h*4+mi][n] = __builtin_amdgcn_mfma_scale_f32_16x16x128_f8f6f4(
              af[mi], bf[n], acc[h*4+mi][n], 0, 0, 0, 0x7F7F7F7Fu, 0, sclB);
      __builtin_amdgcn_s_setprio(0);
      if (h == 0) {
        if (pf) asm volatile("s_waitcnt vmcnt(4)" ::: "memory");
        else    asm volatile("s_waitcnt vmcnt(0)" ::: "memory");
      } else {
        if (pf) asm volatile("s_waitcnt vmcnt(2)" ::: "memory");
      }
      __builtin_amdgcn_s_barrier();
    }
  }

  int rb = tm * 256 + wr * 128 + (lnh << 2);
  if (MODE == 0) {
    u16* Cp = (u16*)C;
    #pragma unroll
    for (int m = 0; m < 8; ++m)
      #pragma unroll
      for (int n = 0; n < 4; ++n) {
        int col = tn * 256 + wc * 64 + n * 16 + lnl;
        #pragma unroll
        for (int v = 0; v < 4; ++v)
          Cp[(size_t)(rb + m * 16 + v) * ldc + col] = f2bf(acc[m][n][v]);
      }
  } else if (MODE == 1) {
    u8* Cp = (u8*)C + (size_t)e * sC;
    #pragma unroll
    for (int m = 0; m < 8; ++m)
      #pragma unroll
      for (int n = 0; n < 2; ++n) {
        int col = tn * 128 + wc * 32 + n * 16 + lnl;
        #pragma unroll
        for (int v = 0; v < 4; ++v) {
          float g = acc[m][n][v];
          float u = acc[m][n + 2][v];
          float sg = g / (1.f + __expf(-g));
          Cp[(size_t)(rb + m * 16 + v) * ldc + col] = (u8)f2e4(sg * u);
        }
      }
  } else if (MODE == 2) {
    u16* Cp = (u16*)C;
    u8* Cq = (u8*)C2;
    #pragma unroll
    for (int m = 0; m < 8; ++m)
      #pragma unroll
      for (int v = 0; v < 4; ++v) {
        int gr = rb + m * 16 + v;
        int i = dst[e * CAPv + gr];
        if (i >= 0) {
          #pragma unroll
          for (int n = 0; n < 4; ++n) {
            int col = tn * 256 + wc * 64 + n * 16 + lnl;
            float x = acc[m][n][v];
            Cp[(size_t)i * Dv + col] = f2bf(x);
            Cq[(size_t)i * Dv + col] = (u8)f2e4(x);
          }
        }
      }
  } else if (MODE == 4) {
    u8* Cp = (u8*)C;
    #pragma unroll
    for (int m = 0; m < 8; ++m)
      #pragma unroll
      for (int n = 0; n < 4; ++n) {
        int col = tn * 256 + wc * 64 + n * 16 + lnl;
        #pragma unroll
        for (int v = 0; v < 4; ++v)
          Cp[(size_t)(rb + m * 16 + v) * ldc + col] = (u8)f2e4(acc[m][n][v]);
      }
  } else {
    u8* Cp = (u8*)C;
    #pragma unroll
    for (int m = 0; m < 8; ++m)
      #pragma unroll
      for (int n = 0; n < 4; ++n) {
        int col = tn * 256 + wc * 64 + n * 16 + lnl;
        #pragma unroll
        for (int v = 0; v < 4; ++v) {
          float xg = acc[m][n][v];
          float gl = 0.5f * xg * (1.f + erff(xg * 0.70710678118654752f));
          Cp[(size_t)(rb + m * 16 + v) * ldc + col] = (u8)f2e4(gl);
        }
      }
  }
}

// ---------------- 128x128 GEMM (small final projection, f32 out) ----------------
__global__ __launch_bounds__(256) void gemm128(
    const u16* __restrict__ A, const u16* __restrict__ B, float* __restrict__ C,
    int Ksz, int lda, int ldb, int ldc, int ntm)
{
  __shared__ char smem[32768];
  int bid = blockIdx.x;
  int tm = bid % ntm, tn = bid / ntm;
  int tid = threadIdx.x, wv = tid >> 6, ln = tid & 63;

  const char* aP[4]; const char* bP[4];
  unsigned aL[4], bL[4];
  #pragma unroll
  for (int r = 0; r < 4; ++r) {
    int lb = r * 4096 + tid * 16;
    int row = lb >> 7;
    int colb = (lb & 127) ^ ((row & 7) << 4);
    aP[r] = (const char*)(A + (size_t)(tm * 128 + row) * lda) + colb;
    bP[r] = (const char*)(B + (size_t)(tn * 128 + row) * ldb) + colb;
    aL[r] = r * 4096 + wv * 1024;
    bL[r] = 16384 + r * 4096 + wv * 1024;
  }

  f32x4 acc[2][8];
  #pragma unroll
  for (int m = 0; m < 2; ++m)
    #pragma unroll
    for (int n = 0; n < 8; ++n) acc[m][n] = (f32x4){0.f, 0.f, 0.f, 0.f};

  for (int k0 = 0; k0 < Ksz; k0 += 64) {
    size_t kbb = (size_t)k0 * 2;
    #pragma unroll
    for (int r = 0; r < 4; ++r) gload16(aP[r] + kbb, smem + aL[r]);
    #pragma unroll
    for (int r = 0; r < 4; ++r) gload16(bP[r] + kbb, smem + bL[r]);
    __syncthreads();
    #pragma unroll
    for (int ks = 0; ks < 2; ++ks) {
      int kbyte = ks * 64 + ((ln >> 4) << 4);
      s16x8 av[2];
      #pragma unroll
      for (int m = 0; m < 2; ++m) {
        int row = wv * 32 + m * 16 + (ln & 15);
        av[m] = *(const s16x8*)(smem + (row << 7) + (kbyte ^ ((row & 7) << 4)));
      }
      #pragma unroll
      for (int n = 0; n < 8; ++n) {
        int row = n * 16 + (ln & 15);
        s16x8 bv = *(const s16x8*)(smem + 16384 + (row << 7) + (kbyte ^ ((row & 7) << 4)));
        acc[0][n] = __builtin_amdgcn_mfma_f32_16x16x32_bf16(av[0], bv, acc[0][n], 0, 0, 0);
        acc[1][n] = __builtin_amdgcn_mfma_f32_16x16x32_bf16(av[1], bv, acc[1][n], 0, 0, 0);
      }
    }
    __syncthreads();
  }

  int rbase = tm * 128 + wv * 32 + ((ln >> 4) << 2);
  int cb = (ln & 15);
  #pragma unroll
  for (int m = 0; m < 2; ++m)
    #pragma unroll
    for (int n = 0; n < 8; ++n)
      #pragma unroll
      for (int v = 0; v < 4; ++v)
        C[(size_t)(rbase + m * 16 + v) * ldc + tn * 128 + n * 16 + cb] = acc[m][n][v];
}

// ---------------- per-token scores + masked softmax + Cmsg (fp8 in/out) ----------------
__global__ __launch_bounds__(256) void scores8_kernel(
    const u8* __restrict__ MQ, const u8* __restrict__ KK,
    const int* __restrict__ keep, u8* __restrict__ Cmsg)
{
  int wv = threadIdx.x >> 6, ln = threadIdx.x & 63;
  int n = blockIdx.x * 4 + wv;
  const u8* m0 = MQ + (size_t)(2 * n) * 2048;
  const u8* m1 = MQ + (size_t)(2 * n + 1) * 2048;
  const u8* q0 = m0 + 1024;
  const u8* q1 = m1 + 1024;
  const u8* k0p = KK + (size_t)(2 * n) * 1024;
  const u8* k1p = KK + (size_t)(2 * n + 1) * 1024;
  int d0 = ln * 16;
  float a0[16], a1[16], b0[16], b1[16];
  dec16(q0 + d0, a0); dec16(q1 + d0, a1);
  dec16(k0p + d0, b0); dec16(k1p + d0, b1);
  float s00 = 0, s01 = 0, s10 = 0, s11 = 0;
  #pragma unroll
  for (int t = 0; t < 16; ++t) {
    s00 += a0[t] * b0[t]; s01 += a0[t] * b1[t];
    s10 += a1[t] * b0[t]; s11 += a1[t] * b1[t];
  }
  #pragma unroll
  for (int off = 32; off >= 1; off >>= 1) {
    s00 += __shfl_xor(s00, off, 64);
    s01 += __shfl_xor(s01, off, 64);
    s10 += __shfl_xor(s10, off, 64);
    s11 += __shfl_xor(s11, off, 64);
  }
  const float inv = 0.03125f;
  int kp0 = keep[2 * n], kp1 = keep[2 * n + 1];
  float A00, A01, A10, A11;
  {
    float v0 = kp0 ? s00 * inv : -1e9f;
    float v1 = (kp0 && kp1) ? s01 * inv : -1e9f;
    float mx = fmaxf(v0, v1);
    float e0 = expf(v0 - mx), e1 = expf(v1 - mx);
    float den = e0 + e1;
    float a0v = kp0 ? e0 / den : 0.f;
    float a1v = (kp0 && kp1) ? e1 / den : 0.f;
    float s = fmaxf(a0v + a1v, 1e-12f);
    A00 = a0v / s; A01 = a1v / s;
  }
  {
    float v0 = (kp1 && kp0) ? s10 * inv : -1e9f;
    float v1 = kp1 ? s11 * inv : -1e9f;
    float mx = fmaxf(v0, v1);
    float e0 = expf(v0 - mx), e1 = expf(v1 - mx);
    float den = e0 + e1;
    float a0v = (kp1 && kp0) ? e0 / den : 0.f;
    float a1v = kp1 ? e1 / den : 0.f;
    float s = fmaxf(a0v + a1v, 1e-12f);
    A10 = a0v / s; A11 = a1v / s;
  }
  float f0[16], f1[16];
  dec16(m0 + d0, f0); dec16(m1 + d0, f1);
  unsigned o0[4], o1[4];
  #pragma unroll
  for (int j = 0; j < 4; ++j) {
    o0[j] = 0; o1[j] = 0;
    #pragma unroll
    for (int b = 0; b < 4; ++b) {
      int t = j * 4 + b;
      o0[j] |= f2e4(A00 * f0[t] + A01 * f1[t]) << (8 * b);
      o1[j] |= f2e4(A10 * f0[t] + A11 * f1[t]) << (8 * b);
    }
  }
  u8* c0 = Cmsg + (size_t)(2 * n) * 1024 + d0;
  u8* c1 = Cmsg + (size_t)(2 * n + 1) * 1024 + d0;
  #pragma unroll
  for (int j = 0; j < 4; ++j) {
    *(unsigned*)(c0 + j * 4) = o0[j];
    *(unsigned*)(c1 + j * 4) = o1[j];
  }
}

// ---------------- combine ----------------
__global__ __launch_bounds__(256) void combine_kernel(
    const u16* __restrict__ sel, const u16* __restrict__ upd,
    const int* __restrict__ keep, const float* __restrict__ tkprob,
    u16* __restrict__ fusedp)
{
  int n = blockIdx.x;
  int t = threadIdx.x;
  float kp0 = keep[2 * n] ? 1.f : 0.f, kp1 = keep[2 * n + 1] ? 1.f : 0.f;
  float p0 = tkprob[2 * n] * kp0, p1 = tkprob[2 * n + 1] * kp1;
  float s = fmaxf(p0 + p1, 1e-12f);
  float w0 = p0 / s, w1 = p1 / s;
  int d0 = t * 4;
  u16x4 s0 = *(const u16x4*)(sel + (size_t)(2 * n) * Dv + d0);
  u16x4 s1 = *(const u16x4*)(sel + (size_t)(2 * n + 1) * Dv + d0);
  u16x4 u0 = *(const u16x4*)(upd + (size_t)(2 * n) * Dv + d0);
  u16x4 u1 = *(const u16x4*)(upd + (size_t)(2 * n + 1) * Dv + d0);
  u16x4 o;
  #pragma unroll
  for (int j = 0; j < 4; ++j) {
    float r0 = (bf2f(s0[j]) + bf2f(u0[j])) * kp0;
    float r1 = (bf2f(s1[j]) + bf2f(u1[j])) * kp1;
    o[j] = f2bf(w0 * r0 + w1 * r1);
  }
  *(u16x4*)(fusedp + (size_t)n * Dv + d0) = o;
}

extern "C" void kernel_launch(void* const* d_in, const int* in_sizes, int n_in,
                              void* d_out, int out_size, void* d_ws, size_t ws_size,
                              hipStream_t stream) {
  const float* x      = (const float*)d_in[0];
  const float* gate_w = (const float*)d_in[1];
  const float* w13    = (const float*)d_in[2];
  const float* w2     = (const float*)d_in[3];
  const float* msg_w  = (const float*)d_in[4];
  const float* q_w    = (const float*)d_in[5];
  const float* k_w    = (const float*)d_in[6];
  const float* upd_w1 = (const float*)d_in[7];
  const float* upd_w2 = (const float*)d_in[8];
  const float* o_w    = (const float*)d_in[9];
  float* out = (float*)d_out;
  float* outAux = out + (size_t)Nv * Dv;
  float* outIdx = outAux + 1;

  char* ws = (char*)d_ws;
  const size_t MBc = 1ull << 20;
  int*   tkidx  = (int*)(ws + 0);
  float* tkprob = (float*)(ws + 32768);
  int*   keepA  = (int*)(ws + 65536);
  int*   dstNK  = (int*)(ws + 98304);
  float* red    = (float*)(ws + 143360);
  // phase A (fp8 experts):
  u8*  BUF8  = (u8*)(ws + 1 * MBc);
  u8*  ACT8  = (u8*)(ws + 12 * MBc);
  u8*  W13B8 = (u8*)(ws + 41 * MBc);
  u8*  W2B8  = (u8*)(ws + 41 * MBc);
  u16* SEL   = (u16*)(ws + 120 * MBc);   // 16 MB (bf16, lives to combine)
  u8*  SEL8  = (u8*)(ws + 136 * MBc);    //  8 MB
  u8*  MSGQ8 = (u8*)(ws + 144 * MBc);    //  2 MB
  u8*  KB8   = (u8*)(ws + 146 * MBc);    //  1 MB
  u16* OB    = (u16*)(ws + 147 * MBc);   //  2 MB (bf16 o_w)
  u8*  UPD1B8= (u8*)(ws + 149 * MBc);    //  4 MB
  u8*  UPD2B8= (u8*)(ws + 153 * MBc);    //  2 MB
  // phase B overlays (expert buffers dead after G2):
  u8*  MQ8   = (u8*)(ws + 1 * MBc);      // 16 MB
  u8*  KK8   = (u8*)(ws + 17 * MBc);     //  8 MB
  u8*  CMSG8 = (u8*)(ws + 25 * MBc);     //  8 MB
  u8*  G1B8  = (u8*)(ws + 33 * MBc);     // 16 MB
  u16* UPD   = (u16*)(ws + 49 * MBc);    // 16 MB
  u16* FUSEDP= (u16*)(ws + 65 * MBc);    //  8 MB

  hipMemsetAsync(red, 0, 68, stream);
  hipMemsetAsync(dstNK, 0xFF, Ev * CAPv * 4, stream);

  router_kernel<<<Nv / 4, 256, 0, stream>>>(x, gate_w, tkidx, tkprob, red, outIdx);
  aux_kernel<<<1, 1, 0, stream>>>(red, outAux);
  rank_kernel<<<1, 256, 0, stream>>>(tkidx, keepA, dstNK);
  pack8_kernel<<<(Ev * CAPv) / 4, 256, 0, stream>>>(x, dstNK, BUF8);

  // G1: w13 -> fp8 (x16, HW scale 2^-4), MX-fp8 SwiGLU GEMM -> ACT8
  tconv8_kernel<<<dim3(TH2v / 64, Dv / 64, Ev), 256, 0, stream>>>(w13, W13B8, Dv, TH2v, 16.f);
  gemm256f8<1><<<dim3((CAPv / 256) * (Hv / 128), Ev), 512, 0, stream>>>(
      BUF8, BUF8, 1 << 30, W13B8, (void*)ACT8, nullptr, nullptr,
      Dv, Dv, Dv, Hv, CAPv / 256,
      (size_t)CAPv * Dv, (size_t)TH2v * Dv, (size_t)CAPv * Hv, 0x7B7B7B7Bu);

  hipMemsetAsync(SEL, 0, (size_t)NKv * Dv * 2, stream);
  hipMemsetAsync(SEL8, 0, (size_t)NKv * Dv, stream);
  tconv8_kernel<<<dim3(Dv / 64, Hv / 64, Ev), 256, 0, stream>>>(w2, W2B8, Hv, Dv, 16.f);
  tconv8_kernel<<<dim3(16, 16, 1), 256, 0, stream>>>(msg_w, MSGQ8, Dv, Dv, 16.f);
  tconv8_kernel<<<dim3(16, 16, 1), 256, 0, stream>>>(q_w, MSGQ8 + (size_t)Dv * Dv, Dv, Dv, 16.f);
  tconv8_kernel<<<dim3(16, 16, 1), 256, 0, stream>>>(k_w, KB8, Dv, Dv, 16.f);
  tconv_kernel<<<dim3(16, 16, 1), 256, 0, stream>>>(o_w, OB, Dv, Dv);
  tconv8_kernel<<<dim3(32, 32, 1), 256, 0, stream>>>(upd_w1, UPD1B8, 2048, 2048, 16.f);
  tconv8_kernel<<<dim3(16, 32, 1), 256, 0, stream>>>(upd_w2, UPD2B8, 2048, Dv, 16.f);

  // G2: MX-fp8 GEMM + dual scatter -> SEL (bf16) + SEL8 (fp8)
  gemm256f8<2><<<dim3((CAPv / 256) * (Dv / 256), Ev), 512, 0, stream>>>(
      ACT8, ACT8, 1 << 30, W2B8, (void*)SEL, (void*)SEL8, dstNK,
      Hv, Hv, Hv, Dv, CAPv / 256,
      (size_t)CAPv * Hv, (size_t)Dv * Hv, 0, 0x7B7B7B7Bu);

  // collaboration (fp8): fused [M|Q], then Kk, then scores
  gemm256f8<4><<<dim3(32 * 8, 1), 512, 0, stream>>>(
      SEL8, SEL8, 1 << 30, MSGQ8, (void*)MQ8, nullptr, nullptr,
      Dv, Dv, Dv, 2048, 32, 0, 0, 0, 0x7B7B7B7Bu);
  gemm256f8<4><<<dim3(32 * 4, 1), 512, 0, stream>>>(
      MQ8, MQ8, 1 << 30, KB8, (void*)KK8, nullptr, nullptr,
      Dv, 2048, Dv, Dv, 32, 0, 0, 0, 0x7B7B7B7Bu);
  scores8_kernel<<<Nv / 4, 256, 0, stream>>>(MQ8, KK8, keepA, CMSG8);

  // update MLP (fp8): cat = [SEL8 | CMSG8] via split-K, gelu -> fp8, then -> bf16
  gemm256f8<5><<<dim3(32 * 8, 1), 512, 0, stream>>>(
      SEL8, CMSG8, Dv, UPD1B8, (void*)G1B8, nullptr, nullptr,
      2048, Dv, 2048, 2048, 32, 0, 0, 0, 0x7B7B7B7Bu);
  gemm256f8<0><<<dim3(32 * 4, 1), 512, 0, stream>>>(
      G1B8, G1B8, 1 << 30, UPD2B8, (void*)UPD, nullptr, nullptr,
      2048, 2048, 2048, Dv, 32, 0, 0, 0, 0x7B7B7B7Bu);

  combine_kernel<<<Nv, 256, 0, stream>>>(SEL, UPD, keepA, tkprob, FUSEDP);

  gemm128<<<dim3(32 * 8, 1), 256, 0, stream>>>(FUSEDP, OB, out, Dv, Dv, Dv, Dv, 32);

  (void)in_sizes; (void)n_in; (void)out_size; (void)ws_size;
}

// Round 9
// 513.762 us; speedup vs baseline: 1.3096x; 1.0452x over previous
//
#include <hip/hip_runtime.h>
#include <math.h>

#define Dv 1024
#define Ev 8
#define Hv 2816
#define Nv 4096
#define NKv 8192
#define CAPv 1280
#define TH2v 5632

typedef unsigned short u16;
typedef unsigned char u8;
typedef __attribute__((ext_vector_type(8))) short s16x8;
typedef __attribute__((ext_vector_type(4))) float f32x4;
typedef __attribute__((ext_vector_type(4))) int i32x4;
typedef __attribute__((ext_vector_type(8))) int i32x8;
typedef __attribute__((ext_vector_type(8))) u16 u16x8;
typedef __attribute__((ext_vector_type(4))) u16 u16x4;

typedef const __attribute__((address_space(1))) void* as1_cvp;
typedef __attribute__((address_space(3))) void* as3_vp;

__device__ __forceinline__ u16 f2bf(float f) {
  unsigned u = __float_as_uint(f);
  u += 0x7fffu + ((u >> 16) & 1u);
  return (u16)(u >> 16);
}
__device__ __forceinline__ float bf2f(u16 h) {
  return __uint_as_float(((unsigned)h) << 16);
}
// f32 -> OCP e4m3fn, RNE, saturate to 448
__device__ __forceinline__ unsigned f2e4(float f) {
  unsigned u = __float_as_uint(f);
  unsigned sgn = (u >> 24) & 0x80u;
  unsigned ax = u & 0x7FFFFFFFu;
  if (ax >= 0x43E00000u) return sgn | 0x7Eu;
  if (ax < 0x3C800000u) {
    int qv = (int)rintf(__uint_as_float(ax) * 512.f);
    return sgn | (unsigned)qv;
  }
  unsigned lsb = (ax >> 20) & 1u;
  unsigned rr = ax + 0x0007FFFFu + lsb;
  unsigned ee = rr >> 23;
  unsigned mm = (rr >> 20) & 7u;
  if (ee > 135u) return sgn | 0x7Eu;
  return sgn | ((ee - 120u) << 3) | mm;
}
// e4m3fn -> f32
__device__ __forceinline__ float e42f(unsigned v) {
  unsigned s = (v & 0x80u) << 24, e = (v >> 3) & 15u, m = v & 7u;
  if (e) return __uint_as_float(s | ((e + 120u) << 23) | (m << 20));
  return __uint_as_float(__float_as_uint((float)m * 0.001953125f) | s);
}
__device__ __forceinline__ void dec16(const u8* p, float* o) {
  const unsigned* w = (const unsigned*)p;
  #pragma unroll
  for (int j = 0; j < 4; ++j) {
    unsigned x = w[j];
    o[j*4+0] = e42f(x & 255u);
    o[j*4+1] = e42f((x >> 8) & 255u);
    o[j*4+2] = e42f((x >> 16) & 255u);
    o[j*4+3] = e42f((x >> 24) & 255u);
  }
}
__device__ __forceinline__ void gload16(const void* g, void* l) {
  __builtin_amdgcn_global_load_lds((as1_cvp)g, (as3_vp)l, 16, 0, 0);
}

// ---------------- router ----------------
__global__ __launch_bounds__(256) void router_kernel(
    const float* __restrict__ x, const float* __restrict__ gw,
    int* __restrict__ tkidx, float* __restrict__ tkprob,
    float* __restrict__ red, float* __restrict__ outIdx)
{
  __shared__ float lred[17];
  int tid = threadIdx.x;
  if (tid < 17) lred[tid] = 0.f;
  __syncthreads();
  int wv = tid >> 6, ln = tid & 63;
  int n = blockIdx.x * 4 + wv;
  float a[8] = {0.f,0.f,0.f,0.f,0.f,0.f,0.f,0.f};
  const float* xr = x + (size_t)n * Dv;
  #pragma unroll
  for (int it = 0; it < 16; ++it) {
    int d = ln + it * 64;
    float xs = xr[d];
    float4 g0 = *(const float4*)(gw + (size_t)d * 8);
    float4 g1 = *(const float4*)(gw + (size_t)d * 8 + 4);
    a[0] += xs * g0.x; a[1] += xs * g0.y; a[2] += xs * g0.z; a[3] += xs * g0.w;
    a[4] += xs * g1.x; a[5] += xs * g1.y; a[6] += xs * g1.z; a[7] += xs * g1.w;
  }
  #pragma unroll
  for (int off = 32; off >= 1; off >>= 1) {
    #pragma unroll
    for (int e = 0; e < 8; ++e) a[e] += __shfl_xor(a[e], off, 64);
  }
  int i1 = 0; float v1 = a[0];
  #pragma unroll
  for (int e = 1; e < 8; ++e) if (a[e] > v1) { v1 = a[e]; i1 = e; }
  int i2 = -1; float v2 = -1e30f;
  #pragma unroll
  for (int e = 0; e < 8; ++e) if (e != i1 && a[e] > v2) { v2 = a[e]; i2 = e; }
  float Z = 0.f;
  #pragma unroll
  for (int e = 0; e < 8; ++e) Z += expf(a[e] - v1);
  float zlse = v1 + logf(Z);
  float t = expf(v2 - v1);
  float p1 = 1.f / (1.f + t);
  float p2 = t * p1;
  if (ln == 0) {
    tkidx[2*n] = i1; tkidx[2*n+1] = i2;
    tkprob[2*n] = p1; tkprob[2*n+1] = p2;
    outIdx[2*n] = (float)i1; outIdx[2*n+1] = (float)i2;
    #pragma unroll
    for (int e = 0; e < 8; ++e) atomicAdd(&lred[e], expf(a[e] - v1) / Z);
    atomicAdd(&lred[8 + i1], 1.f);
    atomicAdd(&lred[16], zlse * zlse);
  }
  __syncthreads();
  if (tid < 17) atomicAdd(&red[tid], lred[tid]);
}

__global__ void aux_kernel(const float* __restrict__ red, float* __restrict__ outAux) {
  float bl = 0.f;
  for (int e = 0; e < 8; ++e) bl += (red[e] / (float)Nv) * (red[8 + e] / (float)Nv);
  bl *= (float)Ev;
  float zl = red[16] / (float)Nv;
  outAux[0] = 0.01f * bl + 0.001f * zl;
}

// ---------------- exact stable rank ----------------
__global__ __launch_bounds__(256) void rank_kernel(const int* __restrict__ tgt,
    int* __restrict__ keep, int* __restrict__ dstNK)
{
  __shared__ int hist[256][8];
  int t = threadIdx.x;
  int h[8] = {0,0,0,0,0,0,0,0};
  int base = t * 32;
  for (int j = 0; j < 32; ++j) h[tgt[base + j]]++;
  for (int e = 0; e < 8; ++e) hist[t][e] = h[e];
  __syncthreads();
  if (t < 8) {
    int run = 0;
    for (int tt = 0; tt < 256; ++tt) { int v = hist[tt][t]; hist[tt][t] = run; run += v; }
  }
  __syncthreads();
  for (int e = 0; e < 8; ++e) h[e] = hist[t][e];
  for (int j = 0; j < 32; ++j) {
    int i = base + j; int e = tgt[i]; int r = h[e]++;
    int kp = (r < CAPv) ? 1 : 0;
    keep[i] = kp;
    if (kp) dstNK[e * CAPv + r] = i;
  }
}

// ---------------- pack tokens -> fp8 ----------------
__global__ __launch_bounds__(256) void pack8_kernel(const float* __restrict__ x,
    const int* __restrict__ dstNK, u8* __restrict__ buf)
{
  int s = blockIdx.x * 4 + (threadIdx.x >> 6);
  int ln = threadIdx.x & 63;
  int i = dstNK[s];
  u8* dst = buf + (size_t)s * Dv;
  if (i >= 0) {
    const float* src = x + (size_t)(i >> 1) * Dv;
    #pragma unroll
    for (int j = 0; j < 4; ++j) {
      int d0 = ln * 16 + j * 4;
      float4 v = *(const float4*)(src + d0);
      unsigned w = f2e4(v.x) | (f2e4(v.y) << 8) | (f2e4(v.z) << 16) | (f2e4(v.w) << 24);
      *(unsigned*)(dst + d0) = w;
    }
  } else {
    #pragma unroll
    for (int j = 0; j < 4; ++j) *(unsigned*)(dst + ln * 16 + j * 4) = 0u;
  }
}

// ---------------- transpose + f32->bf16 ----------------
__global__ __launch_bounds__(256) void tconv_kernel(const float* __restrict__ in,
    u16* __restrict__ out, int R, int C)
{
  __shared__ u16 tile[64][68];
  size_t zoff = (size_t)blockIdx.z * (size_t)R * (size_t)C;
  in += zoff; out += zoff;
  int r0 = blockIdx.y * 64, c0 = blockIdx.x * 64;
  int t = threadIdx.x;
  int cc4 = (t & 15) * 4;
  #pragma unroll
  for (int p = 0; p < 4; ++p) {
    int r = (t >> 4) + p * 16;
    float4 v = *(const float4*)(in + (size_t)(r0 + r) * C + c0 + cc4);
    u16x4 b; b[0]=f2bf(v.x); b[1]=f2bf(v.y); b[2]=f2bf(v.z); b[3]=f2bf(v.w);
    *(u16x4*)(&tile[r][cc4]) = b;
  }
  __syncthreads();
  int rr4 = (t & 15) * 4;
  #pragma unroll
  for (int p = 0; p < 4; ++p) {
    int c = (t >> 4) + p * 16;
    u16x4 o; o[0]=tile[rr4][c]; o[1]=tile[rr4+1][c]; o[2]=tile[rr4+2][c]; o[3]=tile[rr4+3][c];
    *(u16x4*)(out + (size_t)(c0 + c) * R + r0 + rr4) = o;
  }
}

// ---------------- transpose + f32->e4m3 (xsmul) ----------------
__global__ __launch_bounds__(256) void tconv8_kernel(const float* __restrict__ in,
    u8* __restrict__ out, int R, int C, float smul)
{
  __shared__ u8 tile[64][68];
  size_t zoff = (size_t)blockIdx.z * (size_t)R * (size_t)C;
  in += zoff; out += zoff;
  int r0 = blockIdx.y * 64, c0 = blockIdx.x * 64;
  int t = threadIdx.x;
  int cc4 = (t & 15) * 4;
  #pragma unroll
  for (int p = 0; p < 4; ++p) {
    int r = (t >> 4) + p * 16;
    float4 v = *(const float4*)(in + (size_t)(r0 + r) * C + c0 + cc4);
    unsigned w = f2e4(v.x * smul) | (f2e4(v.y * smul) << 8)
               | (f2e4(v.z * smul) << 16) | (f2e4(v.w * smul) << 24);
    *(unsigned*)(&tile[r][cc4]) = w;
  }
  __syncthreads();
  int rr4 = (t & 15) * 4;
  #pragma unroll
  for (int p = 0; p < 4; ++p) {
    int c = (t >> 4) + p * 16;
    unsigned w = (unsigned)tile[rr4][c] | ((unsigned)tile[rr4+1][c] << 8)
               | ((unsigned)tile[rr4+2][c] << 16) | ((unsigned)tile[rr4+3][c] << 24);
    *(unsigned*)(out + (size_t)(c0 + c) * R + r0 + rr4) = w;
  }
}

// ===== 128x128 4-wave MX-fp8 GEMM (m97/m148 structure), BK=128, single-buffer =====
// LDS 32KB -> 3-4 blocks/CU for TLP overlap. Chunk-permute P verified round 6.
// MODE 0: bf16 out  1: SwiGLU -> fp8  2: dual scatter bf16+fp8
// MODE 4: fp8 out   5: gelu -> fp8 (split-K A)
template<int MODE>
__global__ __launch_bounds__(256) void gemm128f8(
    const u8* __restrict__ A, const u8* __restrict__ A2, int splitK,
    const u8* __restrict__ B, void* __restrict__ C, void* __restrict__ C2,
    const int* __restrict__ dst, int Ksz, int lda, int ldb, int ldc, int ntm,
    size_t sA, size_t sB, size_t sC, unsigned sclB)
{
  __shared__ char smem[32768];  // A [0,16K), B [16K,32K)
  int e = blockIdx.y;
  int nwgx = gridDim.x, bid0 = blockIdx.x;
  int q = nwgx >> 3, r = nwgx & 7;
  int xcd = bid0 & 7, lo2 = bid0 >> 3;
  int bid = (xcd < r ? xcd * (q + 1) : r * (q + 1) + (xcd - r) * q) + lo2;
  int tm = bid % ntm, tn = bid / ntm;
  const u8* Ae = A + (size_t)e * sA;
  const u8* Be = B + (size_t)e * sB;
  long long bdelta = (const char*)A2 - (const char*)Ae;
  int tid = threadIdx.x, wv = tid >> 6, ln = tid & 63;
  int lnl = ln & 15, lnh = ln >> 4;

  // staging: pass i covers rows i*32 + wv*8 + (ln>>3); slot = ln&7;
  // source chunk = P(slot ^ (row&7)), P(c) = ((c&3)<<1)|(c>>2)
  const u8* aP[4]; const u8* bP[4];
  unsigned aL[4], bL[4];
  #pragma unroll
  for (int i = 0; i < 4; ++i) {
    int row = i * 32 + wv * 8 + (ln >> 3);
    int c = (ln & 7) ^ (row & 7);
    int cp = ((c & 3) << 1) | (c >> 2);
    aP[i] = Ae + (size_t)(tm * 128 + row) * lda + cp * 16;
    int brow;
    if (MODE == 1) {
      brow = (row < 64) ? (tn * 64 + row) : (Hv + tn * 64 + (row - 64));
    } else {
      brow = tn * 128 + row;
    }
    bP[i] = Be + (size_t)brow * ldb + cp * 16;
    aL[i] = i * 4096 + wv * 1024;
    bL[i] = 16384 + i * 4096 + wv * 1024;
  }

  int arow0 = wv * 32 + lnl;
  int ksw0 = (lnh << 4);
  int ksw1 = 64 + (lnh << 4);

  f32x4 acc[2][8];
  #pragma unroll
  for (int m = 0; m < 2; ++m)
    #pragma unroll
    for (int n = 0; n < 8; ++n) acc[m][n] = (f32x4){0.f, 0.f, 0.f, 0.f};

  for (int k0 = 0; k0 < Ksz; k0 += 128) {
    long long kbA;
    if (MODE == 5 && k0 >= splitK) kbA = bdelta + (long long)(k0 - splitK);
    else kbA = (long long)k0;
    #pragma unroll
    for (int i = 0; i < 4; ++i) gload16(aP[i] + kbA, smem + aL[i]);
    #pragma unroll
    for (int i = 0; i < 4; ++i) gload16(bP[i] + (size_t)k0, smem + bL[i]);
    __syncthreads();

    i32x8 af[2];
    #pragma unroll
    for (int mi = 0; mi < 2; ++mi) {
      int row = arow0 + mi * 16;
      int swz = (row & 7) << 4;
      *(i32x4*)&af[mi] = *(const i32x4*)(smem + row * 128 + (ksw0 ^ swz));
      *((i32x4*)&af[mi] + 1) = *(const i32x4*)(smem + row * 128 + (ksw1 ^ swz));
    }
    #pragma unroll
    for (int n = 0; n < 8; ++n) {
      int row = n * 16 + lnl;
      int swz = (row & 7) << 4;
      i32x8 bf;
      *(i32x4*)&bf = *(const i32x4*)(smem + 16384 + row * 128 + (ksw0 ^ swz));
      *((i32x4*)&bf + 1) = *(const i32x4*)(smem + 16384 + row * 128 + (ksw1 ^ swz));
      acc[0][n] = __builtin_amdgcn_mfma_scale_f32_16x16x128_f8f6f4(
          af[0], bf, acc[0][n], 0, 0, 0, 0x7F7F7F7Fu, 0, sclB);
      acc[1][n] = __builtin_amdgcn_mfma_scale_f32_16x16x128_f8f6f4(
          af[1], bf, acc[1][n], 0, 0, 0, 0x7F7F7F7Fu, 0, sclB);
    }
    __syncthreads();
  }

  int rbase = tm * 128 + wv * 32 + (lnh << 2);
  if (MODE == 0) {
    u16* Cp = (u16*)C;
    #pragma unroll
    for (int mi = 0; mi < 2; ++mi)
      #pragma unroll
      for (int n = 0; n < 8; ++n) {
        int col = tn * 128 + n * 16 + lnl;
        #pragma unroll
        for (int v = 0; v < 4; ++v)
          Cp[(size_t)(rbase + mi * 16 + v) * ldc + col] = f2bf(acc[mi][n][v]);
      }
  } else if (MODE == 1) {
    u8* Cp = (u8*)C + (size_t)e * sC;
    #pragma unroll
    for (int mi = 0; mi < 2; ++mi)
      #pragma unroll
      for (int n = 0; n < 4; ++n) {
        int col = tn * 64 + n * 16 + lnl;
        #pragma unroll
        for (int v = 0; v < 4; ++v) {
          float g = acc[mi][n][v];
          float u = acc[mi][n + 4][v];
          float sg = g / (1.f + __expf(-g));
          Cp[(size_t)(rbase + mi * 16 + v) * ldc + col] = (u8)f2e4(sg * u);
        }
      }
  } else if (MODE == 2) {
    u16* Cp = (u16*)C;
    u8* Cq = (u8*)C2;
    #pragma unroll
    for (int mi = 0; mi < 2; ++mi)
      #pragma unroll
      for (int v = 0; v < 4; ++v) {
        int gr = rbase + mi * 16 + v;
        int i = dst[e * CAPv + gr];
        if (i >= 0) {
          #pragma unroll
          for (int n = 0; n < 8; ++n) {
            int col = tn * 128 + n * 16 + lnl;
            float x = acc[mi][n][v];
            Cp[(size_t)i * Dv + col] = f2bf(x);
            Cq[(size_t)i * Dv + col] = (u8)f2e4(x);
          }
        }
      }
  } else if (MODE == 4) {
    u8* Cp = (u8*)C;
    #pragma unroll
    for (int mi = 0; mi < 2; ++mi)
      #pragma unroll
      for (int n = 0; n < 8; ++n) {
        int col = tn * 128 + n * 16 + lnl;
        #pragma unroll
        for (int v = 0; v < 4; ++v)
          Cp[(size_t)(rbase + mi * 16 + v) * ldc + col] = (u8)f2e4(acc[mi][n][v]);
      }
  } else {
    u8* Cp = (u8*)C;
    #pragma unroll
    for (int mi = 0; mi < 2; ++mi)
      #pragma unroll
      for (int n = 0; n < 8; ++n) {
        int col = tn * 128 + n * 16 + lnl;
        #pragma unroll
        for (int v = 0; v < 4; ++v) {
          float xg = acc[mi][n][v];
          float gl = 0.5f * xg * (1.f + erff(xg * 0.70710678118654752f));
          Cp[(size_t)(rbase + mi * 16 + v) * ldc + col] = (u8)f2e4(gl);
        }
      }
  }
}

// ---------------- 128x128 bf16 GEMM (final projection, f32 out) ----------------
__global__ __launch_bounds__(256) void gemm128(
    const u16* __restrict__ A, const u16* __restrict__ B, float* __restrict__ C,
    int Ksz, int lda, int ldb, int ldc, int ntm)
{
  __shared__ char smem[32768];
  int bid = blockIdx.x;
  int tm = bid % ntm, tn = bid / ntm;
  int tid = threadIdx.x, wv = tid >> 6, ln = tid & 63;

  const char* aP[4]; const char* bP[4];
  unsigned aL[4], bL[4];
  #pragma unroll
  for (int r = 0; r < 4; ++r) {
    int lb = r * 4096 + tid * 16;
    int row = lb >> 7;
    int colb = (lb & 127) ^ ((row & 7) << 4);
    aP[r] = (const char*)(A + (size_t)(tm * 128 + row) * lda) + colb;
    bP[r] = (const char*)(B + (size_t)(tn * 128 + row) * ldb) + colb;
    aL[r] = r * 4096 + wv * 1024;
    bL[r] = 16384 + r * 4096 + wv * 1024;
  }

  f32x4 acc[2][8];
  #pragma unroll
  for (int m = 0; m < 2; ++m)
    #pragma unroll
    for (int n = 0; n < 8; ++n) acc[m][n] = (f32x4){0.f, 0.f, 0.f, 0.f};

  for (int k0 = 0; k0 < Ksz; k0 += 64) {
    size_t kbb = (size_t)k0 * 2;
    #pragma unroll
    for (int r = 0; r < 4; ++r) gload16(aP[r] + kbb, smem + aL[r]);
    #pragma unroll
    for (int r = 0; r < 4; ++r) gload16(bP[r] + kbb, smem + bL[r]);
    __syncthreads();
    #pragma unroll
    for (int ks = 0; ks < 2; ++ks) {
      int kbyte = ks * 64 + ((ln >> 4) << 4);
      s16x8 av[2];
      #pragma unroll
      for (int m = 0; m < 2; ++m) {
        int row = wv * 32 + m * 16 + (ln & 15);
        av[m] = *(const s16x8*)(smem + (row << 7) + (kbyte ^ ((row & 7) << 4)));
      }
      #pragma unroll
      for (int n = 0; n < 8; ++n) {
        int row = n * 16 + (ln & 15);
        s16x8 bv = *(const s16x8*)(smem + 16384 + (row << 7) + (kbyte ^ ((row & 7) << 4)));
        acc[0][n] = __builtin_amdgcn_mfma_f32_16x16x32_bf16(av[0], bv, acc[0][n], 0, 0, 0);
        acc[1][n] = __builtin_amdgcn_mfma_f32_16x16x32_bf16(av[1], bv, acc[1][n], 0, 0, 0);
      }
    }
    __syncthreads();
  }

  int rbase = tm * 128 + wv * 32 + ((ln >> 4) << 2);
  int cb = (ln & 15);
  #pragma unroll
  for (int m = 0; m < 2; ++m)
    #pragma unroll
    for (int n = 0; n < 8; ++n)
      #pragma unroll
      for (int v = 0; v < 4; ++v)
        C[(size_t)(rbase + m * 16 + v) * ldc + tn * 128 + n * 16 + cb] = acc[m][n][v];
}

// ---------------- per-token scores + masked softmax + Cmsg (fp8) ----------------
__global__ __launch_bounds__(256) void scores8_kernel(
    const u8* __restrict__ MQ, const u8* __restrict__ KK,
    const int* __restrict__ keep, u8* __restrict__ Cmsg)
{
  int wv = threadIdx.x >> 6, ln = threadIdx.x & 63;
  int n = blockIdx.x * 4 + wv;
  const u8* m0 = MQ + (size_t)(2 * n) * 2048;
  const u8* m1 = MQ + (size_t)(2 * n + 1) * 2048;
  const u8* q0 = m0 + 1024;
  const u8* q1 = m1 + 1024;
  const u8* k0p = KK + (size_t)(2 * n) * 1024;
  const u8* k1p = KK + (size_t)(2 * n + 1) * 1024;
  int d0 = ln * 16;
  float a0[16], a1[16], b0[16], b1[16];
  dec16(q0 + d0, a0); dec16(q1 + d0, a1);
  dec16(k0p + d0, b0); dec16(k1p + d0, b1);
  float s00 = 0, s01 = 0, s10 = 0, s11 = 0;
  #pragma unroll
  for (int t = 0; t < 16; ++t) {
    s00 += a0[t] * b0[t]; s01 += a0[t] * b1[t];
    s10 += a1[t] * b0[t]; s11 += a1[t] * b1[t];
  }
  #pragma unroll
  for (int off = 32; off >= 1; off >>= 1) {
    s00 += __shfl_xor(s00, off, 64);
    s01 += __shfl_xor(s01, off, 64);
    s10 += __shfl_xor(s10, off, 64);
    s11 += __shfl_xor(s11, off, 64);
  }
  const float inv = 0.03125f;
  int kp0 = keep[2 * n], kp1 = keep[2 * n + 1];
  float A00, A01, A10, A11;
  {
    float v0 = kp0 ? s00 * inv : -1e9f;
    float v1 = (kp0 && kp1) ? s01 * inv : -1e9f;
    float mx = fmaxf(v0, v1);
    float e0 = expf(v0 - mx), e1 = expf(v1 - mx);
    float den = e0 + e1;
    float a0v = kp0 ? e0 / den : 0.f;
    float a1v = (kp0 && kp1) ? e1 / den : 0.f;
    float s = fmaxf(a0v + a1v, 1e-12f);
    A00 = a0v / s; A01 = a1v / s;
  }
  {
    float v0 = (kp1 && kp0) ? s10 * inv : -1e9f;
    float v1 = kp1 ? s11 * inv : -1e9f;
    float mx = fmaxf(v0, v1);
    float e0 = expf(v0 - mx), e1 = expf(v1 - mx);
    float den = e0 + e1;
    float a0v = (kp1 && kp0) ? e0 / den : 0.f;
    float a1v = kp1 ? e1 / den : 0.f;
    float s = fmaxf(a0v + a1v, 1e-12f);
    A10 = a0v / s; A11 = a1v / s;
  }
  float f0[16], f1[16];
  dec16(m0 + d0, f0); dec16(m1 + d0, f1);
  unsigned o0[4], o1[4];
  #pragma unroll
  for (int j = 0; j < 4; ++j) {
    o0[j] = 0; o1[j] = 0;
    #pragma unroll
    for (int b = 0; b < 4; ++b) {
      int t = j * 4 + b;
      o0[j] |= f2e4(A00 * f0[t] + A01 * f1[t]) << (8 * b);
      o1[j] |= f2e4(A10 * f0[t] + A11 * f1[t]) << (8 * b);
    }
  }
  u8* c0 = Cmsg + (size_t)(2 * n) * 1024 + d0;
  u8* c1 = Cmsg + (size_t)(2 * n + 1) * 1024 + d0;
  #pragma unroll
  for (int j = 0; j < 4; ++j) {
    *(unsigned*)(c0 + j * 4) = o0[j];
    *(unsigned*)(c1 + j * 4) = o1[j];
  }
}

// ---------------- combine ----------------
__global__ __launch_bounds__(256) void combine_kernel(
    const u16* __restrict__ sel, const u16* __restrict__ upd,
    const int* __restrict__ keep, const float* __restrict__ tkprob,
    u16* __restrict__ fusedp)
{
  int n = blockIdx.x;
  int t = threadIdx.x;
  float kp0 = keep[2 * n] ? 1.f : 0.f, kp1 = keep[2 * n + 1] ? 1.f : 0.f;
  float p0 = tkprob[2 * n] * kp0, p1 = tkprob[2 * n + 1] * kp1;
  float s = fmaxf(p0 + p1, 1e-12f);
  float w0 = p0 / s, w1 = p1 / s;
  int d0 = t * 4;
  u16x4 s0 = *(const u16x4*)(sel + (size_t)(2 * n) * Dv + d0);
  u16x4 s1 = *(const u16x4*)(sel + (size_t)(2 * n + 1) * Dv + d0);
  u16x4 u0 = *(const u16x4*)(upd + (size_t)(2 * n) * Dv + d0);
  u16x4 u1 = *(const u16x4*)(upd + (size_t)(2 * n + 1) * Dv + d0);
  u16x4 o;
  #pragma unroll
  for (int j = 0; j < 4; ++j) {
    float r0 = (bf2f(s0[j]) + bf2f(u0[j])) * kp0;
    float r1 = (bf2f(s1[j]) + bf2f(u1[j])) * kp1;
    o[j] = f2bf(w0 * r0 + w1 * r1);
  }
  *(u16x4*)(fusedp + (size_t)n * Dv + d0) = o;
}

extern "C" void kernel_launch(void* const* d_in, const int* in_sizes, int n_in,
                              void* d_out, int out_size, void* d_ws, size_t ws_size,
                              hipStream_t stream) {
  const float* x      = (const float*)d_in[0];
  const float* gate_w = (const float*)d_in[1];
  const float* w13    = (const float*)d_in[2];
  const float* w2     = (const float*)d_in[3];
  const float* msg_w  = (const float*)d_in[4];
  const float* q_w    = (const float*)d_in[5];
  const float* k_w    = (const float*)d_in[6];
  const float* upd_w1 = (const float*)d_in[7];
  const float* upd_w2 = (const float*)d_in[8];
  const float* o_w    = (const float*)d_in[9];
  float* out = (float*)d_out;
  float* outAux = out + (size_t)Nv * Dv;
  float* outIdx = outAux + 1;

  char* ws = (char*)d_ws;
  const size_t MBc = 1ull << 20;
  int*   tkidx  = (int*)(ws + 0);
  float* tkprob = (float*)(ws + 32768);
  int*   keepA  = (int*)(ws + 65536);
  int*   dstNK  = (int*)(ws + 98304);
  float* red    = (float*)(ws + 143360);
  // phase A (fp8 experts):
  u8*  BUF8  = (u8*)(ws + 1 * MBc);
  u8*  ACT8  = (u8*)(ws + 12 * MBc);
  u8*  W13B8 = (u8*)(ws + 41 * MBc);
  u8*  W2B8  = (u8*)(ws + 41 * MBc);
  u16* SEL   = (u16*)(ws + 120 * MBc);
  u8*  SEL8  = (u8*)(ws + 136 * MBc);
  u8*  MSGQ8 = (u8*)(ws + 144 * MBc);
  u8*  KB8   = (u8*)(ws + 146 * MBc);
  u16* OB    = (u16*)(ws + 147 * MBc);
  u8*  UPD1B8= (u8*)(ws + 149 * MBc);
  u8*  UPD2B8= (u8*)(ws + 153 * MBc);
  // phase B overlays:
  u8*  MQ8   = (u8*)(ws + 1 * MBc);
  u8*  KK8   = (u8*)(ws + 17 * MBc);
  u8*  CMSG8 = (u8*)(ws + 25 * MBc);
  u8*  G1B8  = (u8*)(ws + 33 * MBc);
  u16* UPD   = (u16*)(ws + 49 * MBc);
  u16* FUSEDP= (u16*)(ws + 65 * MBc);

  hipMemsetAsync(red, 0, 68, stream);
  hipMemsetAsync(dstNK, 0xFF, Ev * CAPv * 4, stream);

  router_kernel<<<Nv / 4, 256, 0, stream>>>(x, gate_w, tkidx, tkprob, red, outIdx);
  aux_kernel<<<1, 1, 0, stream>>>(red, outAux);
  rank_kernel<<<1, 256, 0, stream>>>(tkidx, keepA, dstNK);
  pack8_kernel<<<(Ev * CAPv) / 4, 256, 0, stream>>>(x, dstNK, BUF8);

  // G1: w13 -> fp8 (x16, HW scale 2^-4), MX-fp8 SwiGLU GEMM -> ACT8
  tconv8_kernel<<<dim3(TH2v / 64, Dv / 64, Ev), 256, 0, stream>>>(w13, W13B8, Dv, TH2v, 16.f);
  gemm128f8<1><<<dim3((CAPv / 128) * (Hv / 64), Ev), 256, 0, stream>>>(
      BUF8, BUF8, 1 << 30, W13B8, (void*)ACT8, nullptr, nullptr,
      Dv, Dv, Dv, Hv, CAPv / 128,
      (size_t)CAPv * Dv, (size_t)TH2v * Dv, (size_t)CAPv * Hv, 0x7B7B7B7Bu);

  hipMemsetAsync(SEL, 0, (size_t)NKv * Dv * 2, stream);
  hipMemsetAsync(SEL8, 0, (size_t)NKv * Dv, stream);
  tconv8_kernel<<<dim3(Dv / 64, Hv / 64, Ev), 256, 0, stream>>>(w2, W2B8, Hv, Dv, 16.f);
  tconv8_kernel<<<dim3(16, 16, 1), 256, 0, stream>>>(msg_w, MSGQ8, Dv, Dv, 16.f);
  tconv8_kernel<<<dim3(16, 16, 1), 256, 0, stream>>>(q_w, MSGQ8 + (size_t)Dv * Dv, Dv, Dv, 16.f);
  tconv8_kernel<<<dim3(16, 16, 1), 256, 0, stream>>>(k_w, KB8, Dv, Dv, 16.f);
  tconv_kernel<<<dim3(16, 16, 1), 256, 0, stream>>>(o_w, OB, Dv, Dv);
  tconv8_kernel<<<dim3(32, 32, 1), 256, 0, stream>>>(upd_w1, UPD1B8, 2048, 2048, 16.f);
  tconv8_kernel<<<dim3(16, 32, 1), 256, 0, stream>>>(upd_w2, UPD2B8, 2048, Dv, 16.f);

  // G2: MX-fp8 GEMM + dual scatter -> SEL (bf16) + SEL8 (fp8)
  gemm128f8<2><<<dim3((CAPv / 128) * (Dv / 128), Ev), 256, 0, stream>>>(
      ACT8, ACT8, 1 << 30, W2B8, (void*)SEL, (void*)SEL8, dstNK,
      Hv, Hv, Hv, Dv, CAPv / 128,
      (size_t)CAPv * Hv, (size_t)Dv * Hv, 0, 0x7B7B7B7Bu);

  // collaboration (fp8): fused [M|Q], then Kk, then scores
  gemm128f8<4><<<dim3(64 * 16, 1), 256, 0, stream>>>(
      SEL8, SEL8, 1 << 30, MSGQ8, (void*)MQ8, nullptr, nullptr,
      Dv, Dv, Dv, 2048, 64, 0, 0, 0, 0x7B7B7B7Bu);
  gemm128f8<4><<<dim3(64 * 8, 1), 256, 0, stream>>>(
      MQ8, MQ8, 1 << 30, KB8, (void*)KK8, nullptr, nullptr,
      Dv, 2048, Dv, Dv, 64, 0, 0, 0, 0x7B7B7B7Bu);
  scores8_kernel<<<Nv / 4, 256, 0, stream>>>(MQ8, KK8, keepA, CMSG8);

  // update MLP (fp8): cat = [SEL8 | CMSG8] via split-K, gelu -> fp8, then -> bf16
  gemm128f8<5><<<dim3(64 * 16, 1), 256, 0, stream>>>(
      SEL8, CMSG8, Dv, UPD1B8, (void*)G1B8, nullptr, nullptr,
      2048, Dv, 2048, 2048, 64, 0, 0, 0, 0x7B7B7B7Bu);
  gemm128f8<0><<<dim3(64 * 8, 1), 256, 0, stream>>>(
      G1B8, G1B8, 1 << 30, UPD2B8, (void*)UPD, nullptr, nullptr,
      2048, 2048, 2048, Dv, 64, 0, 0, 0, 0x7B7B7B7Bu);

  combine_kernel<<<Nv, 256, 0, stream>>>(SEL, UPD, keepA, tkprob, FUSEDP);

  gemm128<<<dim3(32 * 8, 1), 256, 0, stream>>>(FUSEDP, OB, out, Dv, Dv, Dv, Dv, 32);

  (void)in_sizes; (void)n_in; (void)out_size; (void)ws_size;
}

// Round 10
// 493.698 us; speedup vs baseline: 1.3628x; 1.0406x over previous
//
#include <hip/hip_runtime.h>
#include <math.h>

#define Dv 1024
#define Ev 8
#define Hv 2816
#define Nv 4096
#define NKv 8192
#define CAPv 1280
#define TH2v 5632

typedef unsigned short u16;
typedef unsigned char u8;
typedef __attribute__((ext_vector_type(4))) float f32x4;
typedef __attribute__((ext_vector_type(4))) int i32x4;
typedef __attribute__((ext_vector_type(8))) int i32x8;
typedef __attribute__((ext_vector_type(4))) u16 u16x4;

typedef const __attribute__((address_space(1))) void* as1_cvp;
typedef __attribute__((address_space(3))) void* as3_vp;

// f32 -> OCP e4m3fn, RNE, saturate to 448
__device__ __forceinline__ unsigned f2e4(float f) {
  unsigned u = __float_as_uint(f);
  unsigned sgn = (u >> 24) & 0x80u;
  unsigned ax = u & 0x7FFFFFFFu;
  if (ax >= 0x43E00000u) return sgn | 0x7Eu;
  if (ax < 0x3C800000u) {
    int qv = (int)rintf(__uint_as_float(ax) * 512.f);
    return sgn | (unsigned)qv;
  }
  unsigned lsb = (ax >> 20) & 1u;
  unsigned rr = ax + 0x0007FFFFu + lsb;
  unsigned ee = rr >> 23;
  unsigned mm = (rr >> 20) & 7u;
  if (ee > 135u) return sgn | 0x7Eu;
  return sgn | ((ee - 120u) << 3) | mm;
}
// e4m3fn -> f32
__device__ __forceinline__ float e42f(unsigned v) {
  unsigned s = (v & 0x80u) << 24, e = (v >> 3) & 15u, m = v & 7u;
  if (e) return __uint_as_float(s | ((e + 120u) << 23) | (m << 20));
  return __uint_as_float(__float_as_uint((float)m * 0.001953125f) | s);
}
__device__ __forceinline__ void dec16(const u8* p, float* o) {
  const unsigned* w = (const unsigned*)p;
  #pragma unroll
  for (int j = 0; j < 4; ++j) {
    unsigned x = w[j];
    o[j*4+0] = e42f(x & 255u);
    o[j*4+1] = e42f((x >> 8) & 255u);
    o[j*4+2] = e42f((x >> 16) & 255u);
    o[j*4+3] = e42f((x >> 24) & 255u);
  }
}
__device__ __forceinline__ void gload16(const void* g, void* l) {
  __builtin_amdgcn_global_load_lds((as1_cvp)g, (as3_vp)l, 16, 0, 0);
}

// ---------------- router ----------------
__global__ __launch_bounds__(256) void router_kernel(
    const float* __restrict__ x, const float* __restrict__ gw,
    int* __restrict__ tkidx, float* __restrict__ tkprob,
    float* __restrict__ red, float* __restrict__ outIdx)
{
  __shared__ float lred[17];
  int tid = threadIdx.x;
  if (tid < 17) lred[tid] = 0.f;
  __syncthreads();
  int wv = tid >> 6, ln = tid & 63;
  int n = blockIdx.x * 4 + wv;
  float a[8] = {0.f,0.f,0.f,0.f,0.f,0.f,0.f,0.f};
  const float* xr = x + (size_t)n * Dv;
  #pragma unroll
  for (int it = 0; it < 16; ++it) {
    int d = ln + it * 64;
    float xs = xr[d];
    float4 g0 = *(const float4*)(gw + (size_t)d * 8);
    float4 g1 = *(const float4*)(gw + (size_t)d * 8 + 4);
    a[0] += xs * g0.x; a[1] += xs * g0.y; a[2] += xs * g0.z; a[3] += xs * g0.w;
    a[4] += xs * g1.x; a[5] += xs * g1.y; a[6] += xs * g1.z; a[7] += xs * g1.w;
  }
  #pragma unroll
  for (int off = 32; off >= 1; off >>= 1) {
    #pragma unroll
    for (int e = 0; e < 8; ++e) a[e] += __shfl_xor(a[e], off, 64);
  }
  int i1 = 0; float v1 = a[0];
  #pragma unroll
  for (int e = 1; e < 8; ++e) if (a[e] > v1) { v1 = a[e]; i1 = e; }
  int i2 = -1; float v2 = -1e30f;
  #pragma unroll
  for (int e = 0; e < 8; ++e) if (e != i1 && a[e] > v2) { v2 = a[e]; i2 = e; }
  float Z = 0.f;
  #pragma unroll
  for (int e = 0; e < 8; ++e) Z += expf(a[e] - v1);
  float zlse = v1 + logf(Z);
  float t = expf(v2 - v1);
  float p1 = 1.f / (1.f + t);
  float p2 = t * p1;
  if (ln == 0) {
    tkidx[2*n] = i1; tkidx[2*n+1] = i2;
    tkprob[2*n] = p1; tkprob[2*n+1] = p2;
    outIdx[2*n] = (float)i1; outIdx[2*n+1] = (float)i2;
    #pragma unroll
    for (int e = 0; e < 8; ++e) atomicAdd(&lred[e], expf(a[e] - v1) / Z);
    atomicAdd(&lred[8 + i1], 1.f);
    atomicAdd(&lred[16], zlse * zlse);
  }
  __syncthreads();
  if (tid < 17) atomicAdd(&red[tid], lred[tid]);
}

__global__ void aux_kernel(const float* __restrict__ red, float* __restrict__ outAux) {
  float bl = 0.f;
  for (int e = 0; e < 8; ++e) bl += (red[e] / (float)Nv) * (red[8 + e] / (float)Nv);
  bl *= (float)Ev;
  float zl = red[16] / (float)Nv;
  outAux[0] = 0.01f * bl + 0.001f * zl;
}

// ---------------- exact stable rank ----------------
__global__ __launch_bounds__(256) void rank_kernel(const int* __restrict__ tgt,
    int* __restrict__ keep, int* __restrict__ dstNK)
{
  __shared__ int hist[256][8];
  int t = threadIdx.x;
  int h[8] = {0,0,0,0,0,0,0,0};
  int base = t * 32;
  for (int j = 0; j < 32; ++j) h[tgt[base + j]]++;
  for (int e = 0; e < 8; ++e) hist[t][e] = h[e];
  __syncthreads();
  if (t < 8) {
    int run = 0;
    for (int tt = 0; tt < 256; ++tt) { int v = hist[tt][t]; hist[tt][t] = run; run += v; }
  }
  __syncthreads();
  for (int e = 0; e < 8; ++e) h[e] = hist[t][e];
  for (int j = 0; j < 32; ++j) {
    int i = base + j; int e = tgt[i]; int r = h[e]++;
    int kp = (r < CAPv) ? 1 : 0;
    keep[i] = kp;
    if (kp) dstNK[e * CAPv + r] = i;
  }
}

// ---------------- pack tokens -> fp8 ----------------
__global__ __launch_bounds__(256) void pack8_kernel(const float* __restrict__ x,
    const int* __restrict__ dstNK, u8* __restrict__ buf)
{
  int s = blockIdx.x * 4 + (threadIdx.x >> 6);
  int ln = threadIdx.x & 63;
  int i = dstNK[s];
  u8* dst = buf + (size_t)s * Dv;
  if (i >= 0) {
    const float* src = x + (size_t)(i >> 1) * Dv;
    #pragma unroll
    for (int j = 0; j < 4; ++j) {
      int d0 = ln * 16 + j * 4;
      float4 v = *(const float4*)(src + d0);
      unsigned w = f2e4(v.x) | (f2e4(v.y) << 8) | (f2e4(v.z) << 16) | (f2e4(v.w) << 24);
      *(unsigned*)(dst + d0) = w;
    }
  } else {
    #pragma unroll
    for (int j = 0; j < 4; ++j) *(unsigned*)(dst + ln * 16 + j * 4) = 0u;
  }
}

// ---------------- straight f32->e4m3 (xsmul) ----------------
__global__ __launch_bounds__(256) void conv8s_kernel(const float* __restrict__ in,
    u8* __restrict__ out, float smul)
{
  int i = blockIdx.x * 256 + threadIdx.x;
  float4 v = *(const float4*)(in + (size_t)i * 4);
  unsigned w = f2e4(v.x * smul) | (f2e4(v.y * smul) << 8)
             | (f2e4(v.z * smul) << 16) | (f2e4(v.w * smul) << 24);
  *(unsigned*)(out + (size_t)i * 4) = w;
}

// ---------------- transpose + f32->e4m3 (xsmul, out row stride ldo) ----------------
__global__ __launch_bounds__(256) void tconv8_kernel(const float* __restrict__ in,
    u8* __restrict__ out, int R, int C, float smul, int ldo)
{
  __shared__ u8 tile[64][68];
  in += (size_t)blockIdx.z * (size_t)R * (size_t)C;
  out += (size_t)blockIdx.z * (size_t)R * (size_t)C;   // only valid when ldo==R (batched use)
  int r0 = blockIdx.y * 64, c0 = blockIdx.x * 64;
  int t = threadIdx.x;
  int cc4 = (t & 15) * 4;
  #pragma unroll
  for (int p = 0; p < 4; ++p) {
    int r = (t >> 4) + p * 16;
    float4 v = *(const float4*)(in + (size_t)(r0 + r) * C + c0 + cc4);
    unsigned w = f2e4(v.x * smul) | (f2e4(v.y * smul) << 8)
               | (f2e4(v.z * smul) << 16) | (f2e4(v.w * smul) << 24);
    *(unsigned*)(&tile[r][cc4]) = w;
  }
  __syncthreads();
  int rr4 = (t & 15) * 4;
  #pragma unroll
  for (int p = 0; p < 4; ++p) {
    int c = (t >> 4) + p * 16;
    unsigned w = (unsigned)tile[rr4][c] | ((unsigned)tile[rr4+1][c] << 8)
               | ((unsigned)tile[rr4+2][c] << 16) | ((unsigned)tile[rr4+3][c] << 24);
    *(unsigned*)(out + (size_t)(c0 + c) * ldo + r0 + rr4) = w;
  }
}

// ===== 128x128 4-wave MX-fp8 GEMM, BK=128, single-buffer (m97/m148 structure) =====
// MODE 1: SwiGLU -> fp8   2: scatter fp8 via dst   4: fp8 out
// MODE 5: gelu -> fp8 (split-K A)   6: f32 out
template<int MODE>
__global__ __launch_bounds__(256, 3) void gemm128f8(
    const u8* __restrict__ A, const u8* __restrict__ A2, int splitK,
    const u8* __restrict__ B, void* __restrict__ C,
    const int* __restrict__ dst, int Ksz, int lda, int ldb, int ldc, int ntm,
    size_t sA, size_t sB, size_t sC, unsigned sclA, unsigned sclB)
{
  __shared__ char smem[32768];
  int e = blockIdx.y;
  int nwgx = gridDim.x, bid0 = blockIdx.x;
  int q = nwgx >> 3, r = nwgx & 7;
  int xcd = bid0 & 7, lo2 = bid0 >> 3;
  int bid = (xcd < r ? xcd * (q + 1) : r * (q + 1) + (xcd - r) * q) + lo2;
  int tm = bid % ntm, tn = bid / ntm;
  const u8* Ae = A + (size_t)e * sA;
  const u8* Be = B + (size_t)e * sB;
  long long bdelta = (const char*)A2 - (const char*)Ae;
  int tid = threadIdx.x, wv = tid >> 6, ln = tid & 63;
  int lnl = ln & 15, lnh = ln >> 4;

  const u8* aP[4]; const u8* bP[4];
  unsigned aL[4], bL[4];
  #pragma unroll
  for (int i = 0; i < 4; ++i) {
    int row = i * 32 + wv * 8 + (ln >> 3);
    int c = (ln & 7) ^ (row & 7);
    int cp = ((c & 3) << 1) | (c >> 2);
    aP[i] = Ae + (size_t)(tm * 128 + row) * lda + cp * 16;
    int brow;
    if (MODE == 1) {
      brow = (row < 64) ? (tn * 64 + row) : (Hv + tn * 64 + (row - 64));
    } else {
      brow = tn * 128 + row;
    }
    bP[i] = Be + (size_t)brow * ldb + cp * 16;
    aL[i] = i * 4096 + wv * 1024;
    bL[i] = 16384 + i * 4096 + wv * 1024;
  }

  int arow0 = wv * 32 + lnl;
  int ksw0 = (lnh << 4);
  int ksw1 = 64 + (lnh << 4);

  f32x4 acc[2][8];
  #pragma unroll
  for (int m = 0; m < 2; ++m)
    #pragma unroll
    for (int n = 0; n < 8; ++n) acc[m][n] = (f32x4){0.f, 0.f, 0.f, 0.f};

  for (int k0 = 0; k0 < Ksz; k0 += 128) {
    long long kbA;
    if (MODE == 5 && k0 >= splitK) kbA = bdelta + (long long)(k0 - splitK);
    else kbA = (long long)k0;
    #pragma unroll
    for (int i = 0; i < 4; ++i) gload16(aP[i] + kbA, smem + aL[i]);
    #pragma unroll
    for (int i = 0; i < 4; ++i) gload16(bP[i] + (size_t)k0, smem + bL[i]);
    __syncthreads();

    i32x8 af[2];
    #pragma unroll
    for (int mi = 0; mi < 2; ++mi) {
      int row = arow0 + mi * 16;
      int swz = (row & 7) << 4;
      *(i32x4*)&af[mi] = *(const i32x4*)(smem + row * 128 + (ksw0 ^ swz));
      *((i32x4*)&af[mi] + 1) = *(const i32x4*)(smem + row * 128 + (ksw1 ^ swz));
    }
    #pragma unroll
    for (int n = 0; n < 8; ++n) {
      int row = n * 16 + lnl;
      int swz = (row & 7) << 4;
      i32x8 bf;
      *(i32x4*)&bf = *(const i32x4*)(smem + 16384 + row * 128 + (ksw0 ^ swz));
      *((i32x4*)&bf + 1) = *(const i32x4*)(smem + 16384 + row * 128 + (ksw1 ^ swz));
      acc[0][n] = __builtin_amdgcn_mfma_scale_f32_16x16x128_f8f6f4(
          af[0], bf, acc[0][n], 0, 0, 0, sclA, 0, sclB);
      acc[1][n] = __builtin_amdgcn_mfma_scale_f32_16x16x128_f8f6f4(
          af[1], bf, acc[1][n], 0, 0, 0, sclA, 0, sclB);
    }
    __syncthreads();
  }

  int rbase = tm * 128 + wv * 32 + (lnh << 2);
  if (MODE == 1) {
    u8* Cp = (u8*)C + (size_t)e * sC;
    #pragma unroll
    for (int mi = 0; mi < 2; ++mi)
      #pragma unroll
      for (int n = 0; n < 4; ++n) {
        int col = tn * 64 + n * 16 + lnl;
        #pragma unroll
        for (int v = 0; v < 4; ++v) {
          float g = acc[mi][n][v];
          float u = acc[mi][n + 4][v];
          float sg = g / (1.f + __expf(-g));
          Cp[(size_t)(rbase + mi * 16 + v) * ldc + col] = (u8)f2e4(sg * u);
        }
      }
  } else if (MODE == 2) {
    u8* Cq = (u8*)C;
    #pragma unroll
    for (int mi = 0; mi < 2; ++mi)
      #pragma unroll
      for (int v = 0; v < 4; ++v) {
        int gr = rbase + mi * 16 + v;
        int i = dst[e * CAPv + gr];
        if (i >= 0) {
          #pragma unroll
          for (int n = 0; n < 8; ++n) {
            int col = tn * 128 + n * 16 + lnl;
            Cq[(size_t)i * Dv + col] = (u8)f2e4(acc[mi][n][v]);
          }
        }
      }
  } else if (MODE == 4) {
    u8* Cp = (u8*)C;
    #pragma unroll
    for (int mi = 0; mi < 2; ++mi)
      #pragma unroll
      for (int n = 0; n < 8; ++n) {
        int col = tn * 128 + n * 16 + lnl;
        #pragma unroll
        for (int v = 0; v < 4; ++v)
          Cp[(size_t)(rbase + mi * 16 + v) * ldc + col] = (u8)f2e4(acc[mi][n][v]);
      }
  } else if (MODE == 5) {
    u8* Cp = (u8*)C;
    #pragma unroll
    for (int mi = 0; mi < 2; ++mi)
      #pragma unroll
      for (int n = 0; n < 8; ++n) {
        int col = tn * 128 + n * 16 + lnl;
        #pragma unroll
        for (int v = 0; v < 4; ++v) {
          float xg = acc[mi][n][v];
          float gl = 0.5f * xg * (1.f + erff(xg * 0.70710678118654752f));
          Cp[(size_t)(rbase + mi * 16 + v) * ldc + col] = (u8)f2e4(gl);
        }
      }
  } else {
    float* Cp = (float*)C;
    #pragma unroll
    for (int mi = 0; mi < 2; ++mi)
      #pragma unroll
      for (int n = 0; n < 8; ++n) {
        int col = tn * 128 + n * 16 + lnl;
        #pragma unroll
        for (int v = 0; v < 4; ++v)
          Cp[(size_t)(rbase + mi * 16 + v) * ldc + col] = acc[mi][n][v];
      }
  }
}

// ---------------- scores + masked softmax + Cmsg (fp8; T = sel@W_s fused in MQ) ----------------
__global__ __launch_bounds__(256) void scores8_kernel(
    const u8* __restrict__ MQ, const u8* __restrict__ SEL8,
    const int* __restrict__ keep, u8* __restrict__ Cmsg)
{
  int wv = threadIdx.x >> 6, ln = threadIdx.x & 63;
  int n = blockIdx.x * 4 + wv;
  const u8* m0 = MQ + (size_t)(2 * n) * 2048;
  const u8* m1 = MQ + (size_t)(2 * n + 1) * 2048;
  const u8* t0 = m0 + 1024;               // T = sel @ W_s
  const u8* t1 = m1 + 1024;
  const u8* s0p = SEL8 + (size_t)(2 * n) * 1024;
  const u8* s1p = SEL8 + (size_t)(2 * n + 1) * 1024;
  int d0 = ln * 16;
  float a0[16], a1[16], b0[16], b1[16];
  dec16(t0 + d0, a0); dec16(t1 + d0, a1);
  dec16(s0p + d0, b0); dec16(s1p + d0, b1);
  float s00 = 0, s01 = 0, s10 = 0, s11 = 0;
  #pragma unroll
  for (int t = 0; t < 16; ++t) {
    s00 += a0[t] * b0[t]; s01 += a0[t] * b1[t];
    s10 += a1[t] * b0[t]; s11 += a1[t] * b1[t];
  }
  #pragma unroll
  for (int off = 32; off >= 1; off >>= 1) {
    s00 += __shfl_xor(s00, off, 64);
    s01 += __shfl_xor(s01, off, 64);
    s10 += __shfl_xor(s10, off, 64);
    s11 += __shfl_xor(s11, off, 64);
  }
  const float inv = 0.03125f;
  int kp0 = keep[2 * n], kp1 = keep[2 * n + 1];
  float A00, A01, A10, A11;
  {
    float v0 = kp0 ? s00 * inv : -1e9f;
    float v1 = (kp0 && kp1) ? s01 * inv : -1e9f;
    float mx = fmaxf(v0, v1);
    float e0 = expf(v0 - mx), e1 = expf(v1 - mx);
    float den = e0 + e1;
    float a0v = kp0 ? e0 / den : 0.f;
    float a1v = (kp0 && kp1) ? e1 / den : 0.f;
    float s = fmaxf(a0v + a1v, 1e-12f);
    A00 = a0v / s; A01 = a1v / s;
  }
  {
    float v0 = (kp1 && kp0) ? s10 * inv : -1e9f;
    float v1 = kp1 ? s11 * inv : -1e9f;
    float mx = fmaxf(v0, v1);
    float e0 = expf(v0 - mx), e1 = expf(v1 - mx);
    float den = e0 + e1;
    float a0v = (kp1 && kp0) ? e0 / den : 0.f;
    float a1v = kp1 ? e1 / den : 0.f;
    float s = fmaxf(a0v + a1v, 1e-12f);
    A10 = a0v / s; A11 = a1v / s;
  }
  float f0[16], f1[16];
  dec16(m0 + d0, f0); dec16(m1 + d0, f1);
  unsigned o0[4], o1[4];
  #pragma unroll
  for (int j = 0; j < 4; ++j) {
    o0[j] = 0; o1[j] = 0;
    #pragma unroll
    for (int b = 0; b < 4; ++b) {
      int t = j * 4 + b;
      o0[j] |= f2e4(A00 * f0[t] + A01 * f1[t]) << (8 * b);
      o1[j] |= f2e4(A10 * f0[t] + A11 * f1[t]) << (8 * b);
    }
  }
  u8* c0 = Cmsg + (size_t)(2 * n) * 1024 + d0;
  u8* c1 = Cmsg + (size_t)(2 * n + 1) * 1024 + d0;
  #pragma unroll
  for (int j = 0; j < 4; ++j) {
    *(unsigned*)(c0 + j * 4) = o0[j];
    *(unsigned*)(c1 + j * 4) = o1[j];
  }
}

// ---------------- combine2: FCAT = [sum w_k sel_k | sum w_k gelu_k] fp8 ----------------
__global__ __launch_bounds__(256) void combine2_kernel(
    const u8* __restrict__ sel8, const u8* __restrict__ g8,
    const int* __restrict__ keep, const float* __restrict__ tkprob,
    u8* __restrict__ fcat)
{
  int n = blockIdx.x;
  int t = threadIdx.x;
  float kp0 = keep[2 * n] ? 1.f : 0.f, kp1 = keep[2 * n + 1] ? 1.f : 0.f;
  float p0 = tkprob[2 * n] * kp0, p1 = tkprob[2 * n + 1] * kp1;
  float s = fmaxf(p0 + p1, 1e-12f);
  float w0 = p0 / s, w1 = p1 / s;
  // sel part: 4 cols/thread
  unsigned a = *(const unsigned*)(sel8 + (size_t)(2 * n) * 1024 + t * 4);
  unsigned b = *(const unsigned*)(sel8 + (size_t)(2 * n + 1) * 1024 + t * 4);
  unsigned o = 0;
  #pragma unroll
  for (int j = 0; j < 4; ++j)
    o |= f2e4(w0 * e42f((a >> (8 * j)) & 255u) + w1 * e42f((b >> (8 * j)) & 255u)) << (8 * j);
  *(unsigned*)(fcat + (size_t)n * 3072 + t * 4) = o;
  // gelu part: 8 cols/thread
  const u8* ga = g8 + (size_t)(2 * n) * 2048 + t * 8;
  const u8* gb = g8 + (size_t)(2 * n + 1) * 2048 + t * 8;
  #pragma unroll
  for (int h = 0; h < 2; ++h) {
    unsigned xa = *(const unsigned*)(ga + h * 4);
    unsigned xb = *(const unsigned*)(gb + h * 4);
    unsigned oo = 0;
    #pragma unroll
    for (int j = 0; j < 4; ++j)
      oo |= f2e4(w0 * e42f((xa >> (8 * j)) & 255u) + w1 * e42f((xb >> (8 * j)) & 255u)) << (8 * j);
    *(unsigned*)(fcat + (size_t)n * 3072 + 1024 + t * 8 + h * 4) = oo;
  }
}

extern "C" void kernel_launch(void* const* d_in, const int* in_sizes, int n_in,
                              void* d_out, int out_size, void* d_ws, size_t ws_size,
                              hipStream_t stream) {
  const float* x      = (const float*)d_in[0];
  const float* gate_w = (const float*)d_in[1];
  const float* w13    = (const float*)d_in[2];
  const float* w2     = (const float*)d_in[3];
  const float* msg_w  = (const float*)d_in[4];
  const float* q_w    = (const float*)d_in[5];
  const float* k_w    = (const float*)d_in[6];
  const float* upd_w1 = (const float*)d_in[7];
  const float* upd_w2 = (const float*)d_in[8];
  const float* o_w    = (const float*)d_in[9];
  float* out = (float*)d_out;
  float* outAux = out + (size_t)Nv * Dv;
  float* outIdx = outAux + 1;

  char* ws = (char*)d_ws;
  const size_t MBc = 1ull << 20;
  int*   tkidx  = (int*)(ws + 0);
  float* tkprob = (float*)(ws + 32768);
  int*   keepA  = (int*)(ws + 65536);
  int*   dstNK  = (int*)(ws + 98304);
  float* red    = (float*)(ws + 143360);
  // phase A:
  u8*  BUF8  = (u8*)(ws + 1 * MBc);     // [1,12)
  u8*  ACT8  = (u8*)(ws + 12 * MBc);    // [12,41)
  u8*  W13B8 = (u8*)(ws + 41 * MBc);    // [41,88) dead after G1
  u8*  W2B8  = (u8*)(ws + 41 * MBc);    // [41,64) after G1, live to G2
  // weight-prep region [64,96) (free after G1):
  float* T1f = (float*)(ws + 64 * MBc); // 4 MB
  float* WSf = (float*)(ws + 68 * MBc); // 4 MB
  float* T2f = (float*)(ws + 72 * MBc); // 8 MB
  u8*  M8s   = (u8*)(ws + 80 * MBc);    // 1 MB
  u8*  Q8s   = (u8*)(ws + 81 * MBc);    // 1 MB
  u8*  U28s  = (u8*)(ws + 82 * MBc);    // 2 MB
  u8*  K8T   = (u8*)(ws + 84 * MBc);    // 1 MB
  u8*  T18   = (u8*)(ws + 85 * MBc);    // 1 MB
  u8*  MTB8  = (u8*)(ws + 86 * MBc);    // 2 MB  [msg^T | W_s^T]
  u8*  WCAT8 = (u8*)(ws + 88 * MBc);    // 3 MB  [o_w^T | (upd_w2@o_w)^T], ld 3072
  u8*  FCAT8 = (u8*)(ws + 96 * MBc);    // 12.6 MB
  u8*  SEL8  = (u8*)(ws + 136 * MBc);   // 8.4 MB
  u8*  UPD1B8= (u8*)(ws + 149 * MBc);   // 4 MB
  // phase B overlays:
  u8*  MQ8   = (u8*)(ws + 1 * MBc);     // 16.8 MB [1,18)
  u8*  CMSG8 = (u8*)(ws + 18 * MBc);    // 8.4 MB  [18,27)
  u8*  G1B8  = (u8*)(ws + 27 * MBc);    // 16.8 MB [27,44)

  hipMemsetAsync(red, 0, 68, stream);
  hipMemsetAsync(dstNK, 0xFF, Ev * CAPv * 4, stream);

  router_kernel<<<Nv / 4, 256, 0, stream>>>(x, gate_w, tkidx, tkprob, red, outIdx);
  aux_kernel<<<1, 1, 0, stream>>>(red, outAux);
  rank_kernel<<<1, 256, 0, stream>>>(tkidx, keepA, dstNK);
  pack8_kernel<<<(Ev * CAPv) / 4, 256, 0, stream>>>(x, dstNK, BUF8);

  // G1: w13 -> fp8 (x16, HW 2^-4), MX-fp8 SwiGLU -> ACT8
  tconv8_kernel<<<dim3(TH2v / 64, Dv / 64, Ev), 256, 0, stream>>>(w13, W13B8, Dv, TH2v, 16.f, Dv);
  gemm128f8<1><<<dim3((CAPv / 128) * (Hv / 64), Ev), 256, 0, stream>>>(
      BUF8, BUF8, 1 << 30, W13B8, (void*)ACT8, nullptr,
      Dv, Dv, Dv, Hv, CAPv / 128,
      (size_t)CAPv * Dv, (size_t)TH2v * Dv, (size_t)CAPv * Hv, 0x7F7F7F7Fu, 0x7B7B7B7Bu);

  // weight prep (W13B8 region dead; W2B8 live to G2)
  hipMemsetAsync(SEL8, 0, (size_t)NKv * Dv, stream);
  tconv8_kernel<<<dim3(Dv / 64, Hv / 64, Ev), 256, 0, stream>>>(w2, W2B8, Hv, Dv, 16.f, Hv);
  conv8s_kernel<<<1024, 256, 0, stream>>>(msg_w, M8s, 16.f);
  conv8s_kernel<<<1024, 256, 0, stream>>>(q_w, Q8s, 16.f);
  conv8s_kernel<<<2048, 256, 0, stream>>>(upd_w2, U28s, 16.f);
  tconv8_kernel<<<dim3(16, 16, 1), 256, 0, stream>>>(k_w, K8T, Dv, Dv, 16.f, Dv);
  tconv8_kernel<<<dim3(16, 16, 1), 256, 0, stream>>>(msg_w, MTB8, Dv, Dv, 16.f, Dv);
  tconv8_kernel<<<dim3(32, 32, 1), 256, 0, stream>>>(upd_w1, UPD1B8, 2048, 2048, 16.f, 2048);
  tconv8_kernel<<<dim3(16, 16, 1), 256, 0, stream>>>(o_w, WCAT8, Dv, Dv, 16.f, 3072);
  // T1 = msg_w @ k_w
  gemm128f8<6><<<dim3(64, 1), 256, 0, stream>>>(
      M8s, M8s, 1 << 30, K8T, (void*)T1f, nullptr,
      Dv, Dv, Dv, Dv, 8, 0, 0, 0, 0x7B7B7B7Bu, 0x7B7B7B7Bu);
  conv8s_kernel<<<1024, 256, 0, stream>>>(T1f, T18, 16.f);
  // W_s = q_w @ T1^T
  gemm128f8<6><<<dim3(64, 1), 256, 0, stream>>>(
      Q8s, Q8s, 1 << 30, T18, (void*)WSf, nullptr,
      Dv, Dv, Dv, Dv, 8, 0, 0, 0, 0x7B7B7B7Bu, 0x7B7B7B7Bu);
  tconv8_kernel<<<dim3(16, 16, 1), 256, 0, stream>>>(WSf, MTB8 + (size_t)Dv * Dv, Dv, Dv, 16.f, Dv);
  // T2 = upd_w2 @ o_w (B = o_w^T inside WCAT8, ldb 3072)
  gemm128f8<6><<<dim3(128, 1), 256, 0, stream>>>(
      U28s, U28s, 1 << 30, WCAT8, (void*)T2f, nullptr,
      Dv, Dv, 3072, Dv, 16, 0, 0, 0, 0x7B7B7B7Bu, 0x7B7B7B7Bu);
  tconv8_kernel<<<dim3(16, 32, 1), 256, 0, stream>>>(T2f, WCAT8 + 1024, 2048, Dv, 16.f, 3072);

  // G2: MX-fp8 GEMM + scatter -> SEL8
  gemm128f8<2><<<dim3((CAPv / 128) * (Dv / 128), Ev), 256, 0, stream>>>(
      ACT8, ACT8, 1 << 30, W2B8, (void*)SEL8, dstNK,
      Hv, Hv, Hv, Dv, CAPv / 128,
      (size_t)CAPv * Hv, (size_t)Dv * Hv, 0, 0x7F7F7F7Fu, 0x7B7B7B7Bu);

  // collaboration: fused [M|T] GEMM, then scores (T_i . sel_j)
  gemm128f8<4><<<dim3(64 * 16, 1), 256, 0, stream>>>(
      SEL8, SEL8, 1 << 30, MTB8, (void*)MQ8, nullptr,
      Dv, Dv, Dv, 2048, 64, 0, 0, 0, 0x7F7F7F7Fu, 0x7B7B7B7Bu);
  scores8_kernel<<<Nv / 4, 256, 0, stream>>>(MQ8, SEL8, keepA, CMSG8);

  // update MLP: gelu([SEL8|CMSG8] @ upd_w1) -> G1B8 (fp8)
  gemm128f8<5><<<dim3(64 * 16, 1), 256, 0, stream>>>(
      SEL8, CMSG8, Dv, UPD1B8, (void*)G1B8, nullptr,
      2048, Dv, 2048, 2048, 64, 0, 0, 0, 0x7F7F7F7Fu, 0x7B7B7B7Bu);

  // FCAT = [sum w sel | sum w gelu], final fused GEMM -> out (f32)
  combine2_kernel<<<Nv, 256, 0, stream>>>(SEL8, G1B8, keepA, tkprob, FCAT8);
  gemm128f8<6><<<dim3(32 * 8, 1), 256, 0, stream>>>(
      FCAT8, FCAT8, 1 << 30, WCAT8, (void*)out, nullptr,
      3072, 3072, 3072, Dv, 32, 0, 0, 0, 0x7F7F7F7Fu, 0x7B7B7B7Bu);

  (void)in_sizes; (void)n_in; (void)out_size; (void)ws_size;
}

// Round 12
// 460.558 us; speedup vs baseline: 1.4608x; 1.0720x over previous
//
#include <hip/hip_runtime.h>
#include <math.h>

#define Dv 1024
#define Ev 8
#define Hv 2816
#define Nv 4096
#define NKv 8192
#define CAPv 1280
#define TH2v 5632

typedef unsigned short u16;
typedef unsigned char u8;
typedef __attribute__((ext_vector_type(4))) float f32x4;
typedef __attribute__((ext_vector_type(4))) int i32x4;
typedef __attribute__((ext_vector_type(8))) int i32x8;

typedef const __attribute__((address_space(1))) void* as1_cvp;
typedef __attribute__((address_space(3))) void* as3_vp;

// f32 -> OCP e4m3fn, RNE, saturate to 448
__device__ __forceinline__ unsigned f2e4(float f) {
  unsigned u = __float_as_uint(f);
  unsigned sgn = (u >> 24) & 0x80u;
  unsigned ax = u & 0x7FFFFFFFu;
  if (ax >= 0x43E00000u) return sgn | 0x7Eu;
  if (ax < 0x3C800000u) {
    int qv = (int)rintf(__uint_as_float(ax) * 512.f);
    return sgn | (unsigned)qv;
  }
  unsigned lsb = (ax >> 20) & 1u;
  unsigned rr = ax + 0x0007FFFFu + lsb;
  unsigned ee = rr >> 23;
  unsigned mm = (rr >> 20) & 7u;
  if (ee > 135u) return sgn | 0x7Eu;
  return sgn | ((ee - 120u) << 3) | mm;
}
// e4m3fn -> f32
__device__ __forceinline__ float e42f(unsigned v) {
  unsigned s = (v & 0x80u) << 24, e = (v >> 3) & 15u, m = v & 7u;
  if (e) return __uint_as_float(s | ((e + 120u) << 23) | (m << 20));
  return __uint_as_float(__float_as_uint((float)m * 0.001953125f) | s);
}
__device__ __forceinline__ void dec16(const u8* p, float* o) {
  const unsigned* w = (const unsigned*)p;
  #pragma unroll
  for (int j = 0; j < 4; ++j) {
    unsigned x = w[j];
    o[j*4+0] = e42f(x & 255u);
    o[j*4+1] = e42f((x >> 8) & 255u);
    o[j*4+2] = e42f((x >> 16) & 255u);
    o[j*4+3] = e42f((x >> 24) & 255u);
  }
}
__device__ __forceinline__ unsigned pack4(float4 v, float s) {
  return f2e4(v.x * s) | (f2e4(v.y * s) << 8) | (f2e4(v.z * s) << 16) | (f2e4(v.w * s) << 24);
}
__device__ __forceinline__ void gload16(const void* g, void* l) {
  __builtin_amdgcn_global_load_lds((as1_cvp)g, (as3_vp)l, 16, 0, 0);
}

// ---------------- router ----------------
__global__ __launch_bounds__(256) void router_kernel(
    const float* __restrict__ x, const float* __restrict__ gw,
    int* __restrict__ tkidx, float* __restrict__ tkprob,
    float* __restrict__ red, float* __restrict__ outIdx)
{
  __shared__ float lred[17];
  int tid = threadIdx.x;
  if (tid < 17) lred[tid] = 0.f;
  __syncthreads();
  int wv = tid >> 6, ln = tid & 63;
  int n = blockIdx.x * 4 + wv;
  float a[8] = {0.f,0.f,0.f,0.f,0.f,0.f,0.f,0.f};
  const float* xr = x + (size_t)n * Dv;
  #pragma unroll
  for (int it = 0; it < 16; ++it) {
    int d = ln + it * 64;
    float xs = xr[d];
    float4 g0 = *(const float4*)(gw + (size_t)d * 8);
    float4 g1 = *(const float4*)(gw + (size_t)d * 8 + 4);
    a[0] += xs * g0.x; a[1] += xs * g0.y; a[2] += xs * g0.z; a[3] += xs * g0.w;
    a[4] += xs * g1.x; a[5] += xs * g1.y; a[6] += xs * g1.z; a[7] += xs * g1.w;
  }
  #pragma unroll
  for (int off = 32; off >= 1; off >>= 1) {
    #pragma unroll
    for (int e = 0; e < 8; ++e) a[e] += __shfl_xor(a[e], off, 64);
  }
  int i1 = 0; float v1 = a[0];
  #pragma unroll
  for (int e = 1; e < 8; ++e) if (a[e] > v1) { v1 = a[e]; i1 = e; }
  int i2 = -1; float v2 = -1e30f;
  #pragma unroll
  for (int e = 0; e < 8; ++e) if (e != i1 && a[e] > v2) { v2 = a[e]; i2 = e; }
  float Z = 0.f;
  #pragma unroll
  for (int e = 0; e < 8; ++e) Z += expf(a[e] - v1);
  float zlse = v1 + logf(Z);
  float t = expf(v2 - v1);
  float p1 = 1.f / (1.f + t);
  float p2 = t * p1;
  if (ln == 0) {
    tkidx[2*n] = i1; tkidx[2*n+1] = i2;
    tkprob[2*n] = p1; tkprob[2*n+1] = p2;
    outIdx[2*n] = (float)i1; outIdx[2*n+1] = (float)i2;
    #pragma unroll
    for (int e = 0; e < 8; ++e) atomicAdd(&lred[e], expf(a[e] - v1) / Z);
    atomicAdd(&lred[8 + i1], 1.f);
    atomicAdd(&lred[16], zlse * zlse);
  }
  __syncthreads();
  if (tid < 17) atomicAdd(&red[tid], lred[tid]);
}

// ---------------- exact stable rank + counts + aux ----------------
__global__ __launch_bounds__(256) void rank_kernel(const int* __restrict__ tgt,
    int* __restrict__ keep, int* __restrict__ dstNK, int* __restrict__ cnt,
    const float* __restrict__ red, float* __restrict__ outAux)
{
  __shared__ int hist[256][8];
  int t = threadIdx.x;
  int h[8] = {0,0,0,0,0,0,0,0};
  int base = t * 32;
  for (int j = 0; j < 32; ++j) h[tgt[base + j]]++;
  for (int e = 0; e < 8; ++e) hist[t][e] = h[e];
  __syncthreads();
  if (t < 8) {
    int run = 0;
    for (int tt = 0; tt < 256; ++tt) { int v = hist[tt][t]; hist[tt][t] = run; run += v; }
    cnt[t] = run < CAPv ? run : CAPv;
  }
  if (t == 0) {
    float bl = 0.f;
    for (int e = 0; e < 8; ++e) bl += (red[e] / (float)Nv) * (red[8 + e] / (float)Nv);
    bl *= (float)Ev;
    outAux[0] = 0.01f * bl + 0.001f * (red[16] / (float)Nv);
  }
  __syncthreads();
  for (int e = 0; e < 8; ++e) h[e] = hist[t][e];
  for (int j = 0; j < 32; ++j) {
    int i = base + j; int e = tgt[i]; int r = h[e]++;
    int kp = (r < CAPv) ? 1 : 0;
    keep[i] = kp;
    if (kp) dstNK[e * CAPv + r] = i;
  }
}

// ---------------- pack tokens -> fp8 ----------------
__global__ __launch_bounds__(256) void pack8_kernel(const float* __restrict__ x,
    const int* __restrict__ dstNK, u8* __restrict__ buf)
{
  int s = blockIdx.x * 4 + (threadIdx.x >> 6);
  int ln = threadIdx.x & 63;
  int i = dstNK[s];
  u8* dst = buf + (size_t)s * Dv;
  if (i >= 0) {
    const float* src = x + (size_t)(i >> 1) * Dv;
    #pragma unroll
    for (int j = 0; j < 4; ++j) {
      int d0 = ln * 16 + j * 4;
      float4 v = *(const float4*)(src + d0);
      *(unsigned*)(dst + d0) = pack4(v, 1.f);
    }
  } else {
    #pragma unroll
    for (int j = 0; j < 4; ++j) *(unsigned*)(dst + ln * 16 + j * 4) = 0u;
  }
}

// ---------------- batched weight conversion (segment table) ----------------
#define NSEG 9
struct WTab {
  const float* in[NSEG];
  u8* out[NSEG];
  int R[NSEG], C[NSEG], ldo[NSEG], nxy[NSEG], nx[NSEG];
  int start[NSEG];
};

__global__ __launch_bounds__(256) void wprep_kernel(WTab T) {
  __shared__ u8 tile[64][68];
  int b = blockIdx.x;
  int s = 0;
  #pragma unroll
  for (int i = 1; i < NSEG; ++i) if (b >= T.start[i]) s = i;
  int rb = b - T.start[s];
  const float* in = T.in[s];
  u8* out = T.out[s];
  int t = threadIdx.x;
  if (T.nx[s] == 0) {
    int i = rb * 256 + t;
    float4 v = *(const float4*)(in + (size_t)i * 4);
    *(unsigned*)(out + (size_t)i * 4) = pack4(v, 16.f);
    return;
  }
  int R = T.R[s], C = T.C[s], ldo = T.ldo[s];
  int z = rb / T.nxy[s], r2 = rb % T.nxy[s];
  int by = r2 / T.nx[s], bx = r2 % T.nx[s];
  in += (size_t)z * R * C;
  out += (size_t)z * (size_t)R * C;   // z>0 only when ldo==R (batched experts)
  int r0 = by * 64, c0 = bx * 64;
  int cc4 = (t & 15) * 4;
  #pragma unroll
  for (int p = 0; p < 4; ++p) {
    int r = (t >> 4) + p * 16;
    float4 v = *(const float4*)(in + (size_t)(r0 + r) * C + c0 + cc4);
    *(unsigned*)(&tile[r][cc4]) = pack4(v, 16.f);
  }
  __syncthreads();
  int rr4 = (t & 15) * 4;
  #pragma unroll
  for (int p = 0; p < 4; ++p) {
    int c = (t >> 4) + p * 16;
    unsigned w = (unsigned)tile[rr4][c] | ((unsigned)tile[rr4+1][c] << 8)
               | ((unsigned)tile[rr4+2][c] << 16) | ((unsigned)tile[rr4+3][c] << 24);
    *(unsigned*)(out + (size_t)(c0 + c) * ldo + r0 + rr4) = w;
  }
}

// ---------------- straight f32->e4m3 (x16), contiguous ----------------
__global__ __launch_bounds__(256) void conv8s_kernel(const float* __restrict__ in,
    u8* __restrict__ out)
{
  int i = blockIdx.x * 256 + threadIdx.x;
  float4 v = *(const float4*)(in + (size_t)i * 4);
  *(unsigned*)(out + (size_t)i * 4) = pack4(v, 16.f);
}

// ---------------- strided f32->e4m3 (x16): in [R][Cw] -> out rows stride ldo ----------------
__global__ __launch_bounds__(256) void conv8st_kernel(const float* __restrict__ in,
    u8* __restrict__ out, int Cw, int ldo)
{
  int i = blockIdx.x * 256 + threadIdx.x;
  int base = i * 4;
  int r = base / Cw, c = base & (Cw - 1);
  float4 v = *(const float4*)(in + (size_t)base);
  *(unsigned*)(out + (size_t)r * ldo + c) = pack4(v, 16.f);
}

// ===== 128x128 4-wave MX-fp8 GEMM, BK=128, single-buffer =====
// MODE 1: SwiGLU -> fp8 (cnt early-exit)  2: scatter fp8 (cnt early-exit)
// MODE 4: fp8 out  5: gelu -> fp8 (split-K A)  6: f32 out
template<int MODE>
__global__ __launch_bounds__(256, 3) void gemm128f8(
    const u8* __restrict__ A, const u8* __restrict__ A2, int splitK,
    const u8* __restrict__ B, void* __restrict__ C,
    const int* __restrict__ dst, const int* __restrict__ cnt,
    int Ksz, int lda, int ldb, int ldc, int ntm,
    size_t sA, size_t sB, size_t sC, unsigned sclA, unsigned sclB)
{
  __shared__ char smem[32768];
  int e = blockIdx.y;
  int nwgx = gridDim.x, bid0 = blockIdx.x;
  int q = nwgx >> 3, r = nwgx & 7;
  int xcd = bid0 & 7, lo2 = bid0 >> 3;
  int bid = (xcd < r ? xcd * (q + 1) : r * (q + 1) + (xcd - r) * q) + lo2;
  int tm = bid % ntm, tn = bid / ntm;
  if (MODE == 1 || MODE == 2) {
    if (tm * 128 >= cnt[e]) return;   // uniform: whole tile beyond expert fill
  }
  const u8* Ae = A + (size_t)e * sA;
  const u8* Be = B + (size_t)e * sB;
  long long bdelta = (const char*)A2 - (const char*)Ae;
  int tid = threadIdx.x, wv = tid >> 6, ln = tid & 63;
  int lnl = ln & 15, lnh = ln >> 4;

  const u8* aP[4]; const u8* bP[4];
  unsigned aL[4], bL[4];
  #pragma unroll
  for (int i = 0; i < 4; ++i) {
    int row = i * 32 + wv * 8 + (ln >> 3);
    int c = (ln & 7) ^ (row & 7);
    int cp = ((c & 3) << 1) | (c >> 2);
    aP[i] = Ae + (size_t)(tm * 128 + row) * lda + cp * 16;
    int brow;
    if (MODE == 1) {
      brow = (row < 64) ? (tn * 64 + row) : (Hv + tn * 64 + (row - 64));
    } else {
      brow = tn * 128 + row;
    }
    bP[i] = Be + (size_t)brow * ldb + cp * 16;
    aL[i] = i * 4096 + wv * 1024;
    bL[i] = 16384 + i * 4096 + wv * 1024;
  }

  int arow0 = wv * 32 + lnl;
  int ksw0 = (lnh << 4);
  int ksw1 = 64 + (lnh << 4);

  f32x4 acc[2][8];
  #pragma unroll
  for (int m = 0; m < 2; ++m)
    #pragma unroll
    for (int n = 0; n < 8; ++n) acc[m][n] = (f32x4){0.f, 0.f, 0.f, 0.f};

  for (int k0 = 0; k0 < Ksz; k0 += 128) {
    long long kbA;
    if (MODE == 5 && k0 >= splitK) kbA = bdelta + (long long)(k0 - splitK);
    else kbA = (long long)k0;
    #pragma unroll
    for (int i = 0; i < 4; ++i) gload16(aP[i] + kbA, smem + aL[i]);
    #pragma unroll
    for (int i = 0; i < 4; ++i) gload16(bP[i] + (size_t)k0, smem + bL[i]);
    __syncthreads();

    i32x8 af[2];
    #pragma unroll
    for (int mi = 0; mi < 2; ++mi) {
      int row = arow0 + mi * 16;
      int swz = (row & 7) << 4;
      *(i32x4*)&af[mi] = *(const i32x4*)(smem + row * 128 + (ksw0 ^ swz));
      *((i32x4*)&af[mi] + 1) = *(const i32x4*)(smem + row * 128 + (ksw1 ^ swz));
    }
    #pragma unroll
    for (int n = 0; n < 8; ++n) {
      int row = n * 16 + lnl;
      int swz = (row & 7) << 4;
      i32x8 bf;
      *(i32x4*)&bf = *(const i32x4*)(smem + 16384 + row * 128 + (ksw0 ^ swz));
      *((i32x4*)&bf + 1) = *(const i32x4*)(smem + 16384 + row * 128 + (ksw1 ^ swz));
      acc[0][n] = __builtin_amdgcn_mfma_scale_f32_16x16x128_f8f6f4(
          af[0], bf, acc[0][n], 0, 0, 0, sclA, 0, sclB);
      acc[1][n] = __builtin_amdgcn_mfma_scale_f32_16x16x128_f8f6f4(
          af[1], bf, acc[1][n], 0, 0, 0, sclA, 0, sclB);
    }
    __syncthreads();
  }

  int rbase = tm * 128 + wv * 32 + (lnh << 2);
  if (MODE == 1) {
    u8* Cp = (u8*)C + (size_t)e * sC;
    #pragma unroll
    for (int mi = 0; mi < 2; ++mi)
      #pragma unroll
      for (int n = 0; n < 4; ++n) {
        int col = tn * 64 + n * 16 + lnl;
        #pragma unroll
        for (int v = 0; v < 4; ++v) {
          float g = acc[mi][n][v];
          float u = acc[mi][n + 4][v];
          float sg = g / (1.f + __expf(-g));
          Cp[(size_t)(rbase + mi * 16 + v) * ldc + col] = (u8)f2e4(sg * u);
        }
      }
  } else if (MODE == 2) {
    u8* Cq = (u8*)C;
    #pragma unroll
    for (int mi = 0; mi < 2; ++mi)
      #pragma unroll
      for (int v = 0; v < 4; ++v) {
        int gr = rbase + mi * 16 + v;
        int i = dst[e * CAPv + gr];
        if (i >= 0) {
          #pragma unroll
          for (int n = 0; n < 8; ++n) {
            int col = tn * 128 + n * 16 + lnl;
            Cq[(size_t)i * Dv + col] = (u8)f2e4(acc[mi][n][v]);
          }
        }
      }
  } else if (MODE == 4) {
    u8* Cp = (u8*)C;
    #pragma unroll
    for (int mi = 0; mi < 2; ++mi)
      #pragma unroll
      for (int n = 0; n < 8; ++n) {
        int col = tn * 128 + n * 16 + lnl;
        #pragma unroll
        for (int v = 0; v < 4; ++v)
          Cp[(size_t)(rbase + mi * 16 + v) * ldc + col] = (u8)f2e4(acc[mi][n][v]);
      }
  } else if (MODE == 5) {
    u8* Cp = (u8*)C;
    #pragma unroll
    for (int mi = 0; mi < 2; ++mi)
      #pragma unroll
      for (int n = 0; n < 8; ++n) {
        int col = tn * 128 + n * 16 + lnl;
        #pragma unroll
        for (int v = 0; v < 4; ++v) {
          float xg = acc[mi][n][v];
          float gl = 0.5f * xg * (1.f + erff(xg * 0.70710678118654752f));
          Cp[(size_t)(rbase + mi * 16 + v) * ldc + col] = (u8)f2e4(gl);
        }
      }
  } else {
    float* Cp = (float*)C;
    #pragma unroll
    for (int mi = 0; mi < 2; ++mi)
      #pragma unroll
      for (int n = 0; n < 8; ++n) {
        int col = tn * 128 + n * 16 + lnl;
        #pragma unroll
        for (int v = 0; v < 4; ++v)
          Cp[(size_t)(rbase + mi * 16 + v) * ldc + col] = acc[mi][n][v];
      }
  }
}

// ---------------- scores + masked softmax + Cmsg ----------------
__global__ __launch_bounds__(256) void scores8_kernel(
    const u8* __restrict__ MQ, const u8* __restrict__ SEL8,
    const int* __restrict__ keep, u8* __restrict__ Cmsg)
{
  int wv = threadIdx.x >> 6, ln = threadIdx.x & 63;
  int n = blockIdx.x * 4 + wv;
  const u8* m0 = MQ + (size_t)(2 * n) * 2048;
  const u8* m1 = MQ + (size_t)(2 * n + 1) * 2048;
  const u8* t0 = m0 + 1024;
  const u8* t1 = m1 + 1024;
  const u8* s0p = SEL8 + (size_t)(2 * n) * 1024;
  const u8* s1p = SEL8 + (size_t)(2 * n + 1) * 1024;
  int d0 = ln * 16;
  float a0[16], a1[16], b0[16], b1[16];
  dec16(t0 + d0, a0); dec16(t1 + d0, a1);
  dec16(s0p + d0, b0); dec16(s1p + d0, b1);
  float s00 = 0, s01 = 0, s10 = 0, s11 = 0;
  #pragma unroll
  for (int t = 0; t < 16; ++t) {
    s00 += a0[t] * b0[t]; s01 += a0[t] * b1[t];
    s10 += a1[t] * b0[t]; s11 += a1[t] * b1[t];
  }
  #pragma unroll
  for (int off = 32; off >= 1; off >>= 1) {
    s00 += __shfl_xor(s00, off, 64);
    s01 += __shfl_xor(s01, off, 64);
    s10 += __shfl_xor(s10, off, 64);
    s11 += __shfl_xor(s11, off, 64);
  }
  const float inv = 0.03125f;
  int kp0 = keep[2 * n], kp1 = keep[2 * n + 1];
  float A00, A01, A10, A11;
  {
    float v0 = kp0 ? s00 * inv : -1e9f;
    float v1 = (kp0 && kp1) ? s01 * inv : -1e9f;
    float mx = fmaxf(v0, v1);
    float e0 = expf(v0 - mx), e1 = expf(v1 - mx);
    float den = e0 + e1;
    float a0v = kp0 ? e0 / den : 0.f;
    float a1v = (kp0 && kp1) ? e1 / den : 0.f;
    float s = fmaxf(a0v + a1v, 1e-12f);
    A00 = a0v / s; A01 = a1v / s;
  }
  {
    float v0 = (kp1 && kp0) ? s10 * inv : -1e9f;
    float v1 = kp1 ? s11 * inv : -1e9f;
    float mx = fmaxf(v0, v1);
    float e0 = expf(v0 - mx), e1 = expf(v1 - mx);
    float den = e0 + e1;
    float a0v = (kp1 && kp0) ? e0 / den : 0.f;
    float a1v = kp1 ? e1 / den : 0.f;
    float s = fmaxf(a0v + a1v, 1e-12f);
    A10 = a0v / s; A11 = a1v / s;
  }
  float f0[16], f1[16];
  dec16(m0 + d0, f0); dec16(m1 + d0, f1);
  unsigned o0[4], o1[4];
  #pragma unroll
  for (int j = 0; j < 4; ++j) {
    o0[j] = 0; o1[j] = 0;
    #pragma unroll
    for (int b = 0; b < 4; ++b) {
      int t = j * 4 + b;
      o0[j] |= f2e4(A00 * f0[t] + A01 * f1[t]) << (8 * b);
      o1[j] |= f2e4(A10 * f0[t] + A11 * f1[t]) << (8 * b);
    }
  }
  u8* c0 = Cmsg + (size_t)(2 * n) * 1024 + d0;
  u8* c1 = Cmsg + (size_t)(2 * n + 1) * 1024 + d0;
  #pragma unroll
  for (int j = 0; j < 4; ++j) {
    *(unsigned*)(c0 + j * 4) = o0[j];
    *(unsigned*)(c1 + j * 4) = o1[j];
  }
}

// ---------------- combine2: FCAT = [sum w_k sel_k | sum w_k gelu_k] fp8 ----------------
__global__ __launch_bounds__(256) void combine2_kernel(
    const u8* __restrict__ sel8, const u8* __restrict__ g8,
    const int* __restrict__ keep, const float* __restrict__ tkprob,
    u8* __restrict__ fcat)
{
  int n = blockIdx.x;
  int t = threadIdx.x;
  float kp0 = keep[2 * n] ? 1.f : 0.f, kp1 = keep[2 * n + 1] ? 1.f : 0.f;
  float p0 = tkprob[2 * n] * kp0, p1 = tkprob[2 * n + 1] * kp1;
  float s = fmaxf(p0 + p1, 1e-12f);
  float w0 = p0 / s, w1 = p1 / s;
  unsigned a = *(const unsigned*)(sel8 + (size_t)(2 * n) * 1024 + t * 4);
  unsigned b = *(const unsigned*)(sel8 + (size_t)(2 * n + 1) * 1024 + t * 4);
  unsigned o = 0;
  #pragma unroll
  for (int j = 0; j < 4; ++j)
    o |= f2e4(w0 * e42f((a >> (8 * j)) & 255u) + w1 * e42f((b >> (8 * j)) & 255u)) << (8 * j);
  *(unsigned*)(fcat + (size_t)n * 3072 + t * 4) = o;
  const u8* ga = g8 + (size_t)(2 * n) * 2048 + t * 8;
  const u8* gb = g8 + (size_t)(2 * n + 1) * 2048 + t * 8;
  #pragma unroll
  for (int h = 0; h < 2; ++h) {
    unsigned xa = *(const unsigned*)(ga + h * 4);
    unsigned xb = *(const unsigned*)(gb + h * 4);
    unsigned oo = 0;
    #pragma unroll
    for (int j = 0; j < 4; ++j)
      oo |= f2e4(w0 * e42f((xa >> (8 * j)) & 255u) + w1 * e42f((xb >> (8 * j)) & 255u)) << (8 * j);
    *(unsigned*)(fcat + (size_t)n * 3072 + 1024 + t * 8 + h * 4) = oo;
  }
}

extern "C" void kernel_launch(void* const* d_in, const int* in_sizes, int n_in,
                              void* d_out, int out_size, void* d_ws, size_t ws_size,
                              hipStream_t stream) {
  const float* x      = (const float*)d_in[0];
  const float* gate_w = (const float*)d_in[1];
  const float* w13    = (const float*)d_in[2];
  const float* w2     = (const float*)d_in[3];
  const float* msg_w  = (const float*)d_in[4];
  const float* q_w    = (const float*)d_in[5];
  const float* k_w    = (const float*)d_in[6];
  const float* upd_w1 = (const float*)d_in[7];
  const float* upd_w2 = (const float*)d_in[8];
  const float* o_w    = (const float*)d_in[9];
  float* out = (float*)d_out;
  float* outAux = out + (size_t)Nv * Dv;
  float* outIdx = outAux + 1;

  char* ws = (char*)d_ws;
  const size_t MBc = 1ull << 20;
  int*   tkidx  = (int*)(ws + 0);
  float* tkprob = (float*)(ws + 32768);
  int*   keepA  = (int*)(ws + 65536);
  int*   dstNK  = (int*)(ws + 98304);
  float* red    = (float*)(ws + 143360);
  int*   cntA   = (int*)(ws + 147456);
  // disjoint workspace map (fix of round-11 wprep aliasing race):
  u8*  BUF8  = (u8*)(ws + 1 * MBc);     // [1,9.4)
  u8*  ACT8  = (u8*)(ws + 12 * MBc);    // [12,40.8)
  u8*  W13B8 = (u8*)(ws + 41 * MBc);    // [41,85)  dead after G1
  u8*  M8s   = (u8*)(ws + 85 * MBc);    // [85,86)
  u8*  Q8s   = (u8*)(ws + 86 * MBc);    // [86,87)
  u8*  K8T   = (u8*)(ws + 87 * MBc);    // [87,88)
  u8*  W2B8r = (u8*)(ws + 88 * MBc);    // [88,110) live to G2
  u8*  U28s  = (u8*)(ws + 110 * MBc);   // [110,112)
  u8*  MTB8  = (u8*)(ws + 112 * MBc);   // [112,114)  [msg^T | W_s^T]
  u8*  WCAT8 = (u8*)(ws + 114 * MBc);   // [114,117)  [o_w^T | T2^T] ld 3072
  u8*  P38   = (u8*)(ws + 117 * MBc);   // [117,118)
  float* P3f = (float*)(ws + 118 * MBc);// [118,122)
  float* WsTf= (float*)(ws + 122 * MBc);// [122,126)
  float* T2Tf= (float*)(ws + 126 * MBc);// [126,134)
  u8*  SEL8  = (u8*)(ws + 136 * MBc);   // [136,144.4)
  u8*  UPD1B8= (u8*)(ws + 149 * MBc);   // [149,153)
  u8*  FCAT8 = (u8*)(ws + 160 * MBc);   // [160,172.6)
  // phase B overlays (BUF8/ACT8/W13B8 dead):
  u8*  MQ8   = (u8*)(ws + 1 * MBc);     // [1,18)
  u8*  CMSG8 = (u8*)(ws + 18 * MBc);    // [18,27)
  u8*  G1B8  = (u8*)(ws + 27 * MBc);    // [27,44)

  hipMemsetAsync(red, 0, 68, stream);
  hipMemsetAsync(dstNK, 0xFF, Ev * CAPv * 4, stream);
  hipMemsetAsync(SEL8, 0, (size_t)NKv * Dv, stream);

  router_kernel<<<Nv / 4, 256, 0, stream>>>(x, gate_w, tkidx, tkprob, red, outIdx);
  rank_kernel<<<1, 256, 0, stream>>>(tkidx, keepA, dstNK, cntA, red, outAux);
  pack8_kernel<<<(Ev * CAPv) / 4, 256, 0, stream>>>(x, dstNK, BUF8);

  // batched weight conversion (one launch) -- all outputs disjoint
  WTab T;
  T.in[0]=w13;    T.out[0]=W13B8; T.R[0]=Dv;   T.C[0]=TH2v; T.ldo[0]=Dv;   T.nxy[0]=88*16; T.nx[0]=88;
  T.in[1]=w2;     T.out[1]=W2B8r; T.R[1]=Hv;   T.C[1]=Dv;   T.ldo[1]=Hv;   T.nxy[1]=16*44; T.nx[1]=16;
  T.in[2]=upd_w1; T.out[2]=UPD1B8;T.R[2]=2048; T.C[2]=2048; T.ldo[2]=2048; T.nxy[2]=32*32; T.nx[2]=32;
  T.in[3]=msg_w;  T.out[3]=MTB8;  T.R[3]=Dv;   T.C[3]=Dv;   T.ldo[3]=Dv;   T.nxy[3]=256;   T.nx[3]=16;
  T.in[4]=o_w;    T.out[4]=WCAT8; T.R[4]=Dv;   T.C[4]=Dv;   T.ldo[4]=3072; T.nxy[4]=256;   T.nx[4]=16;
  T.in[5]=k_w;    T.out[5]=K8T;   T.R[5]=Dv;   T.C[5]=Dv;   T.ldo[5]=Dv;   T.nxy[5]=256;   T.nx[5]=16;
  T.in[6]=msg_w;  T.out[6]=M8s;   T.nx[6]=0; T.R[6]=0; T.C[6]=0; T.ldo[6]=0; T.nxy[6]=0;
  T.in[7]=q_w;    T.out[7]=Q8s;   T.nx[7]=0; T.R[7]=0; T.C[7]=0; T.ldo[7]=0; T.nxy[7]=0;
  T.in[8]=upd_w2; T.out[8]=U28s;  T.nx[8]=0; T.R[8]=0; T.C[8]=0; T.ldo[8]=0; T.nxy[8]=0;
  T.start[0]=0; T.start[1]=11264; T.start[2]=16896; T.start[3]=17920;
  T.start[4]=18176; T.start[5]=18432; T.start[6]=18688; T.start[7]=19712; T.start[8]=20736;
  wprep_kernel<<<22784, 256, 0, stream>>>(T);

  // G1: MX-fp8 SwiGLU -> ACT8 (early-exit via cntA)
  gemm128f8<1><<<dim3((CAPv / 128) * (Hv / 64), Ev), 256, 0, stream>>>(
      BUF8, BUF8, 1 << 30, W13B8, (void*)ACT8, nullptr, cntA,
      Dv, Dv, Dv, Hv, CAPv / 128,
      (size_t)CAPv * Dv, (size_t)TH2v * Dv, (size_t)CAPv * Hv, 0x7F7F7F7Fu, 0x7B7B7B7Bu);

  // W_s^T = (msg@k) @ q^T
  gemm128f8<6><<<dim3(64, 1), 256, 0, stream>>>(
      M8s, M8s, 1 << 30, K8T, (void*)P3f, nullptr, nullptr,
      Dv, Dv, Dv, Dv, 8, 0, 0, 0, 0x7B7B7B7Bu, 0x7B7B7B7Bu);
  conv8s_kernel<<<1024, 256, 0, stream>>>(P3f, P38);
  gemm128f8<6><<<dim3(64, 1), 256, 0, stream>>>(
      P38, P38, 1 << 30, Q8s, (void*)WsTf, nullptr, nullptr,
      Dv, Dv, Dv, Dv, 8, 0, 0, 0, 0x7B7B7B7Bu, 0x7B7B7B7Bu);
  conv8s_kernel<<<1024, 256, 0, stream>>>(WsTf, MTB8 + (size_t)Dv * Dv);
  // T2^T = o_w^T @ upd_w2^T  (A = fp8 o_w^T in WCAT8, lda 3072)
  gemm128f8<6><<<dim3(128, 1), 256, 0, stream>>>(
      WCAT8, WCAT8, 1 << 30, U28s, (void*)T2Tf, nullptr, nullptr,
      Dv, 3072, Dv, 2048, 8, 0, 0, 0, 0x7B7B7B7Bu, 0x7B7B7B7Bu);
  conv8st_kernel<<<2048, 256, 0, stream>>>(T2Tf, WCAT8 + 1024, 2048, 3072);

  // G2: MX-fp8 GEMM + scatter -> SEL8 (early-exit via cntA)
  gemm128f8<2><<<dim3((CAPv / 128) * (Dv / 128), Ev), 256, 0, stream>>>(
      ACT8, ACT8, 1 << 30, W2B8r, (void*)SEL8, dstNK, cntA,
      Hv, Hv, Hv, Dv, CAPv / 128,
      (size_t)CAPv * Hv, (size_t)Dv * Hv, 0, 0x7F7F7F7Fu, 0x7B7B7B7Bu);

  // collaboration: fused [M|T] GEMM, then scores
  gemm128f8<4><<<dim3(64 * 16, 1), 256, 0, stream>>>(
      SEL8, SEL8, 1 << 30, MTB8, (void*)MQ8, nullptr, nullptr,
      Dv, Dv, Dv, 2048, 64, 0, 0, 0, 0x7F7F7F7Fu, 0x7B7B7B7Bu);
  scores8_kernel<<<Nv / 4, 256, 0, stream>>>(MQ8, SEL8, keepA, CMSG8);

  // update MLP: gelu([SEL8|CMSG8] @ upd_w1) -> G1B8
  gemm128f8<5><<<dim3(64 * 16, 1), 256, 0, stream>>>(
      SEL8, CMSG8, Dv, UPD1B8, (void*)G1B8, nullptr, nullptr,
      2048, Dv, 2048, 2048, 64, 0, 0, 0, 0x7F7F7F7Fu, 0x7B7B7B7Bu);

  // FCAT = [sum w sel | sum w gelu], final fused GEMM -> out (f32)
  combine2_kernel<<<Nv, 256, 0, stream>>>(SEL8, G1B8, keepA, tkprob, FCAT8);
  gemm128f8<6><<<dim3(32 * 8, 1), 256, 0, stream>>>(
      FCAT8, FCAT8, 1 << 30, WCAT8, (void*)out, nullptr, nullptr,
      3072, 3072, 3072, Dv, 32, 0, 0, 0, 0x7F7F7F7Fu, 0x7B7B7B7Bu);

  (void)in_sizes; (void)n_in; (void)out_size; (void)ws_size;
}

// Round 13
// 415.796 us; speedup vs baseline: 1.6181x; 1.1077x over previous
//
#include <hip/hip_runtime.h>
#include <math.h>

#define Dv 1024
#define Ev 8
#define Hv 2816
#define Nv 4096
#define NKv 8192
#define CAPv 1280
#define TH2v 5632

typedef unsigned short u16;
typedef unsigned char u8;
typedef __attribute__((ext_vector_type(4))) float f32x4;
typedef __attribute__((ext_vector_type(4))) int i32x4;
typedef __attribute__((ext_vector_type(8))) int i32x8;

typedef const __attribute__((address_space(1))) void* as1_cvp;
typedef __attribute__((address_space(3))) void* as3_vp;

// f32 -> OCP e4m3fn, RNE, saturate to 448 (software fallback)
__device__ __forceinline__ unsigned f2e4(float f) {
  unsigned u = __float_as_uint(f);
  unsigned sgn = (u >> 24) & 0x80u;
  unsigned ax = u & 0x7FFFFFFFu;
  if (ax >= 0x43E00000u) return sgn | 0x7Eu;
  if (ax < 0x3C800000u) {
    int qv = (int)rintf(__uint_as_float(ax) * 512.f);
    return sgn | (unsigned)qv;
  }
  unsigned lsb = (ax >> 20) & 1u;
  unsigned rr = ax + 0x0007FFFFu + lsb;
  unsigned ee = rr >> 23;
  unsigned mm = (rr >> 20) & 7u;
  if (ee > 135u) return sgn | 0x7Eu;
  return sgn | ((ee - 120u) << 3) | mm;
}
// e4m3fn -> f32 (software fallback)
__device__ __forceinline__ float e42f(unsigned v) {
  unsigned s = (v & 0x80u) << 24, e = (v >> 3) & 15u, m = v & 7u;
  if (e) return __uint_as_float(s | ((e + 120u) << 23) | (m << 20));
  return __uint_as_float(__float_as_uint((float)m * 0.001953125f) | s);
}

// packed converters (HW when available)
__device__ __forceinline__ unsigned cvtpk4(float a, float b, float c, float d) {
#if __has_builtin(__builtin_amdgcn_cvt_pk_fp8_f32)
  int w = __builtin_amdgcn_cvt_pk_fp8_f32(a, b, 0, false);
  w = __builtin_amdgcn_cvt_pk_fp8_f32(c, d, w, true);
  return (unsigned)w;
#else
  return f2e4(a) | (f2e4(b) << 8) | (f2e4(c) << 16) | (f2e4(d) << 24);
#endif
}
__device__ __forceinline__ u8 f2e4h(float a) {
#if __has_builtin(__builtin_amdgcn_cvt_pk_fp8_f32)
  return (u8)(__builtin_amdgcn_cvt_pk_fp8_f32(a, a, 0, false) & 0xffu);
#else
  return (u8)f2e4(a);
#endif
}
__device__ __forceinline__ void dec16(const u8* p, float* o) {
  const unsigned* w = (const unsigned*)p;
#if __has_builtin(__builtin_amdgcn_cvt_pk_f32_fp8)
  #pragma unroll
  for (int j = 0; j < 4; ++j) {
    int x = (int)w[j];
    auto lo = __builtin_amdgcn_cvt_pk_f32_fp8(x, false);
    auto hi = __builtin_amdgcn_cvt_pk_f32_fp8(x, true);
    o[j*4+0] = lo[0]; o[j*4+1] = lo[1]; o[j*4+2] = hi[0]; o[j*4+3] = hi[1];
  }
#else
  #pragma unroll
  for (int j = 0; j < 4; ++j) {
    unsigned x = w[j];
    o[j*4+0] = e42f(x & 255u);
    o[j*4+1] = e42f((x >> 8) & 255u);
    o[j*4+2] = e42f((x >> 16) & 255u);
    o[j*4+3] = e42f((x >> 24) & 255u);
  }
#endif
}
__device__ __forceinline__ void dec4(unsigned x, float* o) {
#if __has_builtin(__builtin_amdgcn_cvt_pk_f32_fp8)
  auto lo = __builtin_amdgcn_cvt_pk_f32_fp8((int)x, false);
  auto hi = __builtin_amdgcn_cvt_pk_f32_fp8((int)x, true);
  o[0] = lo[0]; o[1] = lo[1]; o[2] = hi[0]; o[3] = hi[1];
#else
  o[0] = e42f(x & 255u); o[1] = e42f((x >> 8) & 255u);
  o[2] = e42f((x >> 16) & 255u); o[3] = e42f((x >> 24) & 255u);
#endif
}
__device__ __forceinline__ unsigned pack4(float4 v, float s) {
  return cvtpk4(v.x * s, v.y * s, v.z * s, v.w * s);
}
__device__ __forceinline__ void gload16(const void* g, void* l) {
  __builtin_amdgcn_global_load_lds((as1_cvp)g, (as3_vp)l, 16, 0, 0);
}

// ---------------- router ----------------
__global__ __launch_bounds__(256) void router_kernel(
    const float* __restrict__ x, const float* __restrict__ gw,
    int* __restrict__ tkidx, float* __restrict__ tkprob,
    float* __restrict__ red, float* __restrict__ outIdx)
{
  __shared__ float lred[17];
  int tid = threadIdx.x;
  if (tid < 17) lred[tid] = 0.f;
  __syncthreads();
  int wv = tid >> 6, ln = tid & 63;
  int n = blockIdx.x * 4 + wv;
  float a[8] = {0.f,0.f,0.f,0.f,0.f,0.f,0.f,0.f};
  const float* xr = x + (size_t)n * Dv;
  #pragma unroll
  for (int it = 0; it < 16; ++it) {
    int d = ln + it * 64;
    float xs = xr[d];
    float4 g0 = *(const float4*)(gw + (size_t)d * 8);
    float4 g1 = *(const float4*)(gw + (size_t)d * 8 + 4);
    a[0] += xs * g0.x; a[1] += xs * g0.y; a[2] += xs * g0.z; a[3] += xs * g0.w;
    a[4] += xs * g1.x; a[5] += xs * g1.y; a[6] += xs * g1.z; a[7] += xs * g1.w;
  }
  #pragma unroll
  for (int off = 32; off >= 1; off >>= 1) {
    #pragma unroll
    for (int e = 0; e < 8; ++e) a[e] += __shfl_xor(a[e], off, 64);
  }
  int i1 = 0; float v1 = a[0];
  #pragma unroll
  for (int e = 1; e < 8; ++e) if (a[e] > v1) { v1 = a[e]; i1 = e; }
  int i2 = -1; float v2 = -1e30f;
  #pragma unroll
  for (int e = 0; e < 8; ++e) if (e != i1 && a[e] > v2) { v2 = a[e]; i2 = e; }
  float Z = 0.f;
  #pragma unroll
  for (int e = 0; e < 8; ++e) Z += expf(a[e] - v1);
  float zlse = v1 + logf(Z);
  float t = expf(v2 - v1);
  float p1 = 1.f / (1.f + t);
  float p2 = t * p1;
  if (ln == 0) {
    tkidx[2*n] = i1; tkidx[2*n+1] = i2;
    tkprob[2*n] = p1; tkprob[2*n+1] = p2;
    outIdx[2*n] = (float)i1; outIdx[2*n+1] = (float)i2;
    #pragma unroll
    for (int e = 0; e < 8; ++e) atomicAdd(&lred[e], expf(a[e] - v1) / Z);
    atomicAdd(&lred[8 + i1], 1.f);
    atomicAdd(&lred[16], zlse * zlse);
  }
  __syncthreads();
  if (tid < 17) atomicAdd(&red[tid], lred[tid]);
}

// ---------------- exact stable rank + counts + aux ----------------
__global__ __launch_bounds__(256) void rank_kernel(const int* __restrict__ tgt,
    int* __restrict__ keep, int* __restrict__ dstNK, int* __restrict__ cnt,
    const float* __restrict__ red, float* __restrict__ outAux)
{
  __shared__ int hist[256][8];
  int t = threadIdx.x;
  int h[8] = {0,0,0,0,0,0,0,0};
  int base = t * 32;
  for (int j = 0; j < 32; ++j) h[tgt[base + j]]++;
  for (int e = 0; e < 8; ++e) hist[t][e] = h[e];
  __syncthreads();
  if (t < 8) {
    int run = 0;
    for (int tt = 0; tt < 256; ++tt) { int v = hist[tt][t]; hist[tt][t] = run; run += v; }
    cnt[t] = run < CAPv ? run : CAPv;
  }
  if (t == 0) {
    float bl = 0.f;
    for (int e = 0; e < 8; ++e) bl += (red[e] / (float)Nv) * (red[8 + e] / (float)Nv);
    bl *= (float)Ev;
    outAux[0] = 0.01f * bl + 0.001f * (red[16] / (float)Nv);
  }
  __syncthreads();
  for (int e = 0; e < 8; ++e) h[e] = hist[t][e];
  for (int j = 0; j < 32; ++j) {
    int i = base + j; int e = tgt[i]; int r = h[e]++;
    int kp = (r < CAPv) ? 1 : 0;
    keep[i] = kp;
    if (kp) dstNK[e * CAPv + r] = i;
  }
}

// ---------------- pack tokens -> fp8 ----------------
__global__ __launch_bounds__(256) void pack8_kernel(const float* __restrict__ x,
    const int* __restrict__ dstNK, u8* __restrict__ buf)
{
  int s = blockIdx.x * 4 + (threadIdx.x >> 6);
  int ln = threadIdx.x & 63;
  int i = dstNK[s];
  u8* dst = buf + (size_t)s * Dv;
  if (i >= 0) {
    const float* src = x + (size_t)(i >> 1) * Dv;
    #pragma unroll
    for (int j = 0; j < 4; ++j) {
      int d0 = ln * 16 + j * 4;
      float4 v = *(const float4*)(src + d0);
      *(unsigned*)(dst + d0) = pack4(v, 1.f);
    }
  } else {
    #pragma unroll
    for (int j = 0; j < 4; ++j) *(unsigned*)(dst + ln * 16 + j * 4) = 0u;
  }
}

// ---------------- batched weight conversion (f32 LDS transpose + HW cvt) ----------------
#define NSEG 9
struct WTab {
  const float* in[NSEG];
  u8* out[NSEG];
  int R[NSEG], C[NSEG], ldo[NSEG], nxy[NSEG], nx[NSEG];
  int start[NSEG];
};

__global__ __launch_bounds__(256) void wprep_kernel(WTab T) {
  __shared__ float tile[64][65];
  int b = blockIdx.x;
  int s = 0;
  #pragma unroll
  for (int i = 1; i < NSEG; ++i) if (b >= T.start[i]) s = i;
  int rb = b - T.start[s];
  const float* in = T.in[s];
  u8* out = T.out[s];
  int t = threadIdx.x;
  if (T.nx[s] == 0) {
    int i = rb * 256 + t;
    float4 v = *(const float4*)(in + (size_t)i * 4);
    *(unsigned*)(out + (size_t)i * 4) = pack4(v, 16.f);
    return;
  }
  int R = T.R[s], C = T.C[s], ldo = T.ldo[s];
  int z = rb / T.nxy[s], r2 = rb % T.nxy[s];
  int by = r2 / T.nx[s], bx = r2 % T.nx[s];
  in += (size_t)z * R * C;
  out += (size_t)z * (size_t)R * C;   // z>0 only when ldo==R (batched experts)
  int r0 = by * 64, c0 = bx * 64;
  int cc4 = (t & 15) * 4;
  #pragma unroll
  for (int p = 0; p < 4; ++p) {
    int r = (t >> 4) + p * 16;
    float4 v = *(const float4*)(in + (size_t)(r0 + r) * C + c0 + cc4);
    tile[r][cc4+0] = v.x; tile[r][cc4+1] = v.y;
    tile[r][cc4+2] = v.z; tile[r][cc4+3] = v.w;
  }
  __syncthreads();
  int rr4 = (t & 15) * 4;
  #pragma unroll
  for (int p = 0; p < 4; ++p) {
    int c = (t >> 4) + p * 16;
    unsigned w = cvtpk4(tile[rr4][c] * 16.f, tile[rr4+1][c] * 16.f,
                        tile[rr4+2][c] * 16.f, tile[rr4+3][c] * 16.f);
    *(unsigned*)(out + (size_t)(c0 + c) * ldo + r0 + rr4) = w;
  }
}

// ---------------- straight f32->e4m3 (x16), contiguous ----------------
__global__ __launch_bounds__(256) void conv8s_kernel(const float* __restrict__ in,
    u8* __restrict__ out)
{
  int i = blockIdx.x * 256 + threadIdx.x;
  float4 v = *(const float4*)(in + (size_t)i * 4);
  *(unsigned*)(out + (size_t)i * 4) = pack4(v, 16.f);
}

// ---------------- strided f32->e4m3 (x16): in [R][Cw] -> out rows stride ldo ----------------
__global__ __launch_bounds__(256) void conv8st_kernel(const float* __restrict__ in,
    u8* __restrict__ out, int Cw, int ldo)
{
  int i = blockIdx.x * 256 + threadIdx.x;
  int base = i * 4;
  int r = base / Cw, c = base & (Cw - 1);
  float4 v = *(const float4*)(in + (size_t)base);
  *(unsigned*)(out + (size_t)r * ldo + c) = pack4(v, 16.f);
}

// ===== 128x128 4-wave MX-fp8 GEMM, BK=128, single-buffer =====
// MODE 1: SwiGLU -> fp8 (cnt early-exit)  2: scatter fp8 (cnt early-exit)
// MODE 4: fp8 out  5: gelu -> fp8 (split-K A)  6: f32 out
template<int MODE>
__global__ __launch_bounds__(256, 3) void gemm128f8(
    const u8* __restrict__ A, const u8* __restrict__ A2, int splitK,
    const u8* __restrict__ B, void* __restrict__ C,
    const int* __restrict__ dst, const int* __restrict__ cnt,
    int Ksz, int lda, int ldb, int ldc, int ntm,
    size_t sA, size_t sB, size_t sC, unsigned sclA, unsigned sclB)
{
  __shared__ char smem[32768];
  int e = blockIdx.y;
  int nwgx = gridDim.x, bid0 = blockIdx.x;
  int q = nwgx >> 3, r = nwgx & 7;
  int xcd = bid0 & 7, lo2 = bid0 >> 3;
  int bid = (xcd < r ? xcd * (q + 1) : r * (q + 1) + (xcd - r) * q) + lo2;
  int tm = bid % ntm, tn = bid / ntm;
  if (MODE == 1 || MODE == 2) {
    if (tm * 128 >= cnt[e]) return;
  }
  const u8* Ae = A + (size_t)e * sA;
  const u8* Be = B + (size_t)e * sB;
  long long bdelta = (const char*)A2 - (const char*)Ae;
  int tid = threadIdx.x, wv = tid >> 6, ln = tid & 63;
  int lnl = ln & 15, lnh = ln >> 4;

  const u8* aP[4]; const u8* bP[4];
  unsigned aL[4], bL[4];
  #pragma unroll
  for (int i = 0; i < 4; ++i) {
    int row = i * 32 + wv * 8 + (ln >> 3);
    int c = (ln & 7) ^ (row & 7);
    int cp = ((c & 3) << 1) | (c >> 2);
    aP[i] = Ae + (size_t)(tm * 128 + row) * lda + cp * 16;
    int brow;
    if (MODE == 1) {
      brow = (row < 64) ? (tn * 64 + row) : (Hv + tn * 64 + (row - 64));
    } else {
      brow = tn * 128 + row;
    }
    bP[i] = Be + (size_t)brow * ldb + cp * 16;
    aL[i] = i * 4096 + wv * 1024;
    bL[i] = 16384 + i * 4096 + wv * 1024;
  }

  int arow0 = wv * 32 + lnl;
  int ksw0 = (lnh << 4);
  int ksw1 = 64 + (lnh << 4);

  f32x4 acc[2][8];
  #pragma unroll
  for (int m = 0; m < 2; ++m)
    #pragma unroll
    for (int n = 0; n < 8; ++n) acc[m][n] = (f32x4){0.f, 0.f, 0.f, 0.f};

  for (int k0 = 0; k0 < Ksz; k0 += 128) {
    long long kbA;
    if (MODE == 5 && k0 >= splitK) kbA = bdelta + (long long)(k0 - splitK);
    else kbA = (long long)k0;
    #pragma unroll
    for (int i = 0; i < 4; ++i) gload16(aP[i] + kbA, smem + aL[i]);
    #pragma unroll
    for (int i = 0; i < 4; ++i) gload16(bP[i] + (size_t)k0, smem + bL[i]);
    __syncthreads();

    i32x8 af[2];
    #pragma unroll
    for (int mi = 0; mi < 2; ++mi) {
      int row = arow0 + mi * 16;
      int swz = (row & 7) << 4;
      *(i32x4*)&af[mi] = *(const i32x4*)(smem + row * 128 + (ksw0 ^ swz));
      *((i32x4*)&af[mi] + 1) = *(const i32x4*)(smem + row * 128 + (ksw1 ^ swz));
    }
    #pragma unroll
    for (int n = 0; n < 8; ++n) {
      int row = n * 16 + lnl;
      int swz = (row & 7) << 4;
      i32x8 bf;
      *(i32x4*)&bf = *(const i32x4*)(smem + 16384 + row * 128 + (ksw0 ^ swz));
      *((i32x4*)&bf + 1) = *(const i32x4*)(smem + 16384 + row * 128 + (ksw1 ^ swz));
      acc[0][n] = __builtin_amdgcn_mfma_scale_f32_16x16x128_f8f6f4(
          af[0], bf, acc[0][n], 0, 0, 0, sclA, 0, sclB);
      acc[1][n] = __builtin_amdgcn_mfma_scale_f32_16x16x128_f8f6f4(
          af[1], bf, acc[1][n], 0, 0, 0, sclA, 0, sclB);
    }
    __syncthreads();
  }

  int rbase = tm * 128 + wv * 32 + (lnh << 2);
  if (MODE == 1) {
    u8* Cp = (u8*)C + (size_t)e * sC;
    #pragma unroll
    for (int mi = 0; mi < 2; ++mi)
      #pragma unroll
      for (int n = 0; n < 4; ++n) {
        int col = tn * 64 + n * 16 + lnl;
        #pragma unroll
        for (int v = 0; v < 4; ++v) {
          float g = acc[mi][n][v];
          float u = acc[mi][n + 4][v];
          float sg = g / (1.f + __expf(-g));
          Cp[(size_t)(rbase + mi * 16 + v) * ldc + col] = f2e4h(sg * u);
        }
      }
  } else if (MODE == 2) {
    u8* Cq = (u8*)C;
    #pragma unroll
    for (int mi = 0; mi < 2; ++mi)
      #pragma unroll
      for (int v = 0; v < 4; ++v) {
        int gr = rbase + mi * 16 + v;
        int i = dst[e * CAPv + gr];
        if (i >= 0) {
          #pragma unroll
          for (int n = 0; n < 8; ++n) {
            int col = tn * 128 + n * 16 + lnl;
            Cq[(size_t)i * Dv + col] = f2e4h(acc[mi][n][v]);
          }
        }
      }
  } else if (MODE == 4) {
    u8* Cp = (u8*)C;
    #pragma unroll
    for (int mi = 0; mi < 2; ++mi)
      #pragma unroll
      for (int n = 0; n < 8; ++n) {
        int col = tn * 128 + n * 16 + lnl;
        #pragma unroll
        for (int v = 0; v < 4; ++v)
          Cp[(size_t)(rbase + mi * 16 + v) * ldc + col] = f2e4h(acc[mi][n][v]);
      }
  } else if (MODE == 5) {
    u8* Cp = (u8*)C;
    #pragma unroll
    for (int mi = 0; mi < 2; ++mi)
      #pragma unroll
      for (int n = 0; n < 8; ++n) {
        int col = tn * 128 + n * 16 + lnl;
        #pragma unroll
        for (int v = 0; v < 4; ++v) {
          float xg = acc[mi][n][v];
          float gl = 0.5f * xg * (1.f + erff(xg * 0.70710678118654752f));
          Cp[(size_t)(rbase + mi * 16 + v) * ldc + col] = f2e4h(gl);
        }
      }
  } else {
    float* Cp = (float*)C;
    #pragma unroll
    for (int mi = 0; mi < 2; ++mi)
      #pragma unroll
      for (int n = 0; n < 8; ++n) {
        int col = tn * 128 + n * 16 + lnl;
        #pragma unroll
        for (int v = 0; v < 4; ++v)
          Cp[(size_t)(rbase + mi * 16 + v) * ldc + col] = acc[mi][n][v];
      }
  }
}

// ---------------- scores + masked softmax + Cmsg ----------------
__global__ __launch_bounds__(256) void scores8_kernel(
    const u8* __restrict__ MQ, const u8* __restrict__ SEL8,
    const int* __restrict__ keep, u8* __restrict__ Cmsg)
{
  int wv = threadIdx.x >> 6, ln = threadIdx.x & 63;
  int n = blockIdx.x * 4 + wv;
  const u8* m0 = MQ + (size_t)(2 * n) * 2048;
  const u8* m1 = MQ + (size_t)(2 * n + 1) * 2048;
  const u8* t0 = m0 + 1024;
  const u8* t1 = m1 + 1024;
  const u8* s0p = SEL8 + (size_t)(2 * n) * 1024;
  const u8* s1p = SEL8 + (size_t)(2 * n + 1) * 1024;
  int d0 = ln * 16;
  float a0[16], a1[16], b0[16], b1[16];
  dec16(t0 + d0, a0); dec16(t1 + d0, a1);
  dec16(s0p + d0, b0); dec16(s1p + d0, b1);
  float s00 = 0, s01 = 0, s10 = 0, s11 = 0;
  #pragma unroll
  for (int t = 0; t < 16; ++t) {
    s00 += a0[t] * b0[t]; s01 += a0[t] * b1[t];
    s10 += a1[t] * b0[t]; s11 += a1[t] * b1[t];
  }
  #pragma unroll
  for (int off = 32; off >= 1; off >>= 1) {
    s00 += __shfl_xor(s00, off, 64);
    s01 += __shfl_xor(s01, off, 64);
    s10 += __shfl_xor(s10, off, 64);
    s11 += __shfl_xor(s11, off, 64);
  }
  const float inv = 0.03125f;
  int kp0 = keep[2 * n], kp1 = keep[2 * n + 1];
  float A00, A01, A10, A11;
  {
    float v0 = kp0 ? s00 * inv : -1e9f;
    float v1 = (kp0 && kp1) ? s01 * inv : -1e9f;
    float mx = fmaxf(v0, v1);
    float e0 = expf(v0 - mx), e1 = expf(v1 - mx);
    float den = e0 + e1;
    float a0v = kp0 ? e0 / den : 0.f;
    float a1v = (kp0 && kp1) ? e1 / den : 0.f;
    float s = fmaxf(a0v + a1v, 1e-12f);
    A00 = a0v / s; A01 = a1v / s;
  }
  {
    float v0 = (kp1 && kp0) ? s10 * inv : -1e9f;
    float v1 = kp1 ? s11 * inv : -1e9f;
    float mx = fmaxf(v0, v1);
    float e0 = expf(v0 - mx), e1 = expf(v1 - mx);
    float den = e0 + e1;
    float a0v = (kp1 && kp0) ? e0 / den : 0.f;
    float a1v = kp1 ? e1 / den : 0.f;
    float s = fmaxf(a0v + a1v, 1e-12f);
    A10 = a0v / s; A11 = a1v / s;
  }
  float f0[16], f1[16];
  dec16(m0 + d0, f0); dec16(m1 + d0, f1);
  u8* c0 = Cmsg + (size_t)(2 * n) * 1024 + d0;
  u8* c1 = Cmsg + (size_t)(2 * n + 1) * 1024 + d0;
  #pragma unroll
  for (int j = 0; j < 4; ++j) {
    int t = j * 4;
    *(unsigned*)(c0 + j * 4) = cvtpk4(
        A00 * f0[t] + A01 * f1[t],     A00 * f0[t+1] + A01 * f1[t+1],
        A00 * f0[t+2] + A01 * f1[t+2], A00 * f0[t+3] + A01 * f1[t+3]);
    *(unsigned*)(c1 + j * 4) = cvtpk4(
        A10 * f0[t] + A11 * f1[t],     A10 * f0[t+1] + A11 * f1[t+1],
        A10 * f0[t+2] + A11 * f1[t+2], A10 * f0[t+3] + A11 * f1[t+3]);
  }
}

// ---------------- combine2: FCAT = [sum w_k sel_k | sum w_k gelu_k] fp8 ----------------
__global__ __launch_bounds__(256) void combine2_kernel(
    const u8* __restrict__ sel8, const u8* __restrict__ g8,
    const int* __restrict__ keep, const float* __restrict__ tkprob,
    u8* __restrict__ fcat)
{
  int n = blockIdx.x;
  int t = threadIdx.x;
  float kp0 = keep[2 * n] ? 1.f : 0.f, kp1 = keep[2 * n + 1] ? 1.f : 0.f;
  float p0 = tkprob[2 * n] * kp0, p1 = tkprob[2 * n + 1] * kp1;
  float s = fmaxf(p0 + p1, 1e-12f);
  float w0 = p0 / s, w1 = p1 / s;
  unsigned a = *(const unsigned*)(sel8 + (size_t)(2 * n) * 1024 + t * 4);
  unsigned b = *(const unsigned*)(sel8 + (size_t)(2 * n + 1) * 1024 + t * 4);
  float fa[4], fb[4];
  dec4(a, fa); dec4(b, fb);
  *(unsigned*)(fcat + (size_t)n * 3072 + t * 4) = cvtpk4(
      w0 * fa[0] + w1 * fb[0], w0 * fa[1] + w1 * fb[1],
      w0 * fa[2] + w1 * fb[2], w0 * fa[3] + w1 * fb[3]);
  const u8* ga = g8 + (size_t)(2 * n) * 2048 + t * 8;
  const u8* gb = g8 + (size_t)(2 * n + 1) * 2048 + t * 8;
  #pragma unroll
  for (int h = 0; h < 2; ++h) {
    unsigned xa = *(const unsigned*)(ga + h * 4);
    unsigned xb = *(const unsigned*)(gb + h * 4);
    dec4(xa, fa); dec4(xb, fb);
    *(unsigned*)(fcat + (size_t)n * 3072 + 1024 + t * 8 + h * 4) = cvtpk4(
        w0 * fa[0] + w1 * fb[0], w0 * fa[1] + w1 * fb[1],
        w0 * fa[2] + w1 * fb[2], w0 * fa[3] + w1 * fb[3]);
  }
}

extern "C" void kernel_launch(void* const* d_in, const int* in_sizes, int n_in,
                              void* d_out, int out_size, void* d_ws, size_t ws_size,
                              hipStream_t stream) {
  const float* x      = (const float*)d_in[0];
  const float* gate_w = (const float*)d_in[1];
  const float* w13    = (const float*)d_in[2];
  const float* w2     = (const float*)d_in[3];
  const float* msg_w  = (const float*)d_in[4];
  const float* q_w    = (const float*)d_in[5];
  const float* k_w    = (const float*)d_in[6];
  const float* upd_w1 = (const float*)d_in[7];
  const float* upd_w2 = (const float*)d_in[8];
  const float* o_w    = (const float*)d_in[9];
  float* out = (float*)d_out;
  float* outAux = out + (size_t)Nv * Dv;
  float* outIdx = outAux + 1;

  char* ws = (char*)d_ws;
  const size_t MBc = 1ull << 20;
  int*   tkidx  = (int*)(ws + 0);
  float* tkprob = (float*)(ws + 32768);
  int*   keepA  = (int*)(ws + 65536);
  int*   dstNK  = (int*)(ws + 98304);
  float* red    = (float*)(ws + 143360);
  int*   cntA   = (int*)(ws + 147456);
  u8*  BUF8  = (u8*)(ws + 1 * MBc);
  u8*  ACT8  = (u8*)(ws + 12 * MBc);
  u8*  W13B8 = (u8*)(ws + 41 * MBc);
  u8*  M8s   = (u8*)(ws + 85 * MBc);
  u8*  Q8s   = (u8*)(ws + 86 * MBc);
  u8*  K8T   = (u8*)(ws + 87 * MBc);
  u8*  W2B8r = (u8*)(ws + 88 * MBc);
  u8*  U28s  = (u8*)(ws + 110 * MBc);
  u8*  MTB8  = (u8*)(ws + 112 * MBc);
  u8*  WCAT8 = (u8*)(ws + 114 * MBc);
  u8*  P38   = (u8*)(ws + 117 * MBc);
  float* P3f = (float*)(ws + 118 * MBc);
  float* WsTf= (float*)(ws + 122 * MBc);
  float* T2Tf= (float*)(ws + 126 * MBc);
  u8*  SEL8  = (u8*)(ws + 136 * MBc);
  u8*  UPD1B8= (u8*)(ws + 149 * MBc);
  u8*  FCAT8 = (u8*)(ws + 160 * MBc);
  u8*  MQ8   = (u8*)(ws + 1 * MBc);
  u8*  CMSG8 = (u8*)(ws + 18 * MBc);
  u8*  G1B8  = (u8*)(ws + 27 * MBc);

  hipMemsetAsync(red, 0, 68, stream);
  hipMemsetAsync(dstNK, 0xFF, Ev * CAPv * 4, stream);
  hipMemsetAsync(SEL8, 0, (size_t)NKv * Dv, stream);

  router_kernel<<<Nv / 4, 256, 0, stream>>>(x, gate_w, tkidx, tkprob, red, outIdx);
  rank_kernel<<<1, 256, 0, stream>>>(tkidx, keepA, dstNK, cntA, red, outAux);
  pack8_kernel<<<(Ev * CAPv) / 4, 256, 0, stream>>>(x, dstNK, BUF8);

  WTab T;
  T.in[0]=w13;    T.out[0]=W13B8; T.R[0]=Dv;   T.C[0]=TH2v; T.ldo[0]=Dv;   T.nxy[0]=88*16; T.nx[0]=88;
  T.in[1]=w2;     T.out[1]=W2B8r; T.R[1]=Hv;   T.C[1]=Dv;   T.ldo[1]=Hv;   T.nxy[1]=16*44; T.nx[1]=16;
  T.in[2]=upd_w1; T.out[2]=UPD1B8;T.R[2]=2048; T.C[2]=2048; T.ldo[2]=2048; T.nxy[2]=32*32; T.nx[2]=32;
  T.in[3]=msg_w;  T.out[3]=MTB8;  T.R[3]=Dv;   T.C[3]=Dv;   T.ldo[3]=Dv;   T.nxy[3]=256;   T.nx[3]=16;
  T.in[4]=o_w;    T.out[4]=WCAT8; T.R[4]=Dv;   T.C[4]=Dv;   T.ldo[4]=3072; T.nxy[4]=256;   T.nx[4]=16;
  T.in[5]=k_w;    T.out[5]=K8T;   T.R[5]=Dv;   T.C[5]=Dv;   T.ldo[5]=Dv;   T.nxy[5]=256;   T.nx[5]=16;
  T.in[6]=msg_w;  T.out[6]=M8s;   T.nx[6]=0; T.R[6]=0; T.C[6]=0; T.ldo[6]=0; T.nxy[6]=0;
  T.in[7]=q_w;    T.out[7]=Q8s;   T.nx[7]=0; T.R[7]=0; T.C[7]=0; T.ldo[7]=0; T.nxy[7]=0;
  T.in[8]=upd_w2; T.out[8]=U28s;  T.nx[8]=0; T.R[8]=0; T.C[8]=0; T.ldo[8]=0; T.nxy[8]=0;
  T.start[0]=0; T.start[1]=11264; T.start[2]=16896; T.start[3]=17920;
  T.start[4]=18176; T.start[5]=18432; T.start[6]=18688; T.start[7]=19712; T.start[8]=20736;
  wprep_kernel<<<22784, 256, 0, stream>>>(T);

  // G1: MX-fp8 SwiGLU -> ACT8 (early-exit via cntA)
  gemm128f8<1><<<dim3((CAPv / 128) * (Hv / 64), Ev), 256, 0, stream>>>(
      BUF8, BUF8, 1 << 30, W13B8, (void*)ACT8, nullptr, cntA,
      Dv, Dv, Dv, Hv, CAPv / 128,
      (size_t)CAPv * Dv, (size_t)TH2v * Dv, (size_t)CAPv * Hv, 0x7F7F7F7Fu, 0x7B7B7B7Bu);

  // W_s^T = (msg@k) @ q^T
  gemm128f8<6><<<dim3(64, 1), 256, 0, stream>>>(
      M8s, M8s, 1 << 30, K8T, (void*)P3f, nullptr, nullptr,
      Dv, Dv, Dv, Dv, 8, 0, 0, 0, 0x7B7B7B7Bu, 0x7B7B7B7Bu);
  conv8s_kernel<<<1024, 256, 0, stream>>>(P3f, P38);
  gemm128f8<6><<<dim3(64, 1), 256, 0, stream>>>(
      P38, P38, 1 << 30, Q8s, (void*)WsTf, nullptr, nullptr,
      Dv, Dv, Dv, Dv, 8, 0, 0, 0, 0x7B7B7B7Bu, 0x7B7B7B7Bu);
  conv8s_kernel<<<1024, 256, 0, stream>>>(WsTf, MTB8 + (size_t)Dv * Dv);
  // T2^T = o_w^T @ upd_w2^T  (A = fp8 o_w^T in WCAT8, lda 3072)
  gemm128f8<6><<<dim3(128, 1), 256, 0, stream>>>(
      WCAT8, WCAT8, 1 << 30, U28s, (void*)T2Tf, nullptr, nullptr,
      Dv, 3072, Dv, 2048, 8, 0, 0, 0, 0x7B7B7B7Bu, 0x7B7B7B7Bu);
  conv8st_kernel<<<2048, 256, 0, stream>>>(T2Tf, WCAT8 + 1024, 2048, 3072);

  // G2: MX-fp8 GEMM + scatter -> SEL8 (early-exit via cntA)
  gemm128f8<2><<<dim3((CAPv / 128) * (Dv / 128), Ev), 256, 0, stream>>>(
      ACT8, ACT8, 1 << 30, W2B8r, (void*)SEL8, dstNK, cntA,
      Hv, Hv, Hv, Dv, CAPv / 128,
      (size_t)CAPv * Hv, (size_t)Dv * Hv, 0, 0x7F7F7F7Fu, 0x7B7B7B7Bu);

  // collaboration: fused [M|T] GEMM, then scores
  gemm128f8<4><<<dim3(64 * 16, 1), 256, 0, stream>>>(
      SEL8, SEL8, 1 << 30, MTB8, (void*)MQ8, nullptr, nullptr,
      Dv, Dv, Dv, 2048, 64, 0, 0, 0, 0x7F7F7F7Fu, 0x7B7B7B7Bu);
  scores8_kernel<<<Nv / 4, 256, 0, stream>>>(MQ8, SEL8, keepA, CMSG8);

  // update MLP: gelu([SEL8|CMSG8] @ upd_w1) -> G1B8
  gemm128f8<5><<<dim3(64 * 16, 1), 256, 0, stream>>>(
      SEL8, CMSG8, Dv, UPD1B8, (void*)G1B8, nullptr, nullptr,
      2048, Dv, 2048, 2048, 64, 0, 0, 0, 0x7F7F7F7Fu, 0x7B7B7B7Bu);

  // FCAT = [sum w sel | sum w gelu], final fused GEMM -> out (f32)
  combine2_kernel<<<Nv, 256, 0, stream>>>(SEL8, G1B8, keepA, tkprob, FCAT8);
  gemm128f8<6><<<dim3(32 * 8, 1), 256, 0, stream>>>(
      FCAT8, FCAT8, 1 << 30, WCAT8, (void*)out, nullptr, nullptr,
      3072, 3072, 3072, Dv, 32, 0, 0, 0, 0x7F7F7F7Fu, 0x7B7B7B7Bu);

  (void)in_sizes; (void)n_in; (void)out_size; (void)ws_size;
}

// Round 14
// 409.626 us; speedup vs baseline: 1.6425x; 1.0151x over previous
//
#include <hip/hip_runtime.h>
#include <math.h>

#define Dv 1024
#define Ev 8
#define Hv 2816
#define Nv 4096
#define NKv 8192
#define CAPv 1280
#define TH2v 5632

typedef unsigned short u16;
typedef unsigned char u8;
typedef __attribute__((ext_vector_type(4))) float f32x4;
typedef __attribute__((ext_vector_type(4))) int i32x4;
typedef __attribute__((ext_vector_type(8))) int i32x8;
typedef __attribute__((ext_vector_type(4))) unsigned u32x4;

typedef const __attribute__((address_space(1))) void* as1_cvp;
typedef __attribute__((address_space(3))) void* as3_vp;

// f32 -> OCP e4m3fn, RNE, saturate to 448 (software fallback)
__device__ __forceinline__ unsigned f2e4(float f) {
  unsigned u = __float_as_uint(f);
  unsigned sgn = (u >> 24) & 0x80u;
  unsigned ax = u & 0x7FFFFFFFu;
  if (ax >= 0x43E00000u) return sgn | 0x7Eu;
  if (ax < 0x3C800000u) {
    int qv = (int)rintf(__uint_as_float(ax) * 512.f);
    return sgn | (unsigned)qv;
  }
  unsigned lsb = (ax >> 20) & 1u;
  unsigned rr = ax + 0x0007FFFFu + lsb;
  unsigned ee = rr >> 23;
  unsigned mm = (rr >> 20) & 7u;
  if (ee > 135u) return sgn | 0x7Eu;
  return sgn | ((ee - 120u) << 3) | mm;
}
// e4m3fn -> f32 (software fallback)
__device__ __forceinline__ float e42f(unsigned v) {
  unsigned s = (v & 0x80u) << 24, e = (v >> 3) & 15u, m = v & 7u;
  if (e) return __uint_as_float(s | ((e + 120u) << 23) | (m << 20));
  return __uint_as_float(__float_as_uint((float)m * 0.001953125f) | s);
}

// packed converters (HW when available)
__device__ __forceinline__ unsigned cvtpk4(float a, float b, float c, float d) {
#if __has_builtin(__builtin_amdgcn_cvt_pk_fp8_f32)
  int w = __builtin_amdgcn_cvt_pk_fp8_f32(a, b, 0, false);
  w = __builtin_amdgcn_cvt_pk_fp8_f32(c, d, w, true);
  return (unsigned)w;
#else
  return f2e4(a) | (f2e4(b) << 8) | (f2e4(c) << 16) | (f2e4(d) << 24);
#endif
}
__device__ __forceinline__ u8 f2e4h(float a) {
#if __has_builtin(__builtin_amdgcn_cvt_pk_fp8_f32)
  return (u8)(__builtin_amdgcn_cvt_pk_fp8_f32(a, a, 0, false) & 0xffu);
#else
  return (u8)f2e4(a);
#endif
}
__device__ __forceinline__ void dec16(const u8* p, float* o) {
  const unsigned* w = (const unsigned*)p;
#if __has_builtin(__builtin_amdgcn_cvt_pk_f32_fp8)
  #pragma unroll
  for (int j = 0; j < 4; ++j) {
    int x = (int)w[j];
    auto lo = __builtin_amdgcn_cvt_pk_f32_fp8(x, false);
    auto hi = __builtin_amdgcn_cvt_pk_f32_fp8(x, true);
    o[j*4+0] = lo[0]; o[j*4+1] = lo[1]; o[j*4+2] = hi[0]; o[j*4+3] = hi[1];
  }
#else
  #pragma unroll
  for (int j = 0; j < 4; ++j) {
    unsigned x = w[j];
    o[j*4+0] = e42f(x & 255u);
    o[j*4+1] = e42f((x >> 8) & 255u);
    o[j*4+2] = e42f((x >> 16) & 255u);
    o[j*4+3] = e42f((x >> 24) & 255u);
  }
#endif
}
__device__ __forceinline__ void dec4(unsigned x, float* o) {
#if __has_builtin(__builtin_amdgcn_cvt_pk_f32_fp8)
  auto lo = __builtin_amdgcn_cvt_pk_f32_fp8((int)x, false);
  auto hi = __builtin_amdgcn_cvt_pk_f32_fp8((int)x, true);
  o[0] = lo[0]; o[1] = lo[1]; o[2] = hi[0]; o[3] = hi[1];
#else
  o[0] = e42f(x & 255u); o[1] = e42f((x >> 8) & 255u);
  o[2] = e42f((x >> 16) & 255u); o[3] = e42f((x >> 24) & 255u);
#endif
}
__device__ __forceinline__ unsigned pack4(float4 v, float s) {
  return cvtpk4(v.x * s, v.y * s, v.z * s, v.w * s);
}
__device__ __forceinline__ void gload16(const void* g, void* l) {
  __builtin_amdgcn_global_load_lds((as1_cvp)g, (as3_vp)l, 16, 0, 0);
}

// ---------------- router ----------------
__global__ __launch_bounds__(256) void router_kernel(
    const float* __restrict__ x, const float* __restrict__ gw,
    int* __restrict__ tkidx, float* __restrict__ tkprob,
    float* __restrict__ red, float* __restrict__ outIdx)
{
  __shared__ float lred[17];
  int tid = threadIdx.x;
  if (tid < 17) lred[tid] = 0.f;
  __syncthreads();
  int wv = tid >> 6, ln = tid & 63;
  int n = blockIdx.x * 4 + wv;
  float a[8] = {0.f,0.f,0.f,0.f,0.f,0.f,0.f,0.f};
  const float* xr = x + (size_t)n * Dv;
  #pragma unroll
  for (int it = 0; it < 16; ++it) {
    int d = ln + it * 64;
    float xs = xr[d];
    float4 g0 = *(const float4*)(gw + (size_t)d * 8);
    float4 g1 = *(const float4*)(gw + (size_t)d * 8 + 4);
    a[0] += xs * g0.x; a[1] += xs * g0.y; a[2] += xs * g0.z; a[3] += xs * g0.w;
    a[4] += xs * g1.x; a[5] += xs * g1.y; a[6] += xs * g1.z; a[7] += xs * g1.w;
  }
  #pragma unroll
  for (int off = 32; off >= 1; off >>= 1) {
    #pragma unroll
    for (int e = 0; e < 8; ++e) a[e] += __shfl_xor(a[e], off, 64);
  }
  int i1 = 0; float v1 = a[0];
  #pragma unroll
  for (int e = 1; e < 8; ++e) if (a[e] > v1) { v1 = a[e]; i1 = e; }
  int i2 = -1; float v2 = -1e30f;
  #pragma unroll
  for (int e = 0; e < 8; ++e) if (e != i1 && a[e] > v2) { v2 = a[e]; i2 = e; }
  float Z = 0.f;
  #pragma unroll
  for (int e = 0; e < 8; ++e) Z += expf(a[e] - v1);
  float zlse = v1 + logf(Z);
  float t = expf(v2 - v1);
  float p1 = 1.f / (1.f + t);
  float p2 = t * p1;
  if (ln == 0) {
    tkidx[2*n] = i1; tkidx[2*n+1] = i2;
    tkprob[2*n] = p1; tkprob[2*n+1] = p2;
    outIdx[2*n] = (float)i1; outIdx[2*n+1] = (float)i2;
    #pragma unroll
    for (int e = 0; e < 8; ++e) atomicAdd(&lred[e], expf(a[e] - v1) / Z);
    atomicAdd(&lred[8 + i1], 1.f);
    atomicAdd(&lred[16], zlse * zlse);
  }
  __syncthreads();
  if (tid < 17) atomicAdd(&red[tid], lred[tid]);
}

// ---------------- exact stable rank + counts + aux ----------------
__global__ __launch_bounds__(256) void rank_kernel(const int* __restrict__ tgt,
    int* __restrict__ keep, int* __restrict__ dstNK, int* __restrict__ cnt,
    const float* __restrict__ red, float* __restrict__ outAux)
{
  __shared__ int hist[256][8];
  int t = threadIdx.x;
  int h[8] = {0,0,0,0,0,0,0,0};
  int base = t * 32;
  for (int j = 0; j < 32; ++j) h[tgt[base + j]]++;
  for (int e = 0; e < 8; ++e) hist[t][e] = h[e];
  __syncthreads();
  if (t < 8) {
    int run = 0;
    for (int tt = 0; tt < 256; ++tt) { int v = hist[tt][t]; hist[tt][t] = run; run += v; }
    cnt[t] = run < CAPv ? run : CAPv;
  }
  if (t == 0) {
    float bl = 0.f;
    for (int e = 0; e < 8; ++e) bl += (red[e] / (float)Nv) * (red[8 + e] / (float)Nv);
    bl *= (float)Ev;
    outAux[0] = 0.01f * bl + 0.001f * (red[16] / (float)Nv);
  }
  __syncthreads();
  for (int e = 0; e < 8; ++e) h[e] = hist[t][e];
  for (int j = 0; j < 32; ++j) {
    int i = base + j; int e = tgt[i]; int r = h[e]++;
    int kp = (r < CAPv) ? 1 : 0;
    keep[i] = kp;
    if (kp) dstNK[e * CAPv + r] = i;
  }
}

// ---------------- pack tokens -> fp8 ----------------
__global__ __launch_bounds__(256) void pack8_kernel(const float* __restrict__ x,
    const int* __restrict__ dstNK, u8* __restrict__ buf)
{
  int s = blockIdx.x * 4 + (threadIdx.x >> 6);
  int ln = threadIdx.x & 63;
  int i = dstNK[s];
  u8* dst = buf + (size_t)s * Dv;
  if (i >= 0) {
    const float* src = x + (size_t)(i >> 1) * Dv;
    #pragma unroll
    for (int j = 0; j < 4; ++j) {
      int d0 = ln * 16 + j * 4;
      float4 v = *(const float4*)(src + d0);
      *(unsigned*)(dst + d0) = pack4(v, 1.f);
    }
  } else {
    #pragma unroll
    for (int j = 0; j < 4; ++j) *(unsigned*)(dst + ln * 16 + j * 4) = 0u;
  }
}

// ------- batched weight conversion: 128row x 32col tiles, 128B writes -------
#define NSEG 9
struct WTab {
  const float* in[NSEG];
  u8* out[NSEG];
  int R[NSEG], C[NSEG], ldo[NSEG], nxy[NSEG], nx[NSEG];
  int start[NSEG];
};

__global__ __launch_bounds__(256) void wprep_kernel(WTab T) {
  __shared__ float tile[32][132];
  int b = blockIdx.x;
  int s = 0;
  #pragma unroll
  for (int i = 1; i < NSEG; ++i) if (b >= T.start[i]) s = i;
  int rb = b - T.start[s];
  const float* in = T.in[s];
  u8* out = T.out[s];
  int t = threadIdx.x;
  if (T.nx[s] == 0) {
    int i = rb * 256 + t;
    float4 v = *(const float4*)(in + (size_t)i * 4);
    *(unsigned*)(out + (size_t)i * 4) = pack4(v, 16.f);
    return;
  }
  int R = T.R[s], C = T.C[s], ldo = T.ldo[s];
  int z = rb / T.nxy[s], r2 = rb % T.nxy[s];
  int by = r2 / T.nx[s], bx = r2 % T.nx[s];
  in += (size_t)z * R * C;
  out += (size_t)z * (size_t)R * C;   // z>0 only when ldo==R (batched experts)
  int r0 = by * 128, c0 = bx * 32;
  int rr = t >> 3;
  int cc4 = (t & 7) * 4;
  #pragma unroll
  for (int p = 0; p < 4; ++p) {
    int r = rr + p * 32;
    float4 v = *(const float4*)(in + (size_t)(r0 + r) * C + c0 + cc4);
    tile[cc4 + 0][r] = v.x; tile[cc4 + 1][r] = v.y;
    tile[cc4 + 2][r] = v.z; tile[cc4 + 3][r] = v.w;
  }
  __syncthreads();
  int c = t >> 3;
  int rb16 = (t & 7) * 16;
  const float* src = &tile[c][rb16];
  u32x4 w;
  w[0] = cvtpk4(src[0]  * 16.f, src[1]  * 16.f, src[2]  * 16.f, src[3]  * 16.f);
  w[1] = cvtpk4(src[4]  * 16.f, src[5]  * 16.f, src[6]  * 16.f, src[7]  * 16.f);
  w[2] = cvtpk4(src[8]  * 16.f, src[9]  * 16.f, src[10] * 16.f, src[11] * 16.f);
  w[3] = cvtpk4(src[12] * 16.f, src[13] * 16.f, src[14] * 16.f, src[15] * 16.f);
  *(u32x4*)(out + (size_t)(c0 + c) * ldo + r0 + rb16) = w;
}

// ===== 128x128 4-wave MX-fp8 GEMM, BK=128, single-buffer =====
// MODE 1: SwiGLU->fp8 (cnt exit)  2: scatter fp8 (cnt exit)  4: fp8 out
// MODE 5: gelu->fp8 (split-K A)   6: f32 out                 7: fp8 out x16
template<int MODE>
__global__ __launch_bounds__(256, 3) void gemm128f8(
    const u8* __restrict__ A, const u8* __restrict__ A2, int splitK,
    const u8* __restrict__ B, void* __restrict__ C,
    const int* __restrict__ dst, const int* __restrict__ cnt,
    int Ksz, int lda, int ldb, int ldc, int ntm,
    size_t sA, size_t sB, size_t sC, unsigned sclA, unsigned sclB)
{
  __shared__ char smem[32768];
  int e = blockIdx.y;
  int nwgx = gridDim.x, bid0 = blockIdx.x;
  int q = nwgx >> 3, r = nwgx & 7;
  int xcd = bid0 & 7, lo2 = bid0 >> 3;
  int bid = (xcd < r ? xcd * (q + 1) : r * (q + 1) + (xcd - r) * q) + lo2;
  int tm = bid % ntm, tn = bid / ntm;
  if (MODE == 1 || MODE == 2) {
    if (tm * 128 >= cnt[e]) return;
  }
  const u8* Ae = A + (size_t)e * sA;
  const u8* Be = B + (size_t)e * sB;
  long long bdelta = (const char*)A2 - (const char*)Ae;
  int tid = threadIdx.x, wv = tid >> 6, ln = tid & 63;
  int lnl = ln & 15, lnh = ln >> 4;

  const u8* aP[4]; const u8* bP[4];
  unsigned aL[4], bL[4];
  #pragma unroll
  for (int i = 0; i < 4; ++i) {
    int row = i * 32 + wv * 8 + (ln >> 3);
    int c = (ln & 7) ^ (row & 7);
    int cp = ((c & 3) << 1) | (c >> 2);
    aP[i] = Ae + (size_t)(tm * 128 + row) * lda + cp * 16;
    int brow;
    if (MODE == 1) {
      brow = (row < 64) ? (tn * 64 + row) : (Hv + tn * 64 + (row - 64));
    } else {
      brow = tn * 128 + row;
    }
    bP[i] = Be + (size_t)brow * ldb + cp * 16;
    aL[i] = i * 4096 + wv * 1024;
    bL[i] = 16384 + i * 4096 + wv * 1024;
  }

  int arow0 = wv * 32 + lnl;
  int ksw0 = (lnh << 4);
  int ksw1 = 64 + (lnh << 4);

  f32x4 acc[2][8];
  #pragma unroll
  for (int m = 0; m < 2; ++m)
    #pragma unroll
    for (int n = 0; n < 8; ++n) acc[m][n] = (f32x4){0.f, 0.f, 0.f, 0.f};

  for (int k0 = 0; k0 < Ksz; k0 += 128) {
    long long kbA;
    if (MODE == 5 && k0 >= splitK) kbA = bdelta + (long long)(k0 - splitK);
    else kbA = (long long)k0;
    #pragma unroll
    for (int i = 0; i < 4; ++i) gload16(aP[i] + kbA, smem + aL[i]);
    #pragma unroll
    for (int i = 0; i < 4; ++i) gload16(bP[i] + (size_t)k0, smem + bL[i]);
    __syncthreads();

    i32x8 af[2];
    #pragma unroll
    for (int mi = 0; mi < 2; ++mi) {
      int row = arow0 + mi * 16;
      int swz = (row & 7) << 4;
      *(i32x4*)&af[mi] = *(const i32x4*)(smem + row * 128 + (ksw0 ^ swz));
      *((i32x4*)&af[mi] + 1) = *(const i32x4*)(smem + row * 128 + (ksw1 ^ swz));
    }
    #pragma unroll
    for (int n = 0; n < 8; ++n) {
      int row = n * 16 + lnl;
      int swz = (row & 7) << 4;
      i32x8 bf;
      *(i32x4*)&bf = *(const i32x4*)(smem + 16384 + row * 128 + (ksw0 ^ swz));
      *((i32x4*)&bf + 1) = *(const i32x4*)(smem + 16384 + row * 128 + (ksw1 ^ swz));
      acc[0][n] = __builtin_amdgcn_mfma_scale_f32_16x16x128_f8f6f4(
          af[0], bf, acc[0][n], 0, 0, 0, sclA, 0, sclB);
      acc[1][n] = __builtin_amdgcn_mfma_scale_f32_16x16x128_f8f6f4(
          af[1], bf, acc[1][n], 0, 0, 0, sclA, 0, sclB);
    }
    __syncthreads();
  }

  int rbase = tm * 128 + wv * 32 + (lnh << 2);
  if (MODE == 1) {
    u8* Cp = (u8*)C + (size_t)e * sC;
    #pragma unroll
    for (int mi = 0; mi < 2; ++mi)
      #pragma unroll
      for (int n = 0; n < 4; ++n) {
        int col = tn * 64 + n * 16 + lnl;
        #pragma unroll
        for (int v = 0; v < 4; ++v) {
          float g = acc[mi][n][v];
          float u = acc[mi][n + 4][v];
          float sg = g / (1.f + __expf(-g));
          Cp[(size_t)(rbase + mi * 16 + v) * ldc + col] = f2e4h(sg * u);
        }
      }
  } else if (MODE == 2) {
    u8* Cq = (u8*)C;
    #pragma unroll
    for (int mi = 0; mi < 2; ++mi)
      #pragma unroll
      for (int v = 0; v < 4; ++v) {
        int gr = rbase + mi * 16 + v;
        int i = dst[e * CAPv + gr];
        if (i >= 0) {
          #pragma unroll
          for (int n = 0; n < 8; ++n) {
            int col = tn * 128 + n * 16 + lnl;
            Cq[(size_t)i * Dv + col] = f2e4h(acc[mi][n][v]);
          }
        }
      }
  } else if (MODE == 4) {
    u8* Cp = (u8*)C;
    #pragma unroll
    for (int mi = 0; mi < 2; ++mi)
      #pragma unroll
      for (int n = 0; n < 8; ++n) {
        int col = tn * 128 + n * 16 + lnl;
        #pragma unroll
        for (int v = 0; v < 4; ++v)
          Cp[(size_t)(rbase + mi * 16 + v) * ldc + col] = f2e4h(acc[mi][n][v]);
      }
  } else if (MODE == 5) {
    u8* Cp = (u8*)C;
    #pragma unroll
    for (int mi = 0; mi < 2; ++mi)
      #pragma unroll
      for (int n = 0; n < 8; ++n) {
        int col = tn * 128 + n * 16 + lnl;
        #pragma unroll
        for (int v = 0; v < 4; ++v) {
          float xg = acc[mi][n][v];
          float gl = 0.5f * xg * (1.f + erff(xg * 0.70710678118654752f));
          Cp[(size_t)(rbase + mi * 16 + v) * ldc + col] = f2e4h(gl);
        }
      }
  } else if (MODE == 7) {
    u8* Cp = (u8*)C;
    #pragma unroll
    for (int mi = 0; mi < 2; ++mi)
      #pragma unroll
      for (int n = 0; n < 8; ++n) {
        int col = tn * 128 + n * 16 + lnl;
        #pragma unroll
        for (int v = 0; v < 4; ++v)
          Cp[(size_t)(rbase + mi * 16 + v) * ldc + col] = f2e4h(acc[mi][n][v] * 16.f);
      }
  } else {
    float* Cp = (float*)C;
    #pragma unroll
    for (int mi = 0; mi < 2; ++mi)
      #pragma unroll
      for (int n = 0; n < 8; ++n) {
        int col = tn * 128 + n * 16 + lnl;
        #pragma unroll
        for (int v = 0; v < 4; ++v)
          Cp[(size_t)(rbase + mi * 16 + v) * ldc + col] = acc[mi][n][v];
      }
  }
}

// ---------------- scores + masked softmax + Cmsg ----------------
__global__ __launch_bounds__(256) void scores8_kernel(
    const u8* __restrict__ MQ, const u8* __restrict__ SEL8,
    const int* __restrict__ keep, u8* __restrict__ Cmsg)
{
  int wv = threadIdx.x >> 6, ln = threadIdx.x & 63;
  int n = blockIdx.x * 4 + wv;
  const u8* m0 = MQ + (size_t)(2 * n) * 2048;
  const u8* m1 = MQ + (size_t)(2 * n + 1) * 2048;
  const u8* t0 = m0 + 1024;
  const u8* t1 = m1 + 1024;
  const u8* s0p = SEL8 + (size_t)(2 * n) * 1024;
  const u8* s1p = SEL8 + (size_t)(2 * n + 1) * 1024;
  int d0 = ln * 16;
  float a0[16], a1[16], b0[16], b1[16];
  dec16(t0 + d0, a0); dec16(t1 + d0, a1);
  dec16(s0p + d0, b0); dec16(s1p + d0, b1);
  float s00 = 0, s01 = 0, s10 = 0, s11 = 0;
  #pragma unroll
  for (int t = 0; t < 16; ++t) {
    s00 += a0[t] * b0[t]; s01 += a0[t] * b1[t];
    s10 += a1[t] * b0[t]; s11 += a1[t] * b1[t];
  }
  #pragma unroll
  for (int off = 32; off >= 1; off >>= 1) {
    s00 += __shfl_xor(s00, off, 64);
    s01 += __shfl_xor(s01, off, 64);
    s10 += __shfl_xor(s10, off, 64);
    s11 += __shfl_xor(s11, off, 64);
  }
  const float inv = 0.03125f;
  int kp0 = keep[2 * n], kp1 = keep[2 * n + 1];
  float A00, A01, A10, A11;
  {
    float v0 = kp0 ? s00 * inv : -1e9f;
    float v1 = (kp0 && kp1) ? s01 * inv : -1e9f;
    float mx = fmaxf(v0, v1);
    float e0 = expf(v0 - mx), e1 = expf(v1 - mx);
    float den = e0 + e1;
    float a0v = kp0 ? e0 / den : 0.f;
    float a1v = (kp0 && kp1) ? e1 / den : 0.f;
    float s = fmaxf(a0v + a1v, 1e-12f);
    A00 = a0v / s; A01 = a1v / s;
  }
  {
    float v0 = (kp1 && kp0) ? s10 * inv : -1e9f;
    float v1 = kp1 ? s11 * inv : -1e9f;
    float mx = fmaxf(v0, v1);
    float e0 = expf(v0 - mx), e1 = expf(v1 - mx);
    float den = e0 + e1;
    float a0v = (kp1 && kp0) ? e0 / den : 0.f;
    float a1v = kp1 ? e1 / den : 0.f;
    float s = fmaxf(a0v + a1v, 1e-12f);
    A10 = a0v / s; A11 = a1v / s;
  }
  float f0[16], f1[16];
  dec16(m0 + d0, f0); dec16(m1 + d0, f1);
  u8* c0 = Cmsg + (size_t)(2 * n) * 1024 + d0;
  u8* c1 = Cmsg + (size_t)(2 * n + 1) * 1024 + d0;
  #pragma unroll
  for (int j = 0; j < 4; ++j) {
    int t = j * 4;
    *(unsigned*)(c0 + j * 4) = cvtpk4(
        A00 * f0[t] + A01 * f1[t],     A00 * f0[t+1] + A01 * f1[t+1],
        A00 * f0[t+2] + A01 * f1[t+2], A00 * f0[t+3] + A01 * f1[t+3]);
    *(unsigned*)(c1 + j * 4) = cvtpk4(
        A10 * f0[t] + A11 * f1[t],     A10 * f0[t+1] + A11 * f1[t+1],
        A10 * f0[t+2] + A11 * f1[t+2], A10 * f0[t+3] + A11 * f1[t+3]);
  }
}

// ---------------- combine2: FCAT = [sum w_k sel_k | sum w_k gelu_k] fp8 ----------------
__global__ __launch_bounds__(256) void combine2_kernel(
    const u8* __restrict__ sel8, const u8* __restrict__ g8,
    const int* __restrict__ keep, const float* __restrict__ tkprob,
    u8* __restrict__ fcat)
{
  int n = blockIdx.x;
  int t = threadIdx.x;
  float kp0 = keep[2 * n] ? 1.f : 0.f, kp1 = keep[2 * n + 1] ? 1.f : 0.f;
  float p0 = tkprob[2 * n] * kp0, p1 = tkprob[2 * n + 1] * kp1;
  float s = fmaxf(p0 + p1, 1e-12f);
  float w0 = p0 / s, w1 = p1 / s;
  unsigned a = *(const unsigned*)(sel8 + (size_t)(2 * n) * 1024 + t * 4);
  unsigned b = *(const unsigned*)(sel8 + (size_t)(2 * n + 1) * 1024 + t * 4);
  float fa[4], fb[4];
  dec4(a, fa); dec4(b, fb);
  *(unsigned*)(fcat + (size_t)n * 3072 + t * 4) = cvtpk4(
      w0 * fa[0] + w1 * fb[0], w0 * fa[1] + w1 * fb[1],
      w0 * fa[2] + w1 * fb[2], w0 * fa[3] + w1 * fb[3]);
  const u8* ga = g8 + (size_t)(2 * n) * 2048 + t * 8;
  const u8* gb = g8 + (size_t)(2 * n + 1) * 2048 + t * 8;
  #pragma unroll
  for (int h = 0; h < 2; ++h) {
    unsigned xa = *(const unsigned*)(ga + h * 4);
    unsigned xb = *(const unsigned*)(gb + h * 4);
    dec4(xa, fa); dec4(xb, fb);
    *(unsigned*)(fcat + (size_t)n * 3072 + 1024 + t * 8 + h * 4) = cvtpk4(
        w0 * fa[0] + w1 * fb[0], w0 * fa[1] + w1 * fb[1],
        w0 * fa[2] + w1 * fb[2], w0 * fa[3] + w1 * fb[3]);
  }
}

extern "C" void kernel_launch(void* const* d_in, const int* in_sizes, int n_in,
                              void* d_out, int out_size, void* d_ws, size_t ws_size,
                              hipStream_t stream) {
  const float* x      = (const float*)d_in[0];
  const float* gate_w = (const float*)d_in[1];
  const float* w13    = (const float*)d_in[2];
  const float* w2     = (const float*)d_in[3];
  const float* msg_w  = (const float*)d_in[4];
  const float* q_w    = (const float*)d_in[5];
  const float* k_w    = (const float*)d_in[6];
  const float* upd_w1 = (const float*)d_in[7];
  const float* upd_w2 = (const float*)d_in[8];
  const float* o_w    = (const float*)d_in[9];
  float* out = (float*)d_out;
  float* outAux = out + (size_t)Nv * Dv;
  float* outIdx = outAux + 1;

  char* ws = (char*)d_ws;
  const size_t MBc = 1ull << 20;
  int*   tkidx  = (int*)(ws + 0);
  float* tkprob = (float*)(ws + 32768);
  int*   keepA  = (int*)(ws + 65536);
  int*   dstNK  = (int*)(ws + 98304);
  float* red    = (float*)(ws + 143360);
  int*   cntA   = (int*)(ws + 147456);
  u8*  BUF8  = (u8*)(ws + 1 * MBc);
  u8*  ACT8  = (u8*)(ws + 12 * MBc);
  u8*  W13B8 = (u8*)(ws + 41 * MBc);
  u8*  M8s   = (u8*)(ws + 85 * MBc);
  u8*  Q8s   = (u8*)(ws + 86 * MBc);
  u8*  K8T   = (u8*)(ws + 87 * MBc);
  u8*  W2B8r = (u8*)(ws + 88 * MBc);
  u8*  U28s  = (u8*)(ws + 110 * MBc);
  u8*  MTB8  = (u8*)(ws + 112 * MBc);
  u8*  WCAT8 = (u8*)(ws + 114 * MBc);
  u8*  P38   = (u8*)(ws + 117 * MBc);
  u8*  SEL8  = (u8*)(ws + 136 * MBc);
  u8*  UPD1B8= (u8*)(ws + 149 * MBc);
  u8*  FCAT8 = (u8*)(ws + 160 * MBc);
  u8*  MQ8   = (u8*)(ws + 1 * MBc);
  u8*  CMSG8 = (u8*)(ws + 18 * MBc);
  u8*  G1B8  = (u8*)(ws + 27 * MBc);

  hipMemsetAsync(red, 0, 68, stream);
  hipMemsetAsync(dstNK, 0xFF, Ev * CAPv * 4, stream);
  hipMemsetAsync(SEL8, 0, (size_t)NKv * Dv, stream);

  router_kernel<<<Nv / 4, 256, 0, stream>>>(x, gate_w, tkidx, tkprob, red, outIdx);
  rank_kernel<<<1, 256, 0, stream>>>(tkidx, keepA, dstNK, cntA, red, outAux);
  pack8_kernel<<<(Ev * CAPv) / 4, 256, 0, stream>>>(x, dstNK, BUF8);

  WTab T;
  T.in[0]=w13;    T.out[0]=W13B8; T.R[0]=Dv;   T.C[0]=TH2v; T.ldo[0]=Dv;   T.nxy[0]=1408; T.nx[0]=176;
  T.in[1]=w2;     T.out[1]=W2B8r; T.R[1]=Hv;   T.C[1]=Dv;   T.ldo[1]=Hv;   T.nxy[1]=704;  T.nx[1]=32;
  T.in[2]=upd_w1; T.out[2]=UPD1B8;T.R[2]=2048; T.C[2]=2048; T.ldo[2]=2048; T.nxy[2]=1024; T.nx[2]=64;
  T.in[3]=msg_w;  T.out[3]=MTB8;  T.R[3]=Dv;   T.C[3]=Dv;   T.ldo[3]=Dv;   T.nxy[3]=256;  T.nx[3]=32;
  T.in[4]=o_w;    T.out[4]=WCAT8; T.R[4]=Dv;   T.C[4]=Dv;   T.ldo[4]=3072; T.nxy[4]=256;  T.nx[4]=32;
  T.in[5]=k_w;    T.out[5]=K8T;   T.R[5]=Dv;   T.C[5]=Dv;   T.ldo[5]=Dv;   T.nxy[5]=256;  T.nx[5]=32;
  T.in[6]=msg_w;  T.out[6]=M8s;   T.nx[6]=0; T.R[6]=0; T.C[6]=0; T.ldo[6]=0; T.nxy[6]=0;
  T.in[7]=q_w;    T.out[7]=Q8s;   T.nx[7]=0; T.R[7]=0; T.C[7]=0; T.ldo[7]=0; T.nxy[7]=0;
  T.in[8]=upd_w2; T.out[8]=U28s;  T.nx[8]=0; T.R[8]=0; T.C[8]=0; T.ldo[8]=0; T.nxy[8]=0;
  T.start[0]=0; T.start[1]=11264; T.start[2]=16896; T.start[3]=17920;
  T.start[4]=18176; T.start[5]=18432; T.start[6]=18688; T.start[7]=19712; T.start[8]=20736;
  wprep_kernel<<<22784, 256, 0, stream>>>(T);

  // G1: MX-fp8 SwiGLU -> ACT8 (early-exit via cntA)
  gemm128f8<1><<<dim3((CAPv / 128) * (Hv / 64), Ev), 256, 0, stream>>>(
      BUF8, BUF8, 1 << 30, W13B8, (void*)ACT8, nullptr, cntA,
      Dv, Dv, Dv, Hv, CAPv / 128,
      (size_t)CAPv * Dv, (size_t)TH2v * Dv, (size_t)CAPv * Hv, 0x7F7F7F7Fu, 0x7B7B7B7Bu);

  // W_s^T = (msg@k) @ q^T  (MODE 7: fp8 x16 out, no conversion round-trips)
  gemm128f8<7><<<dim3(64, 1), 256, 0, stream>>>(
      M8s, M8s, 1 << 30, K8T, (void*)P38, nullptr, nullptr,
      Dv, Dv, Dv, Dv, 8, 0, 0, 0, 0x7B7B7B7Bu, 0x7B7B7B7Bu);
  gemm128f8<7><<<dim3(64, 1), 256, 0, stream>>>(
      P38, P38, 1 << 30, Q8s, (void*)(MTB8 + (size_t)Dv * Dv), nullptr, nullptr,
      Dv, Dv, Dv, Dv, 8, 0, 0, 0, 0x7B7B7B7Bu, 0x7B7B7B7Bu);
  // T2^T = o_w^T @ upd_w2^T -> WCAT8+1024 (ldc 3072)
  gemm128f8<7><<<dim3(128, 1), 256, 0, stream>>>(
      WCAT8, WCAT8, 1 << 30, U28s, (void*)(WCAT8 + 1024), nullptr, nullptr,
      Dv, 3072, Dv, 3072, 8, 0, 0, 0, 0x7B7B7B7Bu, 0x7B7B7B7Bu);

  // G2: MX-fp8 GEMM + scatter -> SEL8 (early-exit via cntA)
  gemm128f8<2><<<dim3((CAPv / 128) * (Dv / 128), Ev), 256, 0, stream>>>(
      ACT8, ACT8, 1 << 30, W2B8r, (void*)SEL8, dstNK, cntA,
      Hv, Hv, Hv, Dv, CAPv / 128,
      (size_t)CAPv * Hv, (size_t)Dv * Hv, 0, 0x7F7F7F7Fu, 0x7B7B7B7Bu);

  // collaboration: fused [M|T] GEMM, then scores
  gemm128f8<4><<<dim3(64 * 16, 1), 256, 0, stream>>>(
      SEL8, SEL8, 1 << 30, MTB8, (void*)MQ8, nullptr, nullptr,
      Dv, Dv, Dv, 2048, 64, 0, 0, 0, 0x7F7F7F7Fu, 0x7B7B7B7Bu);
  scores8_kernel<<<Nv / 4, 256, 0, stream>>>(MQ8, SEL8, keepA, CMSG8);

  // update MLP: gelu([SEL8|CMSG8] @ upd_w1) -> G1B8
  gemm128f8<5><<<dim3(64 * 16, 1), 256, 0, stream>>>(
      SEL8, CMSG8, Dv, UPD1B8, (void*)G1B8, nullptr, nullptr,
      2048, Dv, 2048, 2048, 64, 0, 0, 0, 0x7F7F7F7Fu, 0x7B7B7B7Bu);

  // FCAT = [sum w sel | sum w gelu], final fused GEMM -> out (f32)
  combine2_kernel<<<Nv, 256, 0, stream>>>(SEL8, G1B8, keepA, tkprob, FCAT8);
  gemm128f8<6><<<dim3(32 * 8, 1), 256, 0, stream>>>(
      FCAT8, FCAT8, 1 << 30, WCAT8, (void*)out, nullptr, nullptr,
      3072, 3072, 3072, Dv, 32, 0, 0, 0, 0x7F7F7F7Fu, 0x7B7B7B7Bu);

  (void)in_sizes; (void)n_in; (void)out_size; (void)ws_size;
}

// Round 15
// 404.735 us; speedup vs baseline: 1.6623x; 1.0121x over previous
//
#include <hip/hip_runtime.h>
#include <math.h>

#define Dv 1024
#define Ev 8
#define Hv 2816
#define Nv 4096
#define NKv 8192
#define CAPv 1280
#define TH2v 5632

typedef unsigned short u16;
typedef unsigned char u8;
typedef __attribute__((ext_vector_type(4))) float f32x4;
typedef __attribute__((ext_vector_type(4))) int i32x4;
typedef __attribute__((ext_vector_type(8))) int i32x8;
typedef __attribute__((ext_vector_type(4))) unsigned u32x4;

typedef const __attribute__((address_space(1))) void* as1_cvp;
typedef __attribute__((address_space(3))) void* as3_vp;

// f32 -> OCP e4m3fn, RNE, saturate to 448 (software fallback)
__device__ __forceinline__ unsigned f2e4(float f) {
  unsigned u = __float_as_uint(f);
  unsigned sgn = (u >> 24) & 0x80u;
  unsigned ax = u & 0x7FFFFFFFu;
  if (ax >= 0x43E00000u) return sgn | 0x7Eu;
  if (ax < 0x3C800000u) {
    int qv = (int)rintf(__uint_as_float(ax) * 512.f);
    return sgn | (unsigned)qv;
  }
  unsigned lsb = (ax >> 20) & 1u;
  unsigned rr = ax + 0x0007FFFFu + lsb;
  unsigned ee = rr >> 23;
  unsigned mm = (rr >> 20) & 7u;
  if (ee > 135u) return sgn | 0x7Eu;
  return sgn | ((ee - 120u) << 3) | mm;
}
// e4m3fn -> f32 (software fallback)
__device__ __forceinline__ float e42f(unsigned v) {
  unsigned s = (v & 0x80u) << 24, e = (v >> 3) & 15u, m = v & 7u;
  if (e) return __uint_as_float(s | ((e + 120u) << 23) | (m << 20));
  return __uint_as_float(__float_as_uint((float)m * 0.001953125f) | s);
}

// packed converters (HW when available)
__device__ __forceinline__ unsigned cvtpk4(float a, float b, float c, float d) {
#if __has_builtin(__builtin_amdgcn_cvt_pk_fp8_f32)
  int w = __builtin_amdgcn_cvt_pk_fp8_f32(a, b, 0, false);
  w = __builtin_amdgcn_cvt_pk_fp8_f32(c, d, w, true);
  return (unsigned)w;
#else
  return f2e4(a) | (f2e4(b) << 8) | (f2e4(c) << 16) | (f2e4(d) << 24);
#endif
}
__device__ __forceinline__ u8 f2e4h(float a) {
#if __has_builtin(__builtin_amdgcn_cvt_pk_fp8_f32)
  return (u8)(__builtin_amdgcn_cvt_pk_fp8_f32(a, a, 0, false) & 0xffu);
#else
  return (u8)f2e4(a);
#endif
}
__device__ __forceinline__ void dec16(const u8* p, float* o) {
  const unsigned* w = (const unsigned*)p;
#if __has_builtin(__builtin_amdgcn_cvt_pk_f32_fp8)
  #pragma unroll
  for (int j = 0; j < 4; ++j) {
    int x = (int)w[j];
    auto lo = __builtin_amdgcn_cvt_pk_f32_fp8(x, false);
    auto hi = __builtin_amdgcn_cvt_pk_f32_fp8(x, true);
    o[j*4+0] = lo[0]; o[j*4+1] = lo[1]; o[j*4+2] = hi[0]; o[j*4+3] = hi[1];
  }
#else
  #pragma unroll
  for (int j = 0; j < 4; ++j) {
    unsigned x = w[j];
    o[j*4+0] = e42f(x & 255u);
    o[j*4+1] = e42f((x >> 8) & 255u);
    o[j*4+2] = e42f((x >> 16) & 255u);
    o[j*4+3] = e42f((x >> 24) & 255u);
  }
#endif
}
__device__ __forceinline__ void dec4(unsigned x, float* o) {
#if __has_builtin(__builtin_amdgcn_cvt_pk_f32_fp8)
  auto lo = __builtin_amdgcn_cvt_pk_f32_fp8((int)x, false);
  auto hi = __builtin_amdgcn_cvt_pk_f32_fp8((int)x, true);
  o[0] = lo[0]; o[1] = lo[1]; o[2] = hi[0]; o[3] = hi[1];
#else
  o[0] = e42f(x & 255u); o[1] = e42f((x >> 8) & 255u);
  o[2] = e42f((x >> 16) & 255u); o[3] = e42f((x >> 24) & 255u);
#endif
}
__device__ __forceinline__ unsigned pack4(float4 v, float s) {
  return cvtpk4(v.x * s, v.y * s, v.z * s, v.w * s);
}
__device__ __forceinline__ void gload16(const void* g, void* l) {
  __builtin_amdgcn_global_load_lds((as1_cvp)g, (as3_vp)l, 16, 0, 0);
}

// ---------------- router ----------------
__global__ __launch_bounds__(256) void router_kernel(
    const float* __restrict__ x, const float* __restrict__ gw,
    int* __restrict__ tkidx, float* __restrict__ tkprob,
    float* __restrict__ red, float* __restrict__ outIdx)
{
  __shared__ float lred[17];
  int tid = threadIdx.x;
  if (tid < 17) lred[tid] = 0.f;
  __syncthreads();
  int wv = tid >> 6, ln = tid & 63;
  int n = blockIdx.x * 4 + wv;
  float a[8] = {0.f,0.f,0.f,0.f,0.f,0.f,0.f,0.f};
  const float* xr = x + (size_t)n * Dv;
  #pragma unroll
  for (int it = 0; it < 16; ++it) {
    int d = ln + it * 64;
    float xs = xr[d];
    float4 g0 = *(const float4*)(gw + (size_t)d * 8);
    float4 g1 = *(const float4*)(gw + (size_t)d * 8 + 4);
    a[0] += xs * g0.x; a[1] += xs * g0.y; a[2] += xs * g0.z; a[3] += xs * g0.w;
    a[4] += xs * g1.x; a[5] += xs * g1.y; a[6] += xs * g1.z; a[7] += xs * g1.w;
  }
  #pragma unroll
  for (int off = 32; off >= 1; off >>= 1) {
    #pragma unroll
    for (int e = 0; e < 8; ++e) a[e] += __shfl_xor(a[e], off, 64);
  }
  int i1 = 0; float v1 = a[0];
  #pragma unroll
  for (int e = 1; e < 8; ++e) if (a[e] > v1) { v1 = a[e]; i1 = e; }
  int i2 = -1; float v2 = -1e30f;
  #pragma unroll
  for (int e = 0; e < 8; ++e) if (e != i1 && a[e] > v2) { v2 = a[e]; i2 = e; }
  float Z = 0.f;
  #pragma unroll
  for (int e = 0; e < 8; ++e) Z += expf(a[e] - v1);
  float zlse = v1 + logf(Z);
  float t = expf(v2 - v1);
  float p1 = 1.f / (1.f + t);
  float p2 = t * p1;
  if (ln == 0) {
    tkidx[2*n] = i1; tkidx[2*n+1] = i2;
    tkprob[2*n] = p1; tkprob[2*n+1] = p2;
    outIdx[2*n] = (float)i1; outIdx[2*n+1] = (float)i2;
    #pragma unroll
    for (int e = 0; e < 8; ++e) atomicAdd(&lred[e], expf(a[e] - v1) / Z);
    atomicAdd(&lred[8 + i1], 1.f);
    atomicAdd(&lred[16], zlse * zlse);
  }
  __syncthreads();
  if (tid < 17) atomicAdd(&red[tid], lred[tid]);
}

// ---------------- exact stable rank + counts + aux ----------------
__global__ __launch_bounds__(256) void rank_kernel(const int* __restrict__ tgt,
    int* __restrict__ keep, int* __restrict__ dstNK, int* __restrict__ cnt,
    const float* __restrict__ red, float* __restrict__ outAux)
{
  __shared__ int hist[256][8];
  int t = threadIdx.x;
  int h[8] = {0,0,0,0,0,0,0,0};
  int base = t * 32;
  for (int j = 0; j < 32; ++j) h[tgt[base + j]]++;
  for (int e = 0; e < 8; ++e) hist[t][e] = h[e];
  __syncthreads();
  if (t < 8) {
    int run = 0;
    for (int tt = 0; tt < 256; ++tt) { int v = hist[tt][t]; hist[tt][t] = run; run += v; }
    cnt[t] = run < CAPv ? run : CAPv;
  }
  if (t == 0) {
    float bl = 0.f;
    for (int e = 0; e < 8; ++e) bl += (red[e] / (float)Nv) * (red[8 + e] / (float)Nv);
    bl *= (float)Ev;
    outAux[0] = 0.01f * bl + 0.001f * (red[16] / (float)Nv);
  }
  __syncthreads();
  for (int e = 0; e < 8; ++e) h[e] = hist[t][e];
  for (int j = 0; j < 32; ++j) {
    int i = base + j; int e = tgt[i]; int r = h[e]++;
    int kp = (r < CAPv) ? 1 : 0;
    keep[i] = kp;
    if (kp) dstNK[e * CAPv + r] = i;
  }
}

// ---------------- pack tokens -> fp8 ----------------
__global__ __launch_bounds__(256) void pack8_kernel(const float* __restrict__ x,
    const int* __restrict__ dstNK, u8* __restrict__ buf)
{
  int s = blockIdx.x * 4 + (threadIdx.x >> 6);
  int ln = threadIdx.x & 63;
  int i = dstNK[s];
  u8* dst = buf + (size_t)s * Dv;
  if (i >= 0) {
    const float* src = x + (size_t)(i >> 1) * Dv;
    #pragma unroll
    for (int j = 0; j < 4; ++j) {
      int d0 = ln * 16 + j * 4;
      float4 v = *(const float4*)(src + d0);
      *(unsigned*)(dst + d0) = pack4(v, 1.f);
    }
  } else {
    #pragma unroll
    for (int j = 0; j < 4; ++j) *(unsigned*)(dst + ln * 16 + j * 4) = 0u;
  }
}

// ------- batched weight conversion: 128x128 tiles, 512B reads / 128B writes -------
#define NSEG 9
struct WTab {
  const float* in[NSEG];
  u8* out[NSEG];
  int R[NSEG], C[NSEG], ldo[NSEG], nxy[NSEG], nx[NSEG];
  int start[NSEG];
};

__global__ __launch_bounds__(256) void wprep_kernel(WTab T) {
  __shared__ u8 tile[128][132];
  int b = blockIdx.x;
  int s = 0;
  #pragma unroll
  for (int i = 1; i < NSEG; ++i) if (b >= T.start[i]) s = i;
  int rb = b - T.start[s];
  const float* in = T.in[s];
  u8* out = T.out[s];
  int t = threadIdx.x;
  if (T.nx[s] == 0) {
    int i = rb * 256 + t;
    float4 v = *(const float4*)(in + (size_t)i * 4);
    *(unsigned*)(out + (size_t)i * 4) = pack4(v, 16.f);
    return;
  }
  int R = T.R[s], C = T.C[s], ldo = T.ldo[s];
  int z = rb / T.nxy[s], r2 = rb % T.nxy[s];
  int by = r2 / T.nx[s], bx = r2 % T.nx[s];
  in += (size_t)z * R * C;
  out += (size_t)z * (size_t)R * C;   // z>0 only when ldo==R (batched experts)
  int r0 = by * 128, c0 = bx * 128;
  int rr = t >> 5;           // 0..7
  int cc4 = (t & 31) * 4;    // 0..124, 512B/row across 32 threads
  #pragma unroll
  for (int p = 0; p < 16; ++p) {
    int r = rr + p * 8;
    float4 v = *(const float4*)(in + (size_t)(r0 + r) * C + c0 + cc4);
    *(unsigned*)(&tile[r][cc4]) = pack4(v, 16.f);   // convert on load side
  }
  __syncthreads();
  int c = t >> 1;            // 0..127
  int rh = (t & 1) * 64;     // 0 or 64: 2 threads cover a 128B column chunk
  u8* op = out + (size_t)(c0 + c) * ldo + r0 + rh;
  #pragma unroll
  for (int q8 = 0; q8 < 4; ++q8) {
    u32x4 w;
    #pragma unroll
    for (int j = 0; j < 4; ++j) {
      int r = rh + q8 * 16 + j * 4;
      w[j] = (unsigned)tile[r][c] | ((unsigned)tile[r+1][c] << 8)
           | ((unsigned)tile[r+2][c] << 16) | ((unsigned)tile[r+3][c] << 24);
    }
    *(u32x4*)(op + q8 * 16) = w;
  }
}

// ===== 128x128 4-wave MX-fp8 GEMM, BK=128, single-buffer =====
// MODE 1: SwiGLU->fp8 (cnt exit)  2: scatter fp8 (cnt exit)  4: fp8 out
// MODE 5: gelu->fp8 (split-K A)   6: f32 out                 7: fp8 out x16
template<int MODE>
__global__ __launch_bounds__(256, 3) void gemm128f8(
    const u8* __restrict__ A, const u8* __restrict__ A2, int splitK,
    const u8* __restrict__ B, void* __restrict__ C,
    const int* __restrict__ dst, const int* __restrict__ cnt,
    int Ksz, int lda, int ldb, int ldc, int ntm,
    size_t sA, size_t sB, size_t sC, unsigned sclA, unsigned sclB)
{
  __shared__ char smem[32768];
  int e = blockIdx.y;
  int nwgx = gridDim.x, bid0 = blockIdx.x;
  int q = nwgx >> 3, r = nwgx & 7;
  int xcd = bid0 & 7, lo2 = bid0 >> 3;
  int bid = (xcd < r ? xcd * (q + 1) : r * (q + 1) + (xcd - r) * q) + lo2;
  int tm = bid % ntm, tn = bid / ntm;
  if (MODE == 1 || MODE == 2) {
    if (tm * 128 >= cnt[e]) return;
  }
  const u8* Ae = A + (size_t)e * sA;
  const u8* Be = B + (size_t)e * sB;
  long long bdelta = (const char*)A2 - (const char*)Ae;
  int tid = threadIdx.x, wv = tid >> 6, ln = tid & 63;
  int lnl = ln & 15, lnh = ln >> 4;

  const u8* aP[4]; const u8* bP[4];
  unsigned aL[4], bL[4];
  #pragma unroll
  for (int i = 0; i < 4; ++i) {
    int row = i * 32 + wv * 8 + (ln >> 3);
    int c = (ln & 7) ^ (row & 7);
    int cp = ((c & 3) << 1) | (c >> 2);
    aP[i] = Ae + (size_t)(tm * 128 + row) * lda + cp * 16;
    int brow;
    if (MODE == 1) {
      brow = (row < 64) ? (tn * 64 + row) : (Hv + tn * 64 + (row - 64));
    } else {
      brow = tn * 128 + row;
    }
    bP[i] = Be + (size_t)brow * ldb + cp * 16;
    aL[i] = i * 4096 + wv * 1024;
    bL[i] = 16384 + i * 4096 + wv * 1024;
  }

  int arow0 = wv * 32 + lnl;
  int ksw0 = (lnh << 4);
  int ksw1 = 64 + (lnh << 4);

  f32x4 acc[2][8];
  #pragma unroll
  for (int m = 0; m < 2; ++m)
    #pragma unroll
    for (int n = 0; n < 8; ++n) acc[m][n] = (f32x4){0.f, 0.f, 0.f, 0.f};

  for (int k0 = 0; k0 < Ksz; k0 += 128) {
    long long kbA;
    if (MODE == 5 && k0 >= splitK) kbA = bdelta + (long long)(k0 - splitK);
    else kbA = (long long)k0;
    #pragma unroll
    for (int i = 0; i < 4; ++i) gload16(aP[i] + kbA, smem + aL[i]);
    #pragma unroll
    for (int i = 0; i < 4; ++i) gload16(bP[i] + (size_t)k0, smem + bL[i]);
    __syncthreads();

    i32x8 af[2];
    #pragma unroll
    for (int mi = 0; mi < 2; ++mi) {
      int row = arow0 + mi * 16;
      int swz = (row & 7) << 4;
      *(i32x4*)&af[mi] = *(const i32x4*)(smem + row * 128 + (ksw0 ^ swz));
      *((i32x4*)&af[mi] + 1) = *(const i32x4*)(smem + row * 128 + (ksw1 ^ swz));
    }
    #pragma unroll
    for (int n = 0; n < 8; ++n) {
      int row = n * 16 + lnl;
      int swz = (row & 7) << 4;
      i32x8 bf;
      *(i32x4*)&bf = *(const i32x4*)(smem + 16384 + row * 128 + (ksw0 ^ swz));
      *((i32x4*)&bf + 1) = *(const i32x4*)(smem + 16384 + row * 128 + (ksw1 ^ swz));
      acc[0][n] = __builtin_amdgcn_mfma_scale_f32_16x16x128_f8f6f4(
          af[0], bf, acc[0][n], 0, 0, 0, sclA, 0, sclB);
      acc[1][n] = __builtin_amdgcn_mfma_scale_f32_16x16x128_f8f6f4(
          af[1], bf, acc[1][n], 0, 0, 0, sclA, 0, sclB);
    }
    __syncthreads();
  }

  int rbase = tm * 128 + wv * 32 + (lnh << 2);
  if (MODE == 1) {
    u8* Cp = (u8*)C + (size_t)e * sC;
    #pragma unroll
    for (int mi = 0; mi < 2; ++mi)
      #pragma unroll
      for (int n = 0; n < 4; ++n) {
        int col = tn * 64 + n * 16 + lnl;
        #pragma unroll
        for (int v = 0; v < 4; ++v) {
          float g = acc[mi][n][v];
          float u = acc[mi][n + 4][v];
          float sg = g / (1.f + __expf(-g));
          Cp[(size_t)(rbase + mi * 16 + v) * ldc + col] = f2e4h(sg * u);
        }
      }
  } else if (MODE == 2) {
    u8* Cq = (u8*)C;
    #pragma unroll
    for (int mi = 0; mi < 2; ++mi)
      #pragma unroll
      for (int v = 0; v < 4; ++v) {
        int gr = rbase + mi * 16 + v;
        int i = dst[e * CAPv + gr];
        if (i >= 0) {
          #pragma unroll
          for (int n = 0; n < 8; ++n) {
            int col = tn * 128 + n * 16 + lnl;
            Cq[(size_t)i * Dv + col] = f2e4h(acc[mi][n][v]);
          }
        }
      }
  } else if (MODE == 4) {
    u8* Cp = (u8*)C;
    #pragma unroll
    for (int mi = 0; mi < 2; ++mi)
      #pragma unroll
      for (int n = 0; n < 8; ++n) {
        int col = tn * 128 + n * 16 + lnl;
        #pragma unroll
        for (int v = 0; v < 4; ++v)
          Cp[(size_t)(rbase + mi * 16 + v) * ldc + col] = f2e4h(acc[mi][n][v]);
      }
  } else if (MODE == 5) {
    u8* Cp = (u8*)C;
    #pragma unroll
    for (int mi = 0; mi < 2; ++mi)
      #pragma unroll
      for (int n = 0; n < 8; ++n) {
        int col = tn * 128 + n * 16 + lnl;
        #pragma unroll
        for (int v = 0; v < 4; ++v) {
          float xg = acc[mi][n][v];
          float gl = 0.5f * xg * (1.f + erff(xg * 0.70710678118654752f));
          Cp[(size_t)(rbase + mi * 16 + v) * ldc + col] = f2e4h(gl);
        }
      }
  } else if (MODE == 7) {
    u8* Cp = (u8*)C;
    #pragma unroll
    for (int mi = 0; mi < 2; ++mi)
      #pragma unroll
      for (int n = 0; n < 8; ++n) {
        int col = tn * 128 + n * 16 + lnl;
        #pragma unroll
        for (int v = 0; v < 4; ++v)
          Cp[(size_t)(rbase + mi * 16 + v) * ldc + col] = f2e4h(acc[mi][n][v] * 16.f);
      }
  } else {
    float* Cp = (float*)C;
    #pragma unroll
    for (int mi = 0; mi < 2; ++mi)
      #pragma unroll
      for (int n = 0; n < 8; ++n) {
        int col = tn * 128 + n * 16 + lnl;
        #pragma unroll
        for (int v = 0; v < 4; ++v)
          Cp[(size_t)(rbase + mi * 16 + v) * ldc + col] = acc[mi][n][v];
      }
  }
}

// ---------------- scores + masked softmax + Cmsg ----------------
__global__ __launch_bounds__(256) void scores8_kernel(
    const u8* __restrict__ MQ, const u8* __restrict__ SEL8,
    const int* __restrict__ keep, u8* __restrict__ Cmsg)
{
  int wv = threadIdx.x >> 6, ln = threadIdx.x & 63;
  int n = blockIdx.x * 4 + wv;
  const u8* m0 = MQ + (size_t)(2 * n) * 2048;
  const u8* m1 = MQ + (size_t)(2 * n + 1) * 2048;
  const u8* t0 = m0 + 1024;
  const u8* t1 = m1 + 1024;
  const u8* s0p = SEL8 + (size_t)(2 * n) * 1024;
  const u8* s1p = SEL8 + (size_t)(2 * n + 1) * 1024;
  int d0 = ln * 16;
  float a0[16], a1[16], b0[16], b1[16];
  dec16(t0 + d0, a0); dec16(t1 + d0, a1);
  dec16(s0p + d0, b0); dec16(s1p + d0, b1);
  float s00 = 0, s01 = 0, s10 = 0, s11 = 0;
  #pragma unroll
  for (int t = 0; t < 16; ++t) {
    s00 += a0[t] * b0[t]; s01 += a0[t] * b1[t];
    s10 += a1[t] * b0[t]; s11 += a1[t] * b1[t];
  }
  #pragma unroll
  for (int off = 32; off >= 1; off >>= 1) {
    s00 += __shfl_xor(s00, off, 64);
    s01 += __shfl_xor(s01, off, 64);
    s10 += __shfl_xor(s10, off, 64);
    s11 += __shfl_xor(s11, off, 64);
  }
  const float inv = 0.03125f;
  int kp0 = keep[2 * n], kp1 = keep[2 * n + 1];
  float A00, A01, A10, A11;
  {
    float v0 = kp0 ? s00 * inv : -1e9f;
    float v1 = (kp0 && kp1) ? s01 * inv : -1e9f;
    float mx = fmaxf(v0, v1);
    float e0 = expf(v0 - mx), e1 = expf(v1 - mx);
    float den = e0 + e1;
    float a0v = kp0 ? e0 / den : 0.f;
    float a1v = (kp0 && kp1) ? e1 / den : 0.f;
    float s = fmaxf(a0v + a1v, 1e-12f);
    A00 = a0v / s; A01 = a1v / s;
  }
  {
    float v0 = (kp1 && kp0) ? s10 * inv : -1e9f;
    float v1 = kp1 ? s11 * inv : -1e9f;
    float mx = fmaxf(v0, v1);
    float e0 = expf(v0 - mx), e1 = expf(v1 - mx);
    float den = e0 + e1;
    float a0v = (kp1 && kp0) ? e0 / den : 0.f;
    float a1v = kp1 ? e1 / den : 0.f;
    float s = fmaxf(a0v + a1v, 1e-12f);
    A10 = a0v / s; A11 = a1v / s;
  }
  float f0[16], f1[16];
  dec16(m0 + d0, f0); dec16(m1 + d0, f1);
  u8* c0 = Cmsg + (size_t)(2 * n) * 1024 + d0;
  u8* c1 = Cmsg + (size_t)(2 * n + 1) * 1024 + d0;
  #pragma unroll
  for (int j = 0; j < 4; ++j) {
    int t = j * 4;
    *(unsigned*)(c0 + j * 4) = cvtpk4(
        A00 * f0[t] + A01 * f1[t],     A00 * f0[t+1] + A01 * f1[t+1],
        A00 * f0[t+2] + A01 * f1[t+2], A00 * f0[t+3] + A01 * f1[t+3]);
    *(unsigned*)(c1 + j * 4) = cvtpk4(
        A10 * f0[t] + A11 * f1[t],     A10 * f0[t+1] + A11 * f1[t+1],
        A10 * f0[t+2] + A11 * f1[t+2], A10 * f0[t+3] + A11 * f1[t+3]);
  }
}

// ---------------- combine2: FCAT = [sum w_k sel_k | sum w_k gelu_k] fp8 ----------------
__global__ __launch_bounds__(256) void combine2_kernel(
    const u8* __restrict__ sel8, const u8* __restrict__ g8,
    const int* __restrict__ keep, const float* __restrict__ tkprob,
    u8* __restrict__ fcat)
{
  int n = blockIdx.x;
  int t = threadIdx.x;
  float kp0 = keep[2 * n] ? 1.f : 0.f, kp1 = keep[2 * n + 1] ? 1.f : 0.f;
  float p0 = tkprob[2 * n] * kp0, p1 = tkprob[2 * n + 1] * kp1;
  float s = fmaxf(p0 + p1, 1e-12f);
  float w0 = p0 / s, w1 = p1 / s;
  unsigned a = *(const unsigned*)(sel8 + (size_t)(2 * n) * 1024 + t * 4);
  unsigned b = *(const unsigned*)(sel8 + (size_t)(2 * n + 1) * 1024 + t * 4);
  float fa[4], fb[4];
  dec4(a, fa); dec4(b, fb);
  *(unsigned*)(fcat + (size_t)n * 3072 + t * 4) = cvtpk4(
      w0 * fa[0] + w1 * fb[0], w0 * fa[1] + w1 * fb[1],
      w0 * fa[2] + w1 * fb[2], w0 * fa[3] + w1 * fb[3]);
  const u8* ga = g8 + (size_t)(2 * n) * 2048 + t * 8;
  const u8* gb = g8 + (size_t)(2 * n + 1) * 2048 + t * 8;
  #pragma unroll
  for (int h = 0; h < 2; ++h) {
    unsigned xa = *(const unsigned*)(ga + h * 4);
    unsigned xb = *(const unsigned*)(gb + h * 4);
    dec4(xa, fa); dec4(xb, fb);
    *(unsigned*)(fcat + (size_t)n * 3072 + 1024 + t * 8 + h * 4) = cvtpk4(
        w0 * fa[0] + w1 * fb[0], w0 * fa[1] + w1 * fb[1],
        w0 * fa[2] + w1 * fb[2], w0 * fa[3] + w1 * fb[3]);
  }
}

extern "C" void kernel_launch(void* const* d_in, const int* in_sizes, int n_in,
                              void* d_out, int out_size, void* d_ws, size_t ws_size,
                              hipStream_t stream) {
  const float* x      = (const float*)d_in[0];
  const float* gate_w = (const float*)d_in[1];
  const float* w13    = (const float*)d_in[2];
  const float* w2     = (const float*)d_in[3];
  const float* msg_w  = (const float*)d_in[4];
  const float* q_w    = (const float*)d_in[5];
  const float* k_w    = (const float*)d_in[6];
  const float* upd_w1 = (const float*)d_in[7];
  const float* upd_w2 = (const float*)d_in[8];
  const float* o_w    = (const float*)d_in[9];
  float* out = (float*)d_out;
  float* outAux = out + (size_t)Nv * Dv;
  float* outIdx = outAux + 1;

  char* ws = (char*)d_ws;
  const size_t MBc = 1ull << 20;
  int*   tkidx  = (int*)(ws + 0);
  float* tkprob = (float*)(ws + 32768);
  int*   keepA  = (int*)(ws + 65536);
  int*   dstNK  = (int*)(ws + 98304);
  float* red    = (float*)(ws + 143360);
  int*   cntA   = (int*)(ws + 147456);
  u8*  BUF8  = (u8*)(ws + 1 * MBc);
  u8*  ACT8  = (u8*)(ws + 12 * MBc);
  u8*  W13B8 = (u8*)(ws + 41 * MBc);
  u8*  M8s   = (u8*)(ws + 85 * MBc);
  u8*  Q8s   = (u8*)(ws + 86 * MBc);
  u8*  K8T   = (u8*)(ws + 87 * MBc);
  u8*  W2B8r = (u8*)(ws + 88 * MBc);
  u8*  U28s  = (u8*)(ws + 110 * MBc);
  u8*  MTB8  = (u8*)(ws + 112 * MBc);
  u8*  WCAT8 = (u8*)(ws + 114 * MBc);
  u8*  P38   = (u8*)(ws + 117 * MBc);
  u8*  SEL8  = (u8*)(ws + 136 * MBc);
  u8*  UPD1B8= (u8*)(ws + 149 * MBc);
  u8*  FCAT8 = (u8*)(ws + 160 * MBc);
  u8*  MQ8   = (u8*)(ws + 1 * MBc);
  u8*  CMSG8 = (u8*)(ws + 18 * MBc);
  u8*  G1B8  = (u8*)(ws + 27 * MBc);

  hipMemsetAsync(red, 0, 68, stream);
  hipMemsetAsync(dstNK, 0xFF, Ev * CAPv * 4, stream);
  hipMemsetAsync(SEL8, 0, (size_t)NKv * Dv, stream);

  router_kernel<<<Nv / 4, 256, 0, stream>>>(x, gate_w, tkidx, tkprob, red, outIdx);
  rank_kernel<<<1, 256, 0, stream>>>(tkidx, keepA, dstNK, cntA, red, outAux);
  pack8_kernel<<<(Ev * CAPv) / 4, 256, 0, stream>>>(x, dstNK, BUF8);

  WTab T;
  T.in[0]=w13;    T.out[0]=W13B8; T.R[0]=Dv;   T.C[0]=TH2v; T.ldo[0]=Dv;   T.nxy[0]=352; T.nx[0]=44;
  T.in[1]=w2;     T.out[1]=W2B8r; T.R[1]=Hv;   T.C[1]=Dv;   T.ldo[1]=Hv;   T.nxy[1]=176; T.nx[1]=8;
  T.in[2]=upd_w1; T.out[2]=UPD1B8;T.R[2]=2048; T.C[2]=2048; T.ldo[2]=2048; T.nxy[2]=256; T.nx[2]=16;
  T.in[3]=msg_w;  T.out[3]=MTB8;  T.R[3]=Dv;   T.C[3]=Dv;   T.ldo[3]=Dv;   T.nxy[3]=64;  T.nx[3]=8;
  T.in[4]=o_w;    T.out[4]=WCAT8; T.R[4]=Dv;   T.C[4]=Dv;   T.ldo[4]=3072; T.nxy[4]=64;  T.nx[4]=8;
  T.in[5]=k_w;    T.out[5]=K8T;   T.R[5]=Dv;   T.C[5]=Dv;   T.ldo[5]=Dv;   T.nxy[5]=64;  T.nx[5]=8;
  T.in[6]=msg_w;  T.out[6]=M8s;   T.nx[6]=0; T.R[6]=0; T.C[6]=0; T.ldo[6]=0; T.nxy[6]=0;
  T.in[7]=q_w;    T.out[7]=Q8s;   T.nx[7]=0; T.R[7]=0; T.C[7]=0; T.ldo[7]=0; T.nxy[7]=0;
  T.in[8]=upd_w2; T.out[8]=U28s;  T.nx[8]=0; T.R[8]=0; T.C[8]=0; T.ldo[8]=0; T.nxy[8]=0;
  T.start[0]=0; T.start[1]=2816; T.start[2]=4224; T.start[3]=4480;
  T.start[4]=4544; T.start[5]=4608; T.start[6]=4672; T.start[7]=5696; T.start[8]=6720;
  wprep_kernel<<<8768, 256, 0, stream>>>(T);

  // G1: MX-fp8 SwiGLU -> ACT8 (early-exit via cntA)
  gemm128f8<1><<<dim3((CAPv / 128) * (Hv / 64), Ev), 256, 0, stream>>>(
      BUF8, BUF8, 1 << 30, W13B8, (void*)ACT8, nullptr, cntA,
      Dv, Dv, Dv, Hv, CAPv / 128,
      (size_t)CAPv * Dv, (size_t)TH2v * Dv, (size_t)CAPv * Hv, 0x7F7F7F7Fu, 0x7B7B7B7Bu);

  // W_s^T = (msg@k) @ q^T  (MODE 7: fp8 x16 out, no conversion round-trips)
  gemm128f8<7><<<dim3(64, 1), 256, 0, stream>>>(
      M8s, M8s, 1 << 30, K8T, (void*)P38, nullptr, nullptr,
      Dv, Dv, Dv, Dv, 8, 0, 0, 0, 0x7B7B7B7Bu, 0x7B7B7B7Bu);
  gemm128f8<7><<<dim3(64, 1), 256, 0, stream>>>(
      P38, P38, 1 << 30, Q8s, (void*)(MTB8 + (size_t)Dv * Dv), nullptr, nullptr,
      Dv, Dv, Dv, Dv, 8, 0, 0, 0, 0x7B7B7B7Bu, 0x7B7B7B7Bu);
  // T2^T = o_w^T @ upd_w2^T -> WCAT8+1024 (ldc 3072)
  gemm128f8<7><<<dim3(128, 1), 256, 0, stream>>>(
      WCAT8, WCAT8, 1 << 30, U28s, (void*)(WCAT8 + 1024), nullptr, nullptr,
      Dv, 3072, Dv, 3072, 8, 0, 0, 0, 0x7B7B7B7Bu, 0x7B7B7B7Bu);

  // G2: MX-fp8 GEMM + scatter -> SEL8 (early-exit via cntA)
  gemm128f8<2><<<dim3((CAPv / 128) * (Dv / 128), Ev), 256, 0, stream>>>(
      ACT8, ACT8, 1 << 30, W2B8r, (void*)SEL8, dstNK, cntA,
      Hv, Hv, Hv, Dv, CAPv / 128,
      (size_t)CAPv * Hv, (size_t)Dv * Hv, 0, 0x7F7F7F7Fu, 0x7B7B7B7Bu);

  // collaboration: fused [M|T] GEMM, then scores
  gemm128f8<4><<<dim3(64 * 16, 1), 256, 0, stream>>>(
      SEL8, SEL8, 1 << 30, MTB8, (void*)MQ8, nullptr, nullptr,
      Dv, Dv, Dv, 2048, 64, 0, 0, 0, 0x7F7F7F7Fu, 0x7B7B7B7Bu);
  scores8_kernel<<<Nv / 4, 256, 0, stream>>>(MQ8, SEL8, keepA, CMSG8);

  // update MLP: gelu([SEL8|CMSG8] @ upd_w1) -> G1B8
  gemm128f8<5><<<dim3(64 * 16, 1), 256, 0, stream>>>(
      SEL8, CMSG8, Dv, UPD1B8, (void*)G1B8, nullptr, nullptr,
      2048, Dv, 2048, 2048, 64, 0, 0, 0, 0x7F7F7F7Fu, 0x7B7B7B7Bu);

  // FCAT = [sum w sel | sum w gelu], final fused GEMM -> out (f32)
  combine2_kernel<<<Nv, 256, 0, stream>>>(SEL8, G1B8, keepA, tkprob, FCAT8);
  gemm128f8<6><<<dim3(32 * 8, 1), 256, 0, stream>>>(
      FCAT8, FCAT8, 1 << 30, WCAT8, (void*)out, nullptr, nullptr,
      3072, 3072, 3072, Dv, 32, 0, 0, 0, 0x7F7F7F7Fu, 0x7B7B7B7Bu);

  (void)in_sizes; (void)n_in; (void)out_size; (void)ws_size;
}